// Round 1
// baseline (2348.371 us; speedup 1.0000x reference)
//
#include <hip/hip_runtime.h>

// ---------------------------------------------------------------------------
// SimpleDifferentialGNN: 2x GCN encoder (enc GEMM + 3x [GEMM, CSR-aggregate,
// graph-LN, relu]) + global_add_pool + MLP head.  All f32.
// N=100000, E=1000000, G=64, D=64, H=128, L=3
// ---------------------------------------------------------------------------

#define TPB 256

// ---------------- small utility kernels ----------------

__global__ __launch_bounds__(TPB) void count_dst_k(const int* __restrict__ dst,
                                                   int* __restrict__ cnt, int E) {
  int e = blockIdx.x * TPB + threadIdx.x;
  if (e < E) atomicAdd(&cnt[dst[e]], 1);
}

__global__ __launch_bounds__(TPB) void dinv_k(const int* __restrict__ cnt,
                                              float* __restrict__ dinv, int n) {
  int i = blockIdx.x * TPB + threadIdx.x;
  if (i < n) dinv[i] = 1.0f / sqrtf((float)cnt[i] + 1.0f);
}

__global__ __launch_bounds__(TPB) void gbounds_k(const int* __restrict__ batch,
                                                 int* __restrict__ gstart, int n, int G) {
  int i = blockIdx.x * TPB + threadIdx.x;
  if (i >= n) return;
  int b = batch[i];
  if (i == 0) {
    for (int g = 0; g <= b; ++g) gstart[g] = 0;
  } else {
    int pb = batch[i - 1];
    for (int g = pb + 1; g <= b; ++g) gstart[g] = i;
  }
  if (i == n - 1) {
    for (int g = b + 1; g <= G; ++g) gstart[g] = n;
  }
}

// single-block exclusive scan of cnt[0..n) -> rowptr[0..n]
__global__ __launch_bounds__(1024) void scan_k(const int* __restrict__ cnt,
                                               int* __restrict__ rowptr, int n) {
  __shared__ int sdata[1024];
  int t = threadIdx.x;
  int chunk = (n + 1023) >> 10;
  int base = t * chunk;
  int end = base + chunk; if (end > n) end = n;
  int s = 0;
  for (int i = base; i < end && i >= 0; ++i) s += cnt[i];
  if (base >= n) s = 0;
  sdata[t] = s;
  __syncthreads();
  for (int d = 1; d < 1024; d <<= 1) {
    int w = (t >= d) ? sdata[t - d] : 0;
    __syncthreads();
    sdata[t] += w;
    __syncthreads();
  }
  int run = sdata[t] - s;  // exclusive prefix of this thread's chunk
  for (int i = base; i < end && i >= 0; ++i) { rowptr[i] = run; run += cnt[i]; }
  if (t == 1023) rowptr[n] = sdata[1023];
}

__global__ __launch_bounds__(TPB) void copy_int_k(const int* __restrict__ src,
                                                  int* __restrict__ dst, int n) {
  int i = blockIdx.x * TPB + threadIdx.x;
  if (i < n) dst[i] = src[i];
}

__global__ __launch_bounds__(TPB) void csrfill_k(const int* __restrict__ esrc,
                                                 const int* __restrict__ edst,
                                                 int* __restrict__ cursor,
                                                 int* __restrict__ csr_src, int E) {
  int e = blockIdx.x * TPB + threadIdx.x;
  if (e >= E) return;
  int d = edst[e];
  int p = atomicAdd(&cursor[d], 1);
  csr_src[p] = esrc[e];
}

// ---------------- GEMM: C[n][j] = sum_k A[n][k]*W[k][j] (+bias) ----------------
// block: 256 threads covers 128 rows x 128 cols, 8x8 per thread.

template <int K, bool BIAS>
__global__ __launch_bounds__(TPB) void gemm_k(const float* __restrict__ A,
                                              const float* __restrict__ W,
                                              const float* __restrict__ bias,
                                              float* __restrict__ C, int nrows) {
  __shared__ float As[32][132];  // [kk][rloc] transposed, padded (16B-aligned rows)
  __shared__ float Ws[32][132];  // [kk][j]
  const int tid = threadIdx.x;
  const int tx = tid & 15;   // col group: j0 = tx*8
  const int ty = tid >> 4;   // row group: r = ty*8 .. +7
  const int r0 = blockIdx.x << 7;
  float acc[8][8];
#pragma unroll
  for (int i = 0; i < 8; ++i)
#pragma unroll
    for (int j = 0; j < 8; ++j) acc[i][j] = 0.f;

  for (int k0 = 0; k0 < K; k0 += 32) {
    __syncthreads();
#pragma unroll
    for (int i = tid; i < 4096; i += TPB) {
      int rloc = i >> 5, kk = i & 31;
      int r = r0 + rloc;
      As[kk][rloc] = (r < nrows) ? A[(long)r * K + (k0 + kk)] : 0.f;
    }
#pragma unroll
    for (int i = tid; i < 4096; i += TPB) {
      int kk = i >> 7, j = i & 127;
      Ws[kk][j] = W[(long)(k0 + kk) * 128 + j];
    }
    __syncthreads();
#pragma unroll
    for (int kk = 0; kk < 32; ++kk) {
      float4 a0 = *(const float4*)&As[kk][ty * 8];
      float4 a1 = *(const float4*)&As[kk][ty * 8 + 4];
      float4 w0 = *(const float4*)&Ws[kk][tx * 8];
      float4 w1 = *(const float4*)&Ws[kk][tx * 8 + 4];
      float a[8] = {a0.x, a0.y, a0.z, a0.w, a1.x, a1.y, a1.z, a1.w};
      float w[8] = {w0.x, w0.y, w0.z, w0.w, w1.x, w1.y, w1.z, w1.w};
#pragma unroll
      for (int i = 0; i < 8; ++i)
#pragma unroll
        for (int j = 0; j < 8; ++j) acc[i][j] = fmaf(a[i], w[j], acc[i][j]);
    }
  }
#pragma unroll
  for (int i = 0; i < 8; ++i) {
    int r = r0 + ty * 8 + i;
    if (r < nrows) {
#pragma unroll
      for (int j = 0; j < 8; ++j) {
        float v = acc[i][j];
        if (BIAS) v += bias[tx * 8 + j];
        C[(long)r * 128 + tx * 8 + j] = v;
      }
    }
  }
}

// ---------------- aggregation: out[d] = xw[d]*dinv[d]^2 + sum_e xw[s]*dinv[s]dinv[d] + b
// one wave per node; lane covers 2 channels (float2). Also emits per-row LN stats.

__global__ __launch_bounds__(TPB) void aggregate_k(
    const float2* __restrict__ xw, const int* __restrict__ rowptr,
    const int* __restrict__ csr, const float* __restrict__ dinv,
    const float* __restrict__ bias, float2* __restrict__ out,
    float* __restrict__ rowsum, float* __restrict__ rowsumsq, int n) {
  int wave = threadIdx.x >> 6, lane = threadIdx.x & 63;
  int d = (blockIdx.x << 2) + wave;
  if (d >= n) return;
  float dd = dinv[d];
  float2 v = xw[(long)d * 64 + lane];
  float2 acc;
  acc.x = v.x * dd * dd;
  acc.y = v.y * dd * dd;
  int p1 = rowptr[d + 1];
  for (int p = rowptr[d]; p < p1; ++p) {
    int s = csr[p];
    float w = dinv[s] * dd;
    float2 u = xw[(long)s * 64 + lane];
    acc.x = fmaf(u.x, w, acc.x);
    acc.y = fmaf(u.y, w, acc.y);
  }
  const float2* b2 = (const float2*)bias;
  float2 bb = b2[lane];
  acc.x += bb.x;
  acc.y += bb.y;
  out[(long)d * 64 + lane] = acc;
  float s1 = acc.x + acc.y;
  float s2 = acc.x * acc.x + acc.y * acc.y;
#pragma unroll
  for (int m = 32; m >= 1; m >>= 1) {
    s1 += __shfl_xor(s1, m);
    s2 += __shfl_xor(s2, m);
  }
  if (lane == 0) { rowsum[d] = s1; rowsumsq[d] = s2; }
}

// ---------------- per-graph LN stats (double accumulation) ----------------

__global__ __launch_bounds__(TPB) void gstats_k(const float* __restrict__ rowsum,
                                                const float* __restrict__ rowsumsq,
                                                const int* __restrict__ gstart,
                                                float* __restrict__ meanA,
                                                float* __restrict__ rsigA) {
  __shared__ double sd1[TPB], sd2[TPB];
  int g = blockIdx.x, t = threadIdx.x;
  int n0 = gstart[g], n1 = gstart[g + 1];
  double s1 = 0, s2 = 0;
  for (int i = n0 + t; i < n1; i += TPB) { s1 += rowsum[i]; s2 += rowsumsq[i]; }
  sd1[t] = s1; sd2[t] = s2;
  __syncthreads();
  for (int st = TPB / 2; st > 0; st >>= 1) {
    if (t < st) { sd1[t] += sd1[t + st]; sd2[t] += sd2[t + st]; }
    __syncthreads();
  }
  if (t == 0) {
    double cntd = (double)(n1 - n0) * 128.0;
    if (cntd > 0.0) {
      double mean = sd1[0] / cntd;
      double var = sd2[0] / cntd - mean * mean;
      if (var < 0.0) var = 0.0;
      meanA[g] = (float)mean;
      rsigA[g] = (float)(1.0 / sqrt(var + 1e-5));
    } else {
      meanA[g] = 0.f;
      rsigA[g] = 0.f;
    }
  }
}

// ---------------- LN apply (+optional relu), in-place ----------------

__global__ __launch_bounds__(TPB) void ln_apply_k(float4* __restrict__ x,
                                                  const int* __restrict__ batch,
                                                  const float* __restrict__ meanA,
                                                  const float* __restrict__ rsigA,
                                                  const float4* __restrict__ w4,
                                                  const float4* __restrict__ b4,
                                                  int n, int doRelu) {
  int idx = blockIdx.x * TPB + threadIdx.x;
  if (idx >= n * 32) return;
  int node = idx >> 5, c4 = idx & 31;
  int g = batch[node];
  float m = meanA[g], r = rsigA[g];
  float4 v = x[idx];
  float4 w = w4[c4];
  float4 b = b4[c4];
  float4 o;
  o.x = (v.x - m) * r * w.x + b.x;
  o.y = (v.y - m) * r * w.y + b.y;
  o.z = (v.z - m) * r * w.z + b.z;
  o.w = (v.w - m) * r * w.w + b.w;
  if (doRelu) {
    o.x = fmaxf(o.x, 0.f);
    o.y = fmaxf(o.y, 0.f);
    o.z = fmaxf(o.z, 0.f);
    o.w = fmaxf(o.w, 0.f);
  }
  x[idx] = o;
}

// ---------------- global add pool ----------------

__global__ __launch_bounds__(128) void pool_k(const float* __restrict__ x,
                                              const int* __restrict__ gstart,
                                              float* __restrict__ pooled, int colofs) {
  int g = blockIdx.x >> 3, s = blockIdx.x & 7, j = threadIdx.x;
  int n0 = gstart[g], n1 = gstart[g + 1];
  float acc = 0.f;
  for (int nn = n0 + s; nn < n1; nn += 8) acc += x[(long)nn * 128 + j];
  atomicAdd(&pooled[g * 256 + colofs + j], acc);
}

// ---------------- MLP head (single block) ----------------

__global__ __launch_bounds__(TPB) void head_k(const float* __restrict__ pooled,
                                              const float* __restrict__ W1,
                                              const float* __restrict__ b1,
                                              const float* __restrict__ W2,
                                              const float* __restrict__ b2,
                                              const float* __restrict__ W3,
                                              const float* __restrict__ b3,
                                              float* __restrict__ out) {
  __shared__ float h1[64 * 128];
  __shared__ float h2[64 * 64];
  int tid = threadIdx.x;
  for (int o = tid; o < 64 * 128; o += TPB) {
    int i = o >> 7, j = o & 127;
    float acc = b1[j];
    for (int k = 0; k < 256; ++k) acc = fmaf(pooled[i * 256 + k], W1[k * 128 + j], acc);
    h1[o] = fmaxf(acc, 0.f);
  }
  __syncthreads();
  for (int o = tid; o < 64 * 64; o += TPB) {
    int i = o >> 6, j = o & 63;
    float acc = b2[j];
    for (int k = 0; k < 128; ++k) acc = fmaf(h1[i * 128 + k], W2[k * 64 + j], acc);
    h2[o] = fmaxf(acc, 0.f);
  }
  __syncthreads();
  if (tid < 64) {
    float acc = b3[0];
    for (int k = 0; k < 64; ++k) acc = fmaf(h2[tid * 64 + k], W3[k], acc);
    out[tid] = acc;
  }
}

// ---------------------------------------------------------------------------

extern "C" void kernel_launch(void* const* d_in, const int* in_sizes, int n_in,
                              void* d_out, int out_size, void* d_ws, size_t ws_size,
                              hipStream_t stream) {
  const int N = in_sizes[2];       // 100000
  const int E = in_sizes[1] / 2;   // 1000000
  const int G = 64, H = 128, D = 64, L = 3;
  (void)n_in; (void)ws_size; (void)D;

  const float* kernel_x = (const float*)d_in[0];
  const int* kernel_ei  = (const int*)d_in[1];
  const int* kernel_b   = (const int*)d_in[2];
  const float* design_x = (const float*)d_in[3];
  const int* design_ei  = (const int*)d_in[4];
  const int* design_b   = (const int*)d_in[5];
  const float* encW  = (const float*)d_in[7];
  const float* encB  = (const float*)d_in[8];
  const float* convW = (const float*)d_in[9];
  const float* convB = (const float*)d_in[10];
  const float* lnw   = (const float*)d_in[11];
  const float* lnb   = (const float*)d_in[12];
  const float* W1 = (const float*)d_in[13];
  const float* b1 = (const float*)d_in[14];
  const float* W2 = (const float*)d_in[15];
  const float* b2 = (const float*)d_in[16];
  const float* W3 = (const float*)d_in[17];
  const float* b3 = (const float*)d_in[18];
  float* out = (float*)d_out;
  (void)out_size;

  // workspace carve-up
  char* ws = (char*)d_ws;
  size_t off = 0;
  auto alloc = [&](size_t bytes) -> void* {
    void* p = ws + off;
    off = (off + bytes + 511) & ~(size_t)511;
    return p;
  };
  float* bufA    = (float*)alloc((size_t)N * H * 4);
  float* bufB    = (float*)alloc((size_t)N * H * 4);
  float* dinv    = (float*)alloc((size_t)N * 4);
  int* cntI      = (int*)alloc((size_t)N * 4);
  int* rowptr    = (int*)alloc((size_t)(N + 1) * 4);
  int* cursor    = (int*)alloc((size_t)N * 4);
  int* csr_src   = (int*)alloc((size_t)E * 4);
  int* gstart    = (int*)alloc((size_t)(G + 1) * 4);
  float* rowsum  = (float*)alloc((size_t)N * 4);
  float* rowsumsq= (float*)alloc((size_t)N * 4);
  float* meanA   = (float*)alloc((size_t)G * 4);
  float* rsigA   = (float*)alloc((size_t)G * 4);
  float* pooled  = (float*)alloc((size_t)G * 2 * H * 4);

  const int gN   = (N + TPB - 1) / TPB;     // 391
  const int gE   = (E + TPB - 1) / TPB;     // 3907
  const int gGemm = (N + 127) / 128;        // 782
  const int gAgg  = (N + 3) / 4;            // 25000
  const int gLn   = (N * 32 + TPB - 1) / TPB;

  hipMemsetAsync(pooled, 0, (size_t)G * 2 * H * 4, stream);

  struct GraphIn { const float* x; const int* ei; const int* batch; int colofs; };
  GraphIn graphs[2] = {
      {kernel_x, kernel_ei, kernel_b, 0},
      {design_x, design_ei, design_b, H},
  };

  for (int gi = 0; gi < 2; ++gi) {
    const float* x = graphs[gi].x;
    const int* esrc = graphs[gi].ei;
    const int* edst = graphs[gi].ei + E;
    const int* batch = graphs[gi].batch;
    int colofs = graphs[gi].colofs;

    // graph structure
    hipMemsetAsync(cntI, 0, (size_t)N * 4, stream);
    count_dst_k<<<gE, TPB, 0, stream>>>(edst, cntI, E);
    dinv_k<<<gN, TPB, 0, stream>>>(cntI, dinv, N);
    gbounds_k<<<gN, TPB, 0, stream>>>(batch, gstart, N, G);
    scan_k<<<1, 1024, 0, stream>>>(cntI, rowptr, N);
    hipMemcpyAsync(cursor, rowptr, (size_t)N * 4, hipMemcpyDeviceToDevice, stream);
    csrfill_k<<<gE, TPB, 0, stream>>>(esrc, edst, cursor, csr_src, E);

    // encoder: bufA = x @ encW + encB
    gemm_k<64, true><<<gGemm, TPB, 0, stream>>>(x, encW, encB, bufA, N);

    for (int i = 0; i < L; ++i) {
      // xw = bufA @ convW[i]  -> bufB
      gemm_k<128, false><<<gGemm, TPB, 0, stream>>>(bufA, convW + (size_t)i * H * H,
                                                    nullptr, bufB, N);
      // aggregate + self-loop + bias + row stats -> bufA
      aggregate_k<<<gAgg, TPB, 0, stream>>>((const float2*)bufB, rowptr, csr_src, dinv,
                                            convB + (size_t)i * H, (float2*)bufA,
                                            rowsum, rowsumsq, N);
      gstats_k<<<G, TPB, 0, stream>>>(rowsum, rowsumsq, gstart, meanA, rsigA);
      ln_apply_k<<<gLn, TPB, 0, stream>>>((float4*)bufA, batch, meanA, rsigA,
                                          (const float4*)(lnw + (size_t)i * H),
                                          (const float4*)(lnb + (size_t)i * H), N,
                                          (i < L - 1) ? 1 : 0);
    }
    pool_k<<<G * 8, 128, 0, stream>>>(bufA, gstart, pooled, colofs);
  }

  head_k<<<1, TPB, 0, stream>>>(pooled, W1, b1, W2, b2, W3, b3, out);
}

// Round 2
// 2032.507 us; speedup vs baseline: 1.1554x; 1.1554x over previous
//
#include <hip/hip_runtime.h>
#include <hip/hip_bf16.h>

// ---------------------------------------------------------------------------
// SimpleDifferentialGNN: 2x GCN encoder (enc GEMM + 3x [GEMM, CSR-aggregate,
// graph-LN, relu]) + global_add_pool + MLP head.
// N=100000, E=1000000, G=64, D=64, H=128, L=3
// R1: parallel head (64 blocks); xw gather buffer in bf16 (halves gather bytes)
// ---------------------------------------------------------------------------

#define TPB 256

__device__ __forceinline__ float bf2f(unsigned short s) {
  unsigned int u = ((unsigned int)s) << 16;
  float f;
  __builtin_memcpy(&f, &u, 4);
  return f;
}

// ---------------- small utility kernels ----------------

__global__ __launch_bounds__(TPB) void count_dst_k(const int* __restrict__ dst,
                                                   int* __restrict__ cnt, int E) {
  int e = blockIdx.x * TPB + threadIdx.x;
  if (e < E) atomicAdd(&cnt[dst[e]], 1);
}

__global__ __launch_bounds__(TPB) void dinv_k(const int* __restrict__ cnt,
                                              float* __restrict__ dinv, int n) {
  int i = blockIdx.x * TPB + threadIdx.x;
  if (i < n) dinv[i] = 1.0f / sqrtf((float)cnt[i] + 1.0f);
}

__global__ __launch_bounds__(TPB) void gbounds_k(const int* __restrict__ batch,
                                                 int* __restrict__ gstart, int n, int G) {
  int i = blockIdx.x * TPB + threadIdx.x;
  if (i >= n) return;
  int b = batch[i];
  if (i == 0) {
    for (int g = 0; g <= b; ++g) gstart[g] = 0;
  } else {
    int pb = batch[i - 1];
    for (int g = pb + 1; g <= b; ++g) gstart[g] = i;
  }
  if (i == n - 1) {
    for (int g = b + 1; g <= G; ++g) gstart[g] = n;
  }
}

// single-block exclusive scan of cnt[0..n) -> rowptr[0..n]
__global__ __launch_bounds__(1024) void scan_k(const int* __restrict__ cnt,
                                               int* __restrict__ rowptr, int n) {
  __shared__ int sdata[1024];
  int t = threadIdx.x;
  int chunk = (n + 1023) >> 10;
  int base = t * chunk;
  int end = base + chunk; if (end > n) end = n;
  int s = 0;
  for (int i = base; i < end && i >= 0; ++i) s += cnt[i];
  if (base >= n) s = 0;
  sdata[t] = s;
  __syncthreads();
  for (int d = 1; d < 1024; d <<= 1) {
    int w = (t >= d) ? sdata[t - d] : 0;
    __syncthreads();
    sdata[t] += w;
    __syncthreads();
  }
  int run = sdata[t] - s;  // exclusive prefix of this thread's chunk
  for (int i = base; i < end && i >= 0; ++i) { rowptr[i] = run; run += cnt[i]; }
  if (t == 1023) rowptr[n] = sdata[1023];
}

__global__ __launch_bounds__(TPB) void csrfill_k(const int* __restrict__ esrc,
                                                 const int* __restrict__ edst,
                                                 int* __restrict__ cursor,
                                                 int* __restrict__ csr_src, int E) {
  int e = blockIdx.x * TPB + threadIdx.x;
  if (e >= E) return;
  int d = edst[e];
  int p = atomicAdd(&cursor[d], 1);
  csr_src[p] = esrc[e];
}

// ---------------- GEMM: C[n][j] = sum_k A[n][k]*W[k][j] (+bias) ----------------
// block: 256 threads covers 128 rows x 128 cols, 8x8 per thread.

template <int K, bool BIAS, bool BF16OUT>
__global__ __launch_bounds__(TPB) void gemm_k(const float* __restrict__ A,
                                              const float* __restrict__ W,
                                              const float* __restrict__ bias,
                                              void* __restrict__ Cv, int nrows) {
  __shared__ float As[32][132];  // [kk][rloc] transposed, padded
  __shared__ float Ws[32][132];  // [kk][j]
  const int tid = threadIdx.x;
  const int tx = tid & 15;   // col group: j0 = tx*8
  const int ty = tid >> 4;   // row group: r = ty*8 .. +7
  const int r0 = blockIdx.x << 7;
  float acc[8][8];
#pragma unroll
  for (int i = 0; i < 8; ++i)
#pragma unroll
    for (int j = 0; j < 8; ++j) acc[i][j] = 0.f;

  for (int k0 = 0; k0 < K; k0 += 32) {
    __syncthreads();
#pragma unroll
    for (int i = tid; i < 4096; i += TPB) {
      int rloc = i >> 5, kk = i & 31;
      int r = r0 + rloc;
      As[kk][rloc] = (r < nrows) ? A[(long)r * K + (k0 + kk)] : 0.f;
    }
#pragma unroll
    for (int i = tid; i < 4096; i += TPB) {
      int kk = i >> 7, j = i & 127;
      Ws[kk][j] = W[(long)(k0 + kk) * 128 + j];
    }
    __syncthreads();
#pragma unroll
    for (int kk = 0; kk < 32; ++kk) {
      float4 a0 = *(const float4*)&As[kk][ty * 8];
      float4 a1 = *(const float4*)&As[kk][ty * 8 + 4];
      float4 w0 = *(const float4*)&Ws[kk][tx * 8];
      float4 w1 = *(const float4*)&Ws[kk][tx * 8 + 4];
      float a[8] = {a0.x, a0.y, a0.z, a0.w, a1.x, a1.y, a1.z, a1.w};
      float w[8] = {w0.x, w0.y, w0.z, w0.w, w1.x, w1.y, w1.z, w1.w};
#pragma unroll
      for (int i = 0; i < 8; ++i)
#pragma unroll
        for (int j = 0; j < 8; ++j) acc[i][j] = fmaf(a[i], w[j], acc[i][j]);
    }
  }
#pragma unroll
  for (int i = 0; i < 8; ++i) {
    int r = r0 + ty * 8 + i;
    if (r < nrows) {
      if (BF16OUT) {
        __hip_bfloat16* C = (__hip_bfloat16*)Cv;
#pragma unroll
        for (int j = 0; j < 8; ++j) {
          float v = acc[i][j];
          if (BIAS) v += bias[tx * 8 + j];
          C[(long)r * 128 + tx * 8 + j] = __float2bfloat16(v);
        }
      } else {
        float* C = (float*)Cv;
#pragma unroll
        for (int j = 0; j < 8; ++j) {
          float v = acc[i][j];
          if (BIAS) v += bias[tx * 8 + j];
          C[(long)r * 128 + tx * 8 + j] = v;
        }
      }
    }
  }
}

// ---------------- aggregation ----------------
// out[d] = xw[d]*dinv[d]^2 + sum_e xw[s]*dinv[s]dinv[d] + b  (xw in bf16)
// one wave per node; lane covers 2 channels. Also emits per-row LN stats.

__global__ __launch_bounds__(TPB) void aggregate_k(
    const ushort2* __restrict__ xw, const int* __restrict__ rowptr,
    const int* __restrict__ csr, const float* __restrict__ dinv,
    const float* __restrict__ bias, float2* __restrict__ out,
    float* __restrict__ rowsum, float* __restrict__ rowsumsq, int n) {
  int wave = threadIdx.x >> 6, lane = threadIdx.x & 63;
  int d = (blockIdx.x << 2) + wave;
  if (d >= n) return;
  float dd = dinv[d];
  ushort2 v = xw[(long)d * 64 + lane];
  float2 acc;
  acc.x = bf2f(v.x) * dd * dd;
  acc.y = bf2f(v.y) * dd * dd;
  int p1 = rowptr[d + 1];
  for (int p = rowptr[d]; p < p1; ++p) {
    int s = csr[p];
    float w = dinv[s] * dd;
    ushort2 u = xw[(long)s * 64 + lane];
    acc.x = fmaf(bf2f(u.x), w, acc.x);
    acc.y = fmaf(bf2f(u.y), w, acc.y);
  }
  const float2* b2 = (const float2*)bias;
  float2 bb = b2[lane];
  acc.x += bb.x;
  acc.y += bb.y;
  out[(long)d * 64 + lane] = acc;
  float s1 = acc.x + acc.y;
  float s2 = acc.x * acc.x + acc.y * acc.y;
#pragma unroll
  for (int m = 32; m >= 1; m >>= 1) {
    s1 += __shfl_xor(s1, m);
    s2 += __shfl_xor(s2, m);
  }
  if (lane == 0) { rowsum[d] = s1; rowsumsq[d] = s2; }
}

// ---------------- per-graph LN stats (double accumulation) ----------------

__global__ __launch_bounds__(TPB) void gstats_k(const float* __restrict__ rowsum,
                                                const float* __restrict__ rowsumsq,
                                                const int* __restrict__ gstart,
                                                float* __restrict__ meanA,
                                                float* __restrict__ rsigA) {
  __shared__ double sd1[TPB], sd2[TPB];
  int g = blockIdx.x, t = threadIdx.x;
  int n0 = gstart[g], n1 = gstart[g + 1];
  double s1 = 0, s2 = 0;
  for (int i = n0 + t; i < n1; i += TPB) { s1 += rowsum[i]; s2 += rowsumsq[i]; }
  sd1[t] = s1; sd2[t] = s2;
  __syncthreads();
  for (int st = TPB / 2; st > 0; st >>= 1) {
    if (t < st) { sd1[t] += sd1[t + st]; sd2[t] += sd2[t + st]; }
    __syncthreads();
  }
  if (t == 0) {
    double cntd = (double)(n1 - n0) * 128.0;
    if (cntd > 0.0) {
      double mean = sd1[0] / cntd;
      double var = sd2[0] / cntd - mean * mean;
      if (var < 0.0) var = 0.0;
      meanA[g] = (float)mean;
      rsigA[g] = (float)(1.0 / sqrt(var + 1e-5));
    } else {
      meanA[g] = 0.f;
      rsigA[g] = 0.f;
    }
  }
}

// ---------------- LN apply (+optional relu), in-place ----------------

__global__ __launch_bounds__(TPB) void ln_apply_k(float4* __restrict__ x,
                                                  const int* __restrict__ batch,
                                                  const float* __restrict__ meanA,
                                                  const float* __restrict__ rsigA,
                                                  const float4* __restrict__ w4,
                                                  const float4* __restrict__ b4,
                                                  int n, int doRelu) {
  int idx = blockIdx.x * TPB + threadIdx.x;
  if (idx >= n * 32) return;
  int node = idx >> 5, c4 = idx & 31;
  int g = batch[node];
  float m = meanA[g], r = rsigA[g];
  float4 v = x[idx];
  float4 w = w4[c4];
  float4 b = b4[c4];
  float4 o;
  o.x = (v.x - m) * r * w.x + b.x;
  o.y = (v.y - m) * r * w.y + b.y;
  o.z = (v.z - m) * r * w.z + b.z;
  o.w = (v.w - m) * r * w.w + b.w;
  if (doRelu) {
    o.x = fmaxf(o.x, 0.f);
    o.y = fmaxf(o.y, 0.f);
    o.z = fmaxf(o.z, 0.f);
    o.w = fmaxf(o.w, 0.f);
  }
  x[idx] = o;
}

// ---------------- global add pool ----------------

__global__ __launch_bounds__(128) void pool_k(const float* __restrict__ x,
                                              const int* __restrict__ gstart,
                                              float* __restrict__ pooled, int colofs) {
  int g = blockIdx.x >> 3, s = blockIdx.x & 7, j = threadIdx.x;
  int n0 = gstart[g], n1 = gstart[g + 1];
  float acc = 0.f;
  for (int nn = n0 + s; nn < n1; nn += 8) acc += x[(long)nn * 128 + j];
  atomicAdd(&pooled[g * 256 + colofs + j], acc);
}

// ---------------- MLP head: one block per graph ----------------

__global__ __launch_bounds__(TPB) void head_k(const float* __restrict__ pooled,
                                              const float* __restrict__ W1,
                                              const float* __restrict__ b1,
                                              const float* __restrict__ W2,
                                              const float* __restrict__ b2,
                                              const float* __restrict__ W3,
                                              const float* __restrict__ b3,
                                              float* __restrict__ out) {
  __shared__ float ps[256];
  __shared__ float part[256];
  __shared__ float h1[128];
  __shared__ float h2[64];
  int g = blockIdx.x, tid = threadIdx.x;
  ps[tid] = pooled[g * 256 + tid];
  __syncthreads();
  // layer 1: h1[j] = relu(sum_k ps[k]*W1[k][j] + b1[j]); 2 threads per j
  {
    int j = tid & 127, half = tid >> 7;
    float acc = 0.f;
    const float* w = W1 + (size_t)half * 128 * 128 + j;
    const float* p = ps + half * 128;
#pragma unroll 8
    for (int k = 0; k < 128; ++k) acc = fmaf(p[k], w[(size_t)k * 128], acc);
    part[tid] = acc;
    __syncthreads();
    if (tid < 128) h1[tid] = fmaxf(part[tid] + part[tid + 128] + b1[tid], 0.f);
    __syncthreads();
  }
  // layer 2: h2[j] = relu(sum_k h1[k]*W2[k][j] + b2[j]); 4 threads per j
  {
    int j = tid & 63, q = tid >> 6;
    float acc = 0.f;
    const float* w = W2 + (size_t)q * 32 * 64 + j;
    const float* p = h1 + q * 32;
#pragma unroll 8
    for (int k = 0; k < 32; ++k) acc = fmaf(p[k], w[(size_t)k * 64], acc);
    part[tid] = acc;
    __syncthreads();
    if (tid < 64)
      h2[tid] = fmaxf(part[tid] + part[tid + 64] + part[tid + 128] + part[tid + 192] + b2[tid], 0.f);
    __syncthreads();
  }
  // layer 3: out[g] = sum_k h2[k]*W3[k] + b3
  if (tid < 64) {
    float v = h2[tid] * W3[tid];
#pragma unroll
    for (int m = 32; m >= 1; m >>= 1) v += __shfl_xor(v, m);
    if (tid == 0) out[g] = v + b3[0];
  }
}

// ---------------------------------------------------------------------------

extern "C" void kernel_launch(void* const* d_in, const int* in_sizes, int n_in,
                              void* d_out, int out_size, void* d_ws, size_t ws_size,
                              hipStream_t stream) {
  const int N = in_sizes[2];       // 100000
  const int E = in_sizes[1] / 2;   // 1000000
  const int G = 64, H = 128, D = 64, L = 3;
  (void)n_in; (void)ws_size; (void)D;

  const float* kernel_x = (const float*)d_in[0];
  const int* kernel_ei  = (const int*)d_in[1];
  const int* kernel_b   = (const int*)d_in[2];
  const float* design_x = (const float*)d_in[3];
  const int* design_ei  = (const int*)d_in[4];
  const int* design_b   = (const int*)d_in[5];
  const float* encW  = (const float*)d_in[7];
  const float* encB  = (const float*)d_in[8];
  const float* convW = (const float*)d_in[9];
  const float* convB = (const float*)d_in[10];
  const float* lnw   = (const float*)d_in[11];
  const float* lnb   = (const float*)d_in[12];
  const float* W1 = (const float*)d_in[13];
  const float* b1 = (const float*)d_in[14];
  const float* W2 = (const float*)d_in[15];
  const float* b2 = (const float*)d_in[16];
  const float* W3 = (const float*)d_in[17];
  const float* b3 = (const float*)d_in[18];
  float* out = (float*)d_out;
  (void)out_size;

  // workspace carve-up
  char* ws = (char*)d_ws;
  size_t off = 0;
  auto alloc = [&](size_t bytes) -> void* {
    void* p = ws + off;
    off = (off + bytes + 511) & ~(size_t)511;
    return p;
  };
  float* bufA    = (float*)alloc((size_t)N * H * 4);
  __hip_bfloat16* bufB = (__hip_bfloat16*)alloc((size_t)N * H * 2);  // xw in bf16
  float* dinv    = (float*)alloc((size_t)N * 4);
  int* cntI      = (int*)alloc((size_t)N * 4);
  int* rowptr    = (int*)alloc((size_t)(N + 1) * 4);
  int* cursor    = (int*)alloc((size_t)N * 4);
  int* csr_src   = (int*)alloc((size_t)E * 4);
  int* gstart    = (int*)alloc((size_t)(G + 1) * 4);
  float* rowsum  = (float*)alloc((size_t)N * 4);
  float* rowsumsq= (float*)alloc((size_t)N * 4);
  float* meanA   = (float*)alloc((size_t)G * 4);
  float* rsigA   = (float*)alloc((size_t)G * 4);
  float* pooled  = (float*)alloc((size_t)G * 2 * H * 4);

  const int gN   = (N + TPB - 1) / TPB;
  const int gE   = (E + TPB - 1) / TPB;
  const int gGemm = (N + 127) / 128;
  const int gAgg  = (N + 3) / 4;
  const int gLn   = (N * 32 + TPB - 1) / TPB;

  hipMemsetAsync(pooled, 0, (size_t)G * 2 * H * 4, stream);

  struct GraphIn { const float* x; const int* ei; const int* batch; int colofs; };
  GraphIn graphs[2] = {
      {kernel_x, kernel_ei, kernel_b, 0},
      {design_x, design_ei, design_b, H},
  };

  for (int gi = 0; gi < 2; ++gi) {
    const float* x = graphs[gi].x;
    const int* esrc = graphs[gi].ei;
    const int* edst = graphs[gi].ei + E;
    const int* batch = graphs[gi].batch;
    int colofs = graphs[gi].colofs;

    // graph structure
    hipMemsetAsync(cntI, 0, (size_t)N * 4, stream);
    count_dst_k<<<gE, TPB, 0, stream>>>(edst, cntI, E);
    dinv_k<<<gN, TPB, 0, stream>>>(cntI, dinv, N);
    gbounds_k<<<gN, TPB, 0, stream>>>(batch, gstart, N, G);
    scan_k<<<1, 1024, 0, stream>>>(cntI, rowptr, N);
    hipMemcpyAsync(cursor, rowptr, (size_t)N * 4, hipMemcpyDeviceToDevice, stream);
    csrfill_k<<<gE, TPB, 0, stream>>>(esrc, edst, cursor, csr_src, E);

    // encoder: bufA = x @ encW + encB   (f32 out)
    gemm_k<64, true, false><<<gGemm, TPB, 0, stream>>>(x, encW, encB, bufA, N);

    for (int i = 0; i < L; ++i) {
      // xw = bufA @ convW[i]  -> bufB (bf16)
      gemm_k<128, false, true><<<gGemm, TPB, 0, stream>>>(
          bufA, convW + (size_t)i * H * H, nullptr, bufB, N);
      // aggregate + self-loop + bias + row stats -> bufA (f32)
      aggregate_k<<<gAgg, TPB, 0, stream>>>((const ushort2*)bufB, rowptr, csr_src, dinv,
                                            convB + (size_t)i * H, (float2*)bufA,
                                            rowsum, rowsumsq, N);
      gstats_k<<<G, TPB, 0, stream>>>(rowsum, rowsumsq, gstart, meanA, rsigA);
      ln_apply_k<<<gLn, TPB, 0, stream>>>((float4*)bufA, batch, meanA, rsigA,
                                          (const float4*)(lnw + (size_t)i * H),
                                          (const float4*)(lnb + (size_t)i * H), N,
                                          (i < L - 1) ? 1 : 0);
    }
    pool_k<<<G * 8, 128, 0, stream>>>(bufA, gstart, pooled, colofs);
  }

  head_k<<<G, TPB, 0, stream>>>(pooled, W1, b1, W2, b2, W3, b3, out);
}

// Round 3
// 1316.008 us; speedup vs baseline: 1.7845x; 1.5444x over previous
//
#include <hip/hip_runtime.h>

// ---------------------------------------------------------------------------
// SimpleDifferentialGNN: 2x GCN encoder + global_add_pool + MLP head.
// N=100000, E=1000000, G=64, D=64, H=128, L=3
// R2: multi-block scan (was 324us single-block); all GEMMs via bf16 MFMA
//     (16x16x32) with XOR-swizzled LDS; hidden state carried as bf16.
// ---------------------------------------------------------------------------

#define TPB 256

typedef __attribute__((ext_vector_type(8))) short bf16x8;
typedef __attribute__((ext_vector_type(4))) float f32x4;

__device__ __forceinline__ float bf2f(unsigned short s) {
  unsigned int u = ((unsigned int)s) << 16;
  float f;
  __builtin_memcpy(&f, &u, 4);
  return f;
}

__device__ __forceinline__ unsigned short f2bf(float f) {
  unsigned int u;
  __builtin_memcpy(&u, &f, 4);
  u = (u + 0x7FFF + ((u >> 16) & 1)) >> 16;  // RNE
  return (unsigned short)u;
}

// ---------------- small utility kernels ----------------

__global__ __launch_bounds__(TPB) void count_dst_k(const int* __restrict__ dst,
                                                   int* __restrict__ cnt, int E) {
  int e = blockIdx.x * TPB + threadIdx.x;
  if (e < E) atomicAdd(&cnt[dst[e]], 1);
}

__global__ __launch_bounds__(TPB) void dinv_k(const int* __restrict__ cnt,
                                              float* __restrict__ dinv, int n) {
  int i = blockIdx.x * TPB + threadIdx.x;
  if (i < n) dinv[i] = 1.0f / sqrtf((float)cnt[i] + 1.0f);
}

__global__ __launch_bounds__(TPB) void gbounds_k(const int* __restrict__ batch,
                                                 int* __restrict__ gstart, int n, int G) {
  int i = blockIdx.x * TPB + threadIdx.x;
  if (i >= n) return;
  int b = batch[i];
  if (i == 0) {
    for (int g = 0; g <= b; ++g) gstart[g] = 0;
  } else {
    int pb = batch[i - 1];
    for (int g = pb + 1; g <= b; ++g) gstart[g] = i;
  }
  if (i == n - 1) {
    for (int g = b + 1; g <= G; ++g) gstart[g] = n;
  }
}

// ---------------- multi-block exclusive scan of cnt -> rowptr ----------------
// pass 1: per-block (512 elems) sums; pass 2: scan the <=256 partials;
// pass 3: per-block fill with carry.

__global__ __launch_bounds__(TPB) void scan_partial_k(const int* __restrict__ cnt,
                                                      int* __restrict__ bsum, int n) {
  __shared__ int sd[TPB];
  int t = threadIdx.x, i0 = blockIdx.x * 512 + t * 2;
  int s = 0;
  if (i0 < n) s += cnt[i0];
  if (i0 + 1 < n) s += cnt[i0 + 1];
  sd[t] = s;
  __syncthreads();
  for (int st = TPB / 2; st > 0; st >>= 1) {
    if (t < st) sd[t] += sd[t + st];
    __syncthreads();
  }
  if (t == 0) bsum[blockIdx.x] = sd[0];
}

__global__ __launch_bounds__(TPB) void scan_small_k(const int* __restrict__ bsum,
                                                    int* __restrict__ bpre, int P,
                                                    int* __restrict__ rowptr, int n) {
  __shared__ int sd[TPB];
  int t = threadIdx.x;
  int v = (t < P) ? bsum[t] : 0;
  sd[t] = v;
  __syncthreads();
  for (int d = 1; d < TPB; d <<= 1) {
    int w = (t >= d) ? sd[t - d] : 0;
    __syncthreads();
    sd[t] += w;
    __syncthreads();
  }
  if (t < P) bpre[t] = sd[t] - v;  // exclusive
  if (t == TPB - 1) rowptr[n] = sd[TPB - 1];
}

__global__ __launch_bounds__(TPB) void scan_fill_k(const int* __restrict__ cnt,
                                                   const int* __restrict__ bpre,
                                                   int* __restrict__ rowptr, int n) {
  __shared__ int sd[TPB];
  int t = threadIdx.x, i0 = blockIdx.x * 512 + t * 2;
  int c0 = (i0 < n) ? cnt[i0] : 0;
  int c1 = (i0 + 1 < n) ? cnt[i0 + 1] : 0;
  int s = c0 + c1;
  sd[t] = s;
  __syncthreads();
  for (int d = 1; d < TPB; d <<= 1) {
    int w = (t >= d) ? sd[t - d] : 0;
    __syncthreads();
    sd[t] += w;
    __syncthreads();
  }
  int ex = sd[t] - s + bpre[blockIdx.x];
  if (i0 < n) rowptr[i0] = ex;
  if (i0 + 1 < n) rowptr[i0 + 1] = ex + c0;
}

__global__ __launch_bounds__(TPB) void csrfill_k(const int* __restrict__ esrc,
                                                 const int* __restrict__ edst,
                                                 int* __restrict__ cursor,
                                                 int* __restrict__ csr_src, int E) {
  int e = blockIdx.x * TPB + threadIdx.x;
  if (e >= E) return;
  int d = edst[e];
  int p = atomicAdd(&cursor[d], 1);
  csr_src[p] = esrc[e];
}

// ---------------- dtype prep ----------------

// x (f32) -> bf16, 4 elems/thread
__global__ __launch_bounds__(TPB) void cvt_x_k(const float4* __restrict__ src,
                                               ushort4* __restrict__ dst, int n4) {
  int i = blockIdx.x * TPB + threadIdx.x;
  if (i >= n4) return;
  float4 v = src[i];
  ushort4 o;
  o.x = f2bf(v.x); o.y = f2bf(v.y); o.z = f2bf(v.z); o.w = f2bf(v.w);
  dst[i] = o;
}

// W [K][C] f32 -> Wt [C][K] bf16
__global__ __launch_bounds__(TPB) void transp_cvt_k(const float* __restrict__ src,
                                                    unsigned short* __restrict__ dst,
                                                    int K, int C) {
  int idx = blockIdx.x * TPB + threadIdx.x;
  if (idx >= K * C) return;
  int k = idx / C, c = idx % C;
  dst[c * K + k] = f2bf(src[idx]);
}

// ---------------- MFMA GEMM: C[r][j] = sum_k A[r][k]*W[k][j] (+bias) --------
// A: [nrows][K] bf16 row-major.  Wt: [128][K] bf16 (W transposed).
// Block: 256 threads = 4 waves; tile 128 rows x 128 cols; whole K in LDS.
// LDS 16B-blocks XOR-swizzled by (row&7) to kill stride-256B bank conflicts.
// Fragment layouts (verified m89/m91): A: row=lane&15, k=(lane>>4)*8+j;
// B: col=lane&15, same k; D: col=lane&15, row=(lane>>4)*4+reg.

template <int K, bool BIAS>
__global__ __launch_bounds__(TPB) void mfma_gemm_k(
    const unsigned short* __restrict__ A, const unsigned short* __restrict__ Wt,
    const float* __restrict__ bias, unsigned short* __restrict__ C, int nrows) {
  __shared__ short As[128 * K];
  __shared__ short Bs[128 * K];
  const int tid = threadIdx.x;
  const int r0 = blockIdx.x << 7;
  const int lane = tid & 63;
  const int wv = tid >> 6;
  const int lr = lane & 15, lg = lane >> 4;
  constexpr int CPR = K / 8;  // 16B chunks per row

  for (int i = tid; i < 128 * CPR; i += TPB) {
    int rloc = i / CPR, cb = i % CPR;
    int r = r0 + rloc;
    bf16x8 v = {0, 0, 0, 0, 0, 0, 0, 0};
    if (r < nrows) v = *(const bf16x8*)(A + (long)r * K + cb * 8);
    int sb = cb ^ (rloc & 7);
    *(bf16x8*)(&As[rloc * K + sb * 8]) = v;
  }
  for (int i = tid; i < 128 * CPR; i += TPB) {
    int rloc = i / CPR, cb = i % CPR;
    bf16x8 v = *(const bf16x8*)(Wt + (long)rloc * K + cb * 8);
    int sb = cb ^ (rloc & 7);
    *(bf16x8*)(&Bs[rloc * K + sb * 8]) = v;
  }
  __syncthreads();

  f32x4 acc[2][8];
#pragma unroll
  for (int m = 0; m < 2; ++m)
#pragma unroll
    for (int n = 0; n < 8; ++n) acc[m][n] = {0.f, 0.f, 0.f, 0.f};

  const int wrow = wv * 32;
#pragma unroll
  for (int k0 = 0; k0 < K; k0 += 32) {
    const int cbk = (k0 >> 3) + lg;
    bf16x8 a[2], b[8];
#pragma unroll
    for (int m = 0; m < 2; ++m) {
      int rr = wrow + m * 16 + lr;
      int sb = cbk ^ (rr & 7);
      a[m] = *(const bf16x8*)(&As[rr * K + sb * 8]);
    }
#pragma unroll
    for (int n = 0; n < 8; ++n) {
      int rr = n * 16 + lr;
      int sb = cbk ^ (rr & 7);
      b[n] = *(const bf16x8*)(&Bs[rr * K + sb * 8]);
    }
#pragma unroll
    for (int m = 0; m < 2; ++m)
#pragma unroll
      for (int n = 0; n < 8; ++n)
        acc[m][n] = __builtin_amdgcn_mfma_f32_16x16x32_bf16(a[m], b[n], acc[m][n], 0, 0, 0);
  }

#pragma unroll
  for (int n = 0; n < 8; ++n) {
    int col = n * 16 + lr;
    float bv = BIAS ? bias[col] : 0.f;
#pragma unroll
    for (int m = 0; m < 2; ++m) {
      int rowb = r0 + wrow + m * 16 + lg * 4;
#pragma unroll
      for (int ri = 0; ri < 4; ++ri) {
        int r = rowb + ri;
        if (r < nrows) C[(long)r * 128 + col] = f2bf(acc[m][n][ri] + bv);
      }
    }
  }
}

// ---------------- aggregation ----------------
// out[d] = xw[d]*dinv[d]^2 + sum_e xw[s]*dinv[s]dinv[d] + b  (xw bf16)
// one wave per node; lane covers 2 channels. Also emits per-row LN stats.

__global__ __launch_bounds__(TPB) void aggregate_k(
    const ushort2* __restrict__ xw, const int* __restrict__ rowptr,
    const int* __restrict__ csr, const float* __restrict__ dinv,
    const float* __restrict__ bias, float2* __restrict__ out,
    float* __restrict__ rowsum, float* __restrict__ rowsumsq, int n) {
  int wave = threadIdx.x >> 6, lane = threadIdx.x & 63;
  int d = (blockIdx.x << 2) + wave;
  if (d >= n) return;
  float dd = dinv[d];
  ushort2 v = xw[(long)d * 64 + lane];
  float2 acc;
  acc.x = bf2f(v.x) * dd * dd;
  acc.y = bf2f(v.y) * dd * dd;
  int p1 = rowptr[d + 1];
  for (int p = rowptr[d]; p < p1; ++p) {
    int s = csr[p];
    float w = dinv[s] * dd;
    ushort2 u = xw[(long)s * 64 + lane];
    acc.x = fmaf(bf2f(u.x), w, acc.x);
    acc.y = fmaf(bf2f(u.y), w, acc.y);
  }
  const float2* b2 = (const float2*)bias;
  float2 bb = b2[lane];
  acc.x += bb.x;
  acc.y += bb.y;
  out[(long)d * 64 + lane] = acc;
  float s1 = acc.x + acc.y;
  float s2 = acc.x * acc.x + acc.y * acc.y;
#pragma unroll
  for (int m = 32; m >= 1; m >>= 1) {
    s1 += __shfl_xor(s1, m);
    s2 += __shfl_xor(s2, m);
  }
  if (lane == 0) { rowsum[d] = s1; rowsumsq[d] = s2; }
}

// ---------------- per-graph LN stats (double accumulation) ----------------

__global__ __launch_bounds__(TPB) void gstats_k(const float* __restrict__ rowsum,
                                                const float* __restrict__ rowsumsq,
                                                const int* __restrict__ gstart,
                                                float* __restrict__ meanA,
                                                float* __restrict__ rsigA) {
  __shared__ double sd1[TPB], sd2[TPB];
  int g = blockIdx.x, t = threadIdx.x;
  int n0 = gstart[g], n1 = gstart[g + 1];
  double s1 = 0, s2 = 0;
  for (int i = n0 + t; i < n1; i += TPB) { s1 += rowsum[i]; s2 += rowsumsq[i]; }
  sd1[t] = s1; sd2[t] = s2;
  __syncthreads();
  for (int st = TPB / 2; st > 0; st >>= 1) {
    if (t < st) { sd1[t] += sd1[t + st]; sd2[t] += sd2[t + st]; }
    __syncthreads();
  }
  if (t == 0) {
    double cntd = (double)(n1 - n0) * 128.0;
    if (cntd > 0.0) {
      double mean = sd1[0] / cntd;
      double var = sd2[0] / cntd - mean * mean;
      if (var < 0.0) var = 0.0;
      meanA[g] = (float)mean;
      rsigA[g] = (float)(1.0 / sqrt(var + 1e-5));
    } else {
      meanA[g] = 0.f;
      rsigA[g] = 0.f;
    }
  }
}

// ---------------- LN apply (+optional relu): f32 in -> bf16 out ----------------

__global__ __launch_bounds__(TPB) void ln_apply_k(const float4* __restrict__ x,
                                                  const int* __restrict__ batch,
                                                  const float* __restrict__ meanA,
                                                  const float* __restrict__ rsigA,
                                                  const float4* __restrict__ w4,
                                                  const float4* __restrict__ b4,
                                                  ushort4* __restrict__ outb,
                                                  int n, int doRelu) {
  int idx = blockIdx.x * TPB + threadIdx.x;
  if (idx >= n * 32) return;
  int node = idx >> 5, c4 = idx & 31;
  int g = batch[node];
  float m = meanA[g], r = rsigA[g];
  float4 v = x[idx];
  float4 w = w4[c4];
  float4 b = b4[c4];
  float4 o;
  o.x = (v.x - m) * r * w.x + b.x;
  o.y = (v.y - m) * r * w.y + b.y;
  o.z = (v.z - m) * r * w.z + b.z;
  o.w = (v.w - m) * r * w.w + b.w;
  if (doRelu) {
    o.x = fmaxf(o.x, 0.f);
    o.y = fmaxf(o.y, 0.f);
    o.z = fmaxf(o.z, 0.f);
    o.w = fmaxf(o.w, 0.f);
  }
  ushort4 ob;
  ob.x = f2bf(o.x); ob.y = f2bf(o.y); ob.z = f2bf(o.z); ob.w = f2bf(o.w);
  outb[idx] = ob;
}

// ---------------- global add pool (bf16 in, f32 atomics out) ----------------

__global__ __launch_bounds__(128) void pool_k(const unsigned short* __restrict__ x,
                                              const int* __restrict__ gstart,
                                              float* __restrict__ pooled, int colofs) {
  int g = blockIdx.x >> 3, s = blockIdx.x & 7, j = threadIdx.x;
  int n0 = gstart[g], n1 = gstart[g + 1];
  float acc = 0.f;
  for (int nn = n0 + s; nn < n1; nn += 8) acc += bf2f(x[(long)nn * 128 + j]);
  atomicAdd(&pooled[g * 256 + colofs + j], acc);
}

// ---------------- MLP head: one block per graph ----------------

__global__ __launch_bounds__(TPB) void head_k(const float* __restrict__ pooled,
                                              const float* __restrict__ W1,
                                              const float* __restrict__ b1,
                                              const float* __restrict__ W2,
                                              const float* __restrict__ b2,
                                              const float* __restrict__ W3,
                                              const float* __restrict__ b3,
                                              float* __restrict__ out) {
  __shared__ float ps[256];
  __shared__ float part[256];
  __shared__ float h1[128];
  __shared__ float h2[64];
  int g = blockIdx.x, tid = threadIdx.x;
  ps[tid] = pooled[g * 256 + tid];
  __syncthreads();
  {
    int j = tid & 127, half = tid >> 7;
    float acc = 0.f;
    const float* w = W1 + (size_t)half * 128 * 128 + j;
    const float* p = ps + half * 128;
#pragma unroll 8
    for (int k = 0; k < 128; ++k) acc = fmaf(p[k], w[(size_t)k * 128], acc);
    part[tid] = acc;
    __syncthreads();
    if (tid < 128) h1[tid] = fmaxf(part[tid] + part[tid + 128] + b1[tid], 0.f);
    __syncthreads();
  }
  {
    int j = tid & 63, q = tid >> 6;
    float acc = 0.f;
    const float* w = W2 + (size_t)q * 32 * 64 + j;
    const float* p = h1 + q * 32;
#pragma unroll 8
    for (int k = 0; k < 32; ++k) acc = fmaf(p[k], w[(size_t)k * 64], acc);
    part[tid] = acc;
    __syncthreads();
    if (tid < 64)
      h2[tid] = fmaxf(part[tid] + part[tid + 64] + part[tid + 128] + part[tid + 192] + b2[tid], 0.f);
    __syncthreads();
  }
  if (tid < 64) {
    float v = h2[tid] * W3[tid];
#pragma unroll
    for (int m = 32; m >= 1; m >>= 1) v += __shfl_xor(v, m);
    if (tid == 0) out[g] = v + b3[0];
  }
}

// ---------------------------------------------------------------------------

extern "C" void kernel_launch(void* const* d_in, const int* in_sizes, int n_in,
                              void* d_out, int out_size, void* d_ws, size_t ws_size,
                              hipStream_t stream) {
  const int N = in_sizes[2];       // 100000
  const int E = in_sizes[1] / 2;   // 1000000
  const int G = 64, H = 128, D = 64, L = 3;
  (void)n_in; (void)ws_size; (void)D; (void)out_size;

  const float* kernel_x = (const float*)d_in[0];
  const int* kernel_ei  = (const int*)d_in[1];
  const int* kernel_b   = (const int*)d_in[2];
  const float* design_x = (const float*)d_in[3];
  const int* design_ei  = (const int*)d_in[4];
  const int* design_b   = (const int*)d_in[5];
  const float* encW  = (const float*)d_in[7];
  const float* encB  = (const float*)d_in[8];
  const float* convW = (const float*)d_in[9];
  const float* convB = (const float*)d_in[10];
  const float* lnw   = (const float*)d_in[11];
  const float* lnb   = (const float*)d_in[12];
  const float* W1 = (const float*)d_in[13];
  const float* b1 = (const float*)d_in[14];
  const float* W2 = (const float*)d_in[15];
  const float* b2 = (const float*)d_in[16];
  const float* W3 = (const float*)d_in[17];
  const float* b3 = (const float*)d_in[18];
  float* out = (float*)d_out;

  // workspace carve-up
  char* ws = (char*)d_ws;
  size_t off = 0;
  auto alloc = [&](size_t bytes) -> void* {
    void* p = ws + off;
    off = (off + bytes + 511) & ~(size_t)511;
    return p;
  };
  float* bufA            = (float*)alloc((size_t)N * H * 4);          // aggregate out (f32)
  unsigned short* bufB   = (unsigned short*)alloc((size_t)N * H * 2); // xw (bf16); aliases xb
  unsigned short* hb     = (unsigned short*)alloc((size_t)N * H * 2); // hidden (bf16)
  float* dinv    = (float*)alloc((size_t)N * 4);
  int* cntI      = (int*)alloc((size_t)N * 4);
  int* rowptr    = (int*)alloc((size_t)(N + 1) * 4);
  int* cursor    = (int*)alloc((size_t)N * 4);
  int* csr_src   = (int*)alloc((size_t)E * 4);
  int* gstart    = (int*)alloc((size_t)(G + 1) * 4);
  float* rowsum  = (float*)alloc((size_t)N * 4);
  float* rowsumsq= (float*)alloc((size_t)N * 4);
  float* meanA   = (float*)alloc((size_t)G * 4);
  float* rsigA   = (float*)alloc((size_t)G * 4);
  float* pooled  = (float*)alloc((size_t)G * 2 * H * 4);
  int* bsum      = (int*)alloc(512 * 4);
  int* bpre      = (int*)alloc(512 * 4);
  unsigned short* encWt  = (unsigned short*)alloc((size_t)128 * 64 * 2);
  unsigned short* convWt = (unsigned short*)alloc((size_t)L * 128 * 128 * 2);

  unsigned short* xb = bufB;  // x in bf16 lives in bufB until conv gemm 0 overwrites it

  const int gN    = (N + TPB - 1) / TPB;
  const int gE    = (E + TPB - 1) / TPB;
  const int gGemm = (N + 127) / 128;
  const int gAgg  = (N + 3) / 4;
  const int gLn   = (N * 32 + TPB - 1) / TPB;
  const int P     = (N + 511) / 512;  // scan blocks (<=256)

  // weights: transpose+convert once
  transp_cvt_k<<<(64 * 128 + TPB - 1) / TPB, TPB, 0, stream>>>(encW, encWt, 64, 128);
  for (int i = 0; i < L; ++i)
    transp_cvt_k<<<(128 * 128 + TPB - 1) / TPB, TPB, 0, stream>>>(
        convW + (size_t)i * H * H, convWt + (size_t)i * H * H, 128, 128);

  hipMemsetAsync(pooled, 0, (size_t)G * 2 * H * 4, stream);

  struct GraphIn { const float* x; const int* ei; const int* batch; int colofs; };
  GraphIn graphs[2] = {
      {kernel_x, kernel_ei, kernel_b, 0},
      {design_x, design_ei, design_b, H},
  };

  for (int gi = 0; gi < 2; ++gi) {
    const float* x = graphs[gi].x;
    const int* esrc = graphs[gi].ei;
    const int* edst = graphs[gi].ei + E;
    const int* batch = graphs[gi].batch;
    int colofs = graphs[gi].colofs;

    // x -> bf16 (into bufB; consumed by enc gemm before conv gemm overwrites)
    cvt_x_k<<<(N * 16 + TPB - 1) / TPB, TPB, 0, stream>>>(
        (const float4*)x, (ushort4*)xb, N * 16);

    // graph structure
    hipMemsetAsync(cntI, 0, (size_t)N * 4, stream);
    count_dst_k<<<gE, TPB, 0, stream>>>(edst, cntI, E);
    dinv_k<<<gN, TPB, 0, stream>>>(cntI, dinv, N);
    gbounds_k<<<gN, TPB, 0, stream>>>(batch, gstart, N, G);
    scan_partial_k<<<P, TPB, 0, stream>>>(cntI, bsum, N);
    scan_small_k<<<1, TPB, 0, stream>>>(bsum, bpre, P, rowptr, N);
    scan_fill_k<<<P, TPB, 0, stream>>>(cntI, bpre, rowptr, N);
    hipMemcpyAsync(cursor, rowptr, (size_t)N * 4, hipMemcpyDeviceToDevice, stream);
    csrfill_k<<<gE, TPB, 0, stream>>>(esrc, edst, cursor, csr_src, E);

    // encoder: hb = bf16(x @ encW + encB)
    mfma_gemm_k<64, true><<<gGemm, TPB, 0, stream>>>(xb, encWt, encB, hb, N);

    for (int i = 0; i < L; ++i) {
      // xw = hb @ convW[i] -> bufB (bf16)
      mfma_gemm_k<128, false><<<gGemm, TPB, 0, stream>>>(
          hb, convWt + (size_t)i * H * H, nullptr, bufB, N);
      // aggregate + self-loop + bias + row stats -> bufA (f32)
      aggregate_k<<<gAgg, TPB, 0, stream>>>((const ushort2*)bufB, rowptr, csr_src, dinv,
                                            convB + (size_t)i * H, (float2*)bufA,
                                            rowsum, rowsumsq, N);
      gstats_k<<<G, TPB, 0, stream>>>(rowsum, rowsumsq, gstart, meanA, rsigA);
      ln_apply_k<<<gLn, TPB, 0, stream>>>((const float4*)bufA, batch, meanA, rsigA,
                                          (const float4*)(lnw + (size_t)i * H),
                                          (const float4*)(lnb + (size_t)i * H),
                                          (ushort4*)hb, N, (i < L - 1) ? 1 : 0);
    }
    pool_k<<<G * 8, 128, 0, stream>>>(hb, gstart, pooled, colofs);
  }

  head_k<<<G, TPB, 0, stream>>>(pooled, W1, b1, W2, b2, W3, b3, out);
}

// Round 4
// 878.254 us; speedup vs baseline: 2.6739x; 1.4984x over previous
//
#include <hip/hip_runtime.h>

// ---------------------------------------------------------------------------
// SimpleDifferentialGNN: 2x GCN encoder + global_add_pool + MLP head.
// N=100000, E=1000000, G=64, D=64, H=128, L=3
// R3: aggregate de-latency-ized (dinv folded into GEMM epilogue; csr indices
//     batched via shfl; 4-way independent gathers; bf16 output).
//     LN+ReLU fused into next GEMM's A-staging; final LN folded into head.
// ---------------------------------------------------------------------------

#define TPB 256

typedef __attribute__((ext_vector_type(8))) short bf16x8;
typedef __attribute__((ext_vector_type(4))) float f32x4;

__device__ __forceinline__ float bf2f(unsigned short s) {
  unsigned int u = ((unsigned int)s) << 16;
  float f;
  __builtin_memcpy(&f, &u, 4);
  return f;
}

__device__ __forceinline__ unsigned short f2bf(float f) {
  unsigned int u;
  __builtin_memcpy(&u, &f, 4);
  u = (u + 0x7FFF + ((u >> 16) & 1)) >> 16;  // RNE
  return (unsigned short)u;
}

// ---------------- small utility kernels ----------------

__global__ __launch_bounds__(TPB) void count_dst_k(const int* __restrict__ dst,
                                                   int* __restrict__ cnt, int E) {
  int e = blockIdx.x * TPB + threadIdx.x;
  if (e < E) atomicAdd(&cnt[dst[e]], 1);
}

__global__ __launch_bounds__(TPB) void dinv_k(const int* __restrict__ cnt,
                                              float* __restrict__ dinv, int n) {
  int i = blockIdx.x * TPB + threadIdx.x;
  if (i < n) dinv[i] = 1.0f / sqrtf((float)cnt[i] + 1.0f);
}

__global__ __launch_bounds__(TPB) void gbounds_k(const int* __restrict__ batch,
                                                 int* __restrict__ gstart, int n, int G) {
  int i = blockIdx.x * TPB + threadIdx.x;
  if (i >= n) return;
  int b = batch[i];
  if (i == 0) {
    for (int g = 0; g <= b; ++g) gstart[g] = 0;
  } else {
    int pb = batch[i - 1];
    for (int g = pb + 1; g <= b; ++g) gstart[g] = i;
  }
  if (i == n - 1) {
    for (int g = b + 1; g <= G; ++g) gstart[g] = n;
  }
}

// ---------------- multi-block exclusive scan ----------------

__global__ __launch_bounds__(TPB) void scan_partial_k(const int* __restrict__ cnt,
                                                      int* __restrict__ bsum, int n) {
  __shared__ int sd[TPB];
  int t = threadIdx.x, i0 = blockIdx.x * 512 + t * 2;
  int s = 0;
  if (i0 < n) s += cnt[i0];
  if (i0 + 1 < n) s += cnt[i0 + 1];
  sd[t] = s;
  __syncthreads();
  for (int st = TPB / 2; st > 0; st >>= 1) {
    if (t < st) sd[t] += sd[t + st];
    __syncthreads();
  }
  if (t == 0) bsum[blockIdx.x] = sd[0];
}

__global__ __launch_bounds__(TPB) void scan_small_k(const int* __restrict__ bsum,
                                                    int* __restrict__ bpre, int P,
                                                    int* __restrict__ rowptr, int n) {
  __shared__ int sd[TPB];
  int t = threadIdx.x;
  int v = (t < P) ? bsum[t] : 0;
  sd[t] = v;
  __syncthreads();
  for (int d = 1; d < TPB; d <<= 1) {
    int w = (t >= d) ? sd[t - d] : 0;
    __syncthreads();
    sd[t] += w;
    __syncthreads();
  }
  if (t < P) bpre[t] = sd[t] - v;
  if (t == TPB - 1) rowptr[n] = sd[TPB - 1];
}

__global__ __launch_bounds__(TPB) void scan_fill_k(const int* __restrict__ cnt,
                                                   const int* __restrict__ bpre,
                                                   int* __restrict__ rowptr, int n) {
  __shared__ int sd[TPB];
  int t = threadIdx.x, i0 = blockIdx.x * 512 + t * 2;
  int c0 = (i0 < n) ? cnt[i0] : 0;
  int c1 = (i0 + 1 < n) ? cnt[i0 + 1] : 0;
  int s = c0 + c1;
  sd[t] = s;
  __syncthreads();
  for (int d = 1; d < TPB; d <<= 1) {
    int w = (t >= d) ? sd[t - d] : 0;
    __syncthreads();
    sd[t] += w;
    __syncthreads();
  }
  int ex = sd[t] - s + bpre[blockIdx.x];
  if (i0 < n) rowptr[i0] = ex;
  if (i0 + 1 < n) rowptr[i0 + 1] = ex + c0;
}

__global__ __launch_bounds__(TPB) void csrfill_k(const int* __restrict__ esrc,
                                                 const int* __restrict__ edst,
                                                 int* __restrict__ cursor,
                                                 int* __restrict__ csr_src, int E) {
  int e = blockIdx.x * TPB + threadIdx.x;
  if (e >= E) return;
  int d = edst[e];
  int p = atomicAdd(&cursor[d], 1);
  csr_src[p] = esrc[e];
}

// ---------------- dtype prep ----------------

__global__ __launch_bounds__(TPB) void cvt_x_k(const float4* __restrict__ src,
                                               ushort4* __restrict__ dst, int n4) {
  int i = blockIdx.x * TPB + threadIdx.x;
  if (i >= n4) return;
  float4 v = src[i];
  ushort4 o;
  o.x = f2bf(v.x); o.y = f2bf(v.y); o.z = f2bf(v.z); o.w = f2bf(v.w);
  dst[i] = o;
}

// W [K][C] f32 -> Wt [C][K] bf16
__global__ __launch_bounds__(TPB) void transp_cvt_k(const float* __restrict__ src,
                                                    unsigned short* __restrict__ dst,
                                                    int K, int C) {
  int idx = blockIdx.x * TPB + threadIdx.x;
  if (idx >= K * C) return;
  int k = idx / C, c = idx % C;
  dst[c * K + k] = f2bf(src[idx]);
}

// ---------------- MFMA GEMM with optional fused input-LN+ReLU and output
// dinv-scaling.  A: [nrows][K] bf16.  Wt: [128][K] bf16 (pre-transposed).
// Block 256 thr = 4 waves; tile 128x128; whole K in LDS, XOR-swizzled.

template <int K, bool BIAS, bool LNRELU, bool SCALE>
__global__ __launch_bounds__(TPB) void mfma_gemm_k(
    const unsigned short* __restrict__ A, const unsigned short* __restrict__ Wt,
    const float* __restrict__ bias, unsigned short* __restrict__ C, int nrows,
    const int* __restrict__ batch, const float* __restrict__ meanA,
    const float* __restrict__ rsigA, const float* __restrict__ lnw,
    const float* __restrict__ lnb, const float* __restrict__ dinv) {
  __shared__ short As[128 * K];
  __shared__ short Bs[128 * K];
  const int tid = threadIdx.x;
  const int r0 = blockIdx.x << 7;
  const int lane = tid & 63;
  const int wv = tid >> 6;
  const int lr = lane & 15, lg = lane >> 4;
  constexpr int CPR = K / 8;

  for (int i = tid; i < 128 * CPR; i += TPB) {
    int rloc = i / CPR, cb = i % CPR;
    int r = r0 + rloc;
    bf16x8 v = {0, 0, 0, 0, 0, 0, 0, 0};
    if (r < nrows) {
      v = *(const bf16x8*)(A + (long)r * K + cb * 8);
      if (LNRELU) {
        int g = batch[r];
        float m = meanA[g], rs = rsigA[g];
        int c0 = cb * 8;
#pragma unroll
        for (int j = 0; j < 8; ++j) {
          float f = bf2f((unsigned short)v[j]);
          f = (f - m) * rs * lnw[c0 + j] + lnb[c0 + j];
          f = fmaxf(f, 0.f);
          v[j] = (short)f2bf(f);
        }
      }
    }
    int sb = cb ^ (rloc & 7);
    *(bf16x8*)(&As[rloc * K + sb * 8]) = v;
  }
  for (int i = tid; i < 128 * CPR; i += TPB) {
    int rloc = i / CPR, cb = i % CPR;
    bf16x8 v = *(const bf16x8*)(Wt + (long)rloc * K + cb * 8);
    int sb = cb ^ (rloc & 7);
    *(bf16x8*)(&Bs[rloc * K + sb * 8]) = v;
  }
  __syncthreads();

  f32x4 acc[2][8];
#pragma unroll
  for (int m = 0; m < 2; ++m)
#pragma unroll
    for (int n = 0; n < 8; ++n) acc[m][n] = {0.f, 0.f, 0.f, 0.f};

  const int wrow = wv * 32;
#pragma unroll
  for (int k0 = 0; k0 < K; k0 += 32) {
    const int cbk = (k0 >> 3) + lg;
    bf16x8 a[2], b[8];
#pragma unroll
    for (int m = 0; m < 2; ++m) {
      int rr = wrow + m * 16 + lr;
      int sb = cbk ^ (rr & 7);
      a[m] = *(const bf16x8*)(&As[rr * K + sb * 8]);
    }
#pragma unroll
    for (int n = 0; n < 8; ++n) {
      int rr = n * 16 + lr;
      int sb = cbk ^ (rr & 7);
      b[n] = *(const bf16x8*)(&Bs[rr * K + sb * 8]);
    }
#pragma unroll
    for (int m = 0; m < 2; ++m)
#pragma unroll
      for (int n = 0; n < 8; ++n)
        acc[m][n] = __builtin_amdgcn_mfma_f32_16x16x32_bf16(a[m], b[n], acc[m][n], 0, 0, 0);
  }

  float bv[8];
#pragma unroll
  for (int n = 0; n < 8; ++n) bv[n] = BIAS ? bias[n * 16 + lr] : 0.f;
#pragma unroll
  for (int m = 0; m < 2; ++m) {
#pragma unroll
    for (int ri = 0; ri < 4; ++ri) {
      int r = r0 + wrow + m * 16 + lg * 4 + ri;
      if (r < nrows) {
        float dv = SCALE ? dinv[r] : 1.f;
#pragma unroll
        for (int n = 0; n < 8; ++n) {
          float v = acc[m][n][ri] + bv[n];
          if (SCALE) v *= dv;
          C[(long)r * 128 + n * 16 + lr] = f2bf(v);
        }
      }
    }
  }
}

// ---------------- aggregation ----------------
// xws already dinv-scaled: out[d] = dd*(xws[d] + sum_e xws[s]) + b
// one wave per node; lane holds 2 channels (uint = 2x bf16).
// csr indices batched per-64 via one coalesced load + shfl broadcast;
// 4-way unroll for independent gathers.

__global__ __launch_bounds__(TPB) void aggregate_k(
    const unsigned int* __restrict__ xws, const int* __restrict__ rowptr,
    const int* __restrict__ csr, const float* __restrict__ dinv,
    const float* __restrict__ bias, ushort2* __restrict__ outb,
    float* __restrict__ rowsum, float* __restrict__ rowsumsq, int n) {
  int wave = threadIdx.x >> 6, lane = threadIdx.x & 63;
  int d = (blockIdx.x << 2) + wave;
  if (d >= n) return;
  float dd = dinv[d];
  unsigned int v = xws[(long)d * 64 + lane];
  float ax = bf2f((unsigned short)(v & 0xffff));
  float ay = bf2f((unsigned short)(v >> 16));
  int p0 = rowptr[d], p1 = rowptr[d + 1];
  for (int base = p0; base < p1; base += 64) {
    int idx = base + lane;
    int sl = (idx < p1) ? csr[idx] : 0;
    int cnt = p1 - base;
    if (cnt > 64) cnt = 64;
    int e = 0;
    for (; e + 4 <= cnt; e += 4) {
      int s0 = __shfl(sl, e), s1 = __shfl(sl, e + 1);
      int s2 = __shfl(sl, e + 2), s3 = __shfl(sl, e + 3);
      unsigned int u0 = xws[(long)s0 * 64 + lane];
      unsigned int u1 = xws[(long)s1 * 64 + lane];
      unsigned int u2 = xws[(long)s2 * 64 + lane];
      unsigned int u3 = xws[(long)s3 * 64 + lane];
      ax += bf2f((unsigned short)(u0 & 0xffff)) + bf2f((unsigned short)(u1 & 0xffff)) +
            bf2f((unsigned short)(u2 & 0xffff)) + bf2f((unsigned short)(u3 & 0xffff));
      ay += bf2f((unsigned short)(u0 >> 16)) + bf2f((unsigned short)(u1 >> 16)) +
            bf2f((unsigned short)(u2 >> 16)) + bf2f((unsigned short)(u3 >> 16));
    }
    for (; e < cnt; ++e) {
      int s = __shfl(sl, e);
      unsigned int u = xws[(long)s * 64 + lane];
      ax += bf2f((unsigned short)(u & 0xffff));
      ay += bf2f((unsigned short)(u >> 16));
    }
  }
  const float2* b2 = (const float2*)bias;
  float2 bb = b2[lane];
  ax = ax * dd + bb.x;
  ay = ay * dd + bb.y;
  ushort2 ob;
  ob.x = f2bf(ax);
  ob.y = f2bf(ay);
  outb[(long)d * 64 + lane] = ob;
  float s1 = ax + ay;
  float s2 = ax * ax + ay * ay;
#pragma unroll
  for (int m = 32; m >= 1; m >>= 1) {
    s1 += __shfl_xor(s1, m);
    s2 += __shfl_xor(s2, m);
  }
  if (lane == 0) { rowsum[d] = s1; rowsumsq[d] = s2; }
}

// ---------------- per-graph LN stats (double accumulation) ----------------

__global__ __launch_bounds__(TPB) void gstats_k(const float* __restrict__ rowsum,
                                                const float* __restrict__ rowsumsq,
                                                const int* __restrict__ gstart,
                                                float* __restrict__ meanA,
                                                float* __restrict__ rsigA,
                                                float* __restrict__ cntA) {
  __shared__ double sd1[TPB], sd2[TPB];
  int g = blockIdx.x, t = threadIdx.x;
  int n0 = gstart[g], n1 = gstart[g + 1];
  double s1 = 0, s2 = 0;
  for (int i = n0 + t; i < n1; i += TPB) { s1 += rowsum[i]; s2 += rowsumsq[i]; }
  sd1[t] = s1; sd2[t] = s2;
  __syncthreads();
  for (int st = TPB / 2; st > 0; st >>= 1) {
    if (t < st) { sd1[t] += sd1[t + st]; sd2[t] += sd2[t + st]; }
    __syncthreads();
  }
  if (t == 0) {
    double cntd = (double)(n1 - n0) * 128.0;
    if (cntd > 0.0) {
      double mean = sd1[0] / cntd;
      double var = sd2[0] / cntd - mean * mean;
      if (var < 0.0) var = 0.0;
      meanA[g] = (float)mean;
      rsigA[g] = (float)(1.0 / sqrt(var + 1e-5));
    } else {
      meanA[g] = 0.f;
      rsigA[g] = 0.f;
    }
    cntA[g] = (float)(n1 - n0);
  }
}

// ---------------- global add pool: raw bf16 rows -> 8 deterministic partials --

__global__ __launch_bounds__(128) void pool_k(const unsigned short* __restrict__ x,
                                              const int* __restrict__ gstart,
                                              float* __restrict__ part) {
  int g = blockIdx.x >> 3, s = blockIdx.x & 7, j = threadIdx.x;
  int n0 = gstart[g], n1 = gstart[g + 1];
  float acc = 0.f;
  for (int nn = n0 + s; nn < n1; nn += 8) acc += bf2f(x[(long)nn * 128 + j]);
  part[((long)s * 64 + g) * 128 + j] = acc;
}

// ---------------- MLP head: one block per graph ----------------
// Applies the final graph-LN algebraically to the pooled raw sums:
// pooled_LN[j] = w2[j]*rsig*(S[j]-mean*cnt) + b2[j]*cnt

__global__ __launch_bounds__(TPB) void head_k(
    const float* __restrict__ partK, const float* __restrict__ partD,
    const float* __restrict__ meanF, const float* __restrict__ rsigF,
    const float* __restrict__ cntF, const float* __restrict__ lnw2,
    const float* __restrict__ lnb2, const float* __restrict__ W1,
    const float* __restrict__ b1, const float* __restrict__ W2,
    const float* __restrict__ b2, const float* __restrict__ W3,
    const float* __restrict__ b3, float* __restrict__ out) {
  __shared__ float ps[256];
  __shared__ float part[256];
  __shared__ float h1[128];
  __shared__ float h2[64];
  int g = blockIdx.x, tid = threadIdx.x;
  {
    int j = tid & 127, side = tid >> 7;
    const float* pp = side ? partD : partK;
    float S = 0.f;
#pragma unroll
    for (int s = 0; s < 8; ++s) S += pp[((long)s * 64 + g) * 128 + j];
    float m = meanF[side * 64 + g], r = rsigF[side * 64 + g], c = cntF[side * 64 + g];
    ps[tid] = lnw2[j] * r * (S - m * c) + lnb2[j] * c;
  }
  __syncthreads();
  {
    int j = tid & 127, half = tid >> 7;
    float acc = 0.f;
    const float* w = W1 + (size_t)half * 128 * 128 + j;
    const float* p = ps + half * 128;
#pragma unroll 8
    for (int k = 0; k < 128; ++k) acc = fmaf(p[k], w[(size_t)k * 128], acc);
    part[tid] = acc;
    __syncthreads();
    if (tid < 128) h1[tid] = fmaxf(part[tid] + part[tid + 128] + b1[tid], 0.f);
    __syncthreads();
  }
  {
    int j = tid & 63, q = tid >> 6;
    float acc = 0.f;
    const float* w = W2 + (size_t)q * 32 * 64 + j;
    const float* p = h1 + q * 32;
#pragma unroll 8
    for (int k = 0; k < 32; ++k) acc = fmaf(p[k], w[(size_t)k * 64], acc);
    part[tid] = acc;
    __syncthreads();
    if (tid < 64)
      h2[tid] = fmaxf(part[tid] + part[tid + 64] + part[tid + 128] + part[tid + 192] + b2[tid], 0.f);
    __syncthreads();
  }
  if (tid < 64) {
    float v = h2[tid] * W3[tid];
#pragma unroll
    for (int m = 32; m >= 1; m >>= 1) v += __shfl_xor(v, m);
    if (tid == 0) out[g] = v + b3[0];
  }
}

// ---------------------------------------------------------------------------

extern "C" void kernel_launch(void* const* d_in, const int* in_sizes, int n_in,
                              void* d_out, int out_size, void* d_ws, size_t ws_size,
                              hipStream_t stream) {
  const int N = in_sizes[2];       // 100000
  const int E = in_sizes[1] / 2;   // 1000000
  const int G = 64, H = 128, D = 64, L = 3;
  (void)n_in; (void)ws_size; (void)D; (void)out_size;

  const float* kernel_x = (const float*)d_in[0];
  const int* kernel_ei  = (const int*)d_in[1];
  const int* kernel_b   = (const int*)d_in[2];
  const float* design_x = (const float*)d_in[3];
  const int* design_ei  = (const int*)d_in[4];
  const int* design_b   = (const int*)d_in[5];
  const float* encW  = (const float*)d_in[7];
  const float* encB  = (const float*)d_in[8];
  const float* convW = (const float*)d_in[9];
  const float* convB = (const float*)d_in[10];
  const float* lnw   = (const float*)d_in[11];
  const float* lnb   = (const float*)d_in[12];
  const float* W1 = (const float*)d_in[13];
  const float* b1 = (const float*)d_in[14];
  const float* W2 = (const float*)d_in[15];
  const float* b2 = (const float*)d_in[16];
  const float* W3 = (const float*)d_in[17];
  const float* b3 = (const float*)d_in[18];
  float* out = (float*)d_out;

  char* ws = (char*)d_ws;
  size_t off = 0;
  auto alloc = [&](size_t bytes) -> void* {
    void* p = ws + off;
    off = (off + bytes + 511) & ~(size_t)511;
    return p;
  };
  unsigned short* hb   = (unsigned short*)alloc((size_t)N * H * 2);  // enc out
  unsigned short* bufX = (unsigned short*)alloc((size_t)N * H * 2);  // xws
  unsigned short* bufY = (unsigned short*)alloc((size_t)N * H * 2);  // agg out
  unsigned short* xb   = (unsigned short*)alloc((size_t)N * 64 * 2); // x bf16
  float* dinv    = (float*)alloc((size_t)N * 4);
  int* cntI      = (int*)alloc((size_t)N * 4);
  int* rowptr    = (int*)alloc((size_t)(N + 1) * 4);
  int* cursor    = (int*)alloc((size_t)N * 4);
  int* csr_src   = (int*)alloc((size_t)E * 4);
  int* gstart    = (int*)alloc((size_t)(G + 1) * 4);
  float* rowsum  = (float*)alloc((size_t)N * 4);
  float* rowsumsq= (float*)alloc((size_t)N * 4);
  float* meanS   = (float*)alloc((size_t)G * 4);   // scratch stats (layers 0,1)
  float* rsigS   = (float*)alloc((size_t)G * 4);
  float* cntS    = (float*)alloc((size_t)G * 4);
  float* meanF   = (float*)alloc((size_t)2 * G * 4);  // final-layer stats per side
  float* rsigF   = (float*)alloc((size_t)2 * G * 4);
  float* cntF    = (float*)alloc((size_t)2 * G * 4);
  float* partK   = (float*)alloc((size_t)8 * G * 128 * 4);
  float* partD   = (float*)alloc((size_t)8 * G * 128 * 4);
  int* bsum      = (int*)alloc(512 * 4);
  int* bpre      = (int*)alloc(512 * 4);
  unsigned short* encWt  = (unsigned short*)alloc((size_t)128 * 64 * 2);
  unsigned short* convWt = (unsigned short*)alloc((size_t)L * 128 * 128 * 2);

  const int gN    = (N + TPB - 1) / TPB;
  const int gE    = (E + TPB - 1) / TPB;
  const int gGemm = (N + 127) / 128;
  const int gAgg  = (N + 3) / 4;
  const int P     = (N + 511) / 512;

  transp_cvt_k<<<(64 * 128 + TPB - 1) / TPB, TPB, 0, stream>>>(encW, encWt, 64, 128);
  for (int i = 0; i < L; ++i)
    transp_cvt_k<<<(128 * 128 + TPB - 1) / TPB, TPB, 0, stream>>>(
        convW + (size_t)i * H * H, convWt + (size_t)i * H * H, 128, 128);

  struct GraphIn { const float* x; const int* ei; const int* batch; };
  GraphIn graphs[2] = {
      {kernel_x, kernel_ei, kernel_b},
      {design_x, design_ei, design_b},
  };

  for (int gi = 0; gi < 2; ++gi) {
    const float* x = graphs[gi].x;
    const int* esrc = graphs[gi].ei;
    const int* edst = graphs[gi].ei + E;
    const int* batch = graphs[gi].batch;

    cvt_x_k<<<(N * 16 + TPB - 1) / TPB, TPB, 0, stream>>>(
        (const float4*)x, (ushort4*)xb, N * 16);

    hipMemsetAsync(cntI, 0, (size_t)N * 4, stream);
    count_dst_k<<<gE, TPB, 0, stream>>>(edst, cntI, E);
    dinv_k<<<gN, TPB, 0, stream>>>(cntI, dinv, N);
    gbounds_k<<<gN, TPB, 0, stream>>>(batch, gstart, N, G);
    scan_partial_k<<<P, TPB, 0, stream>>>(cntI, bsum, N);
    scan_small_k<<<1, TPB, 0, stream>>>(bsum, bpre, P, rowptr, N);
    scan_fill_k<<<P, TPB, 0, stream>>>(cntI, bpre, rowptr, N);
    hipMemcpyAsync(cursor, rowptr, (size_t)N * 4, hipMemcpyDeviceToDevice, stream);
    csrfill_k<<<gE, TPB, 0, stream>>>(esrc, edst, cursor, csr_src, E);

    // encoder: hb = bf16(x @ encW + encB)
    mfma_gemm_k<64, true, false, false><<<gGemm, TPB, 0, stream>>>(
        xb, encWt, encB, hb, N, nullptr, nullptr, nullptr, nullptr, nullptr, nullptr);

    for (int i = 0; i < L; ++i) {
      const unsigned short* src = (i == 0) ? hb : bufY;
      float* mS = (i == L - 1) ? meanF + gi * G : meanS;
      float* rS = (i == L - 1) ? rsigF + gi * G : rsigS;
      float* cS = (i == L - 1) ? cntF + gi * G : cntS;
      // xws = LN?(src) @ convW[i] * dinv  -> bufX (bf16)
      if (i == 0)
        mfma_gemm_k<128, false, false, true><<<gGemm, TPB, 0, stream>>>(
            src, convWt + (size_t)i * H * H, nullptr, bufX, N,
            nullptr, nullptr, nullptr, nullptr, nullptr, dinv);
      else
        mfma_gemm_k<128, false, true, true><<<gGemm, TPB, 0, stream>>>(
            src, convWt + (size_t)i * H * H, nullptr, bufX, N,
            batch, meanS, rsigS, lnw + (size_t)(i - 1) * H,
            lnb + (size_t)(i - 1) * H, dinv);
      // aggregate -> bufY (bf16) + row stats
      aggregate_k<<<gAgg, TPB, 0, stream>>>((const unsigned int*)bufX, rowptr, csr_src,
                                            dinv, convB + (size_t)i * H,
                                            (ushort2*)bufY, rowsum, rowsumsq, N);
      gstats_k<<<G, TPB, 0, stream>>>(rowsum, rowsumsq, gstart, mS, rS, cS);
    }
    pool_k<<<G * 8, 128, 0, stream>>>(bufY, gstart, gi ? partD : partK);
  }

  head_k<<<G, TPB, 0, stream>>>(partK, partD, meanF, rsigF, cntF,
                                lnw + (size_t)(L - 1) * H, lnb + (size_t)(L - 1) * H,
                                W1, b1, W2, b2, W3, b3, out);
}

// Round 5
// 837.554 us; speedup vs baseline: 2.8038x; 1.0486x over previous
//
#include <hip/hip_runtime.h>

// ---------------------------------------------------------------------------
// SimpleDifferentialGNN: 2x GCN encoder + global_add_pool + MLP head.
// N=100000, E=1000000, G=64, D=64, H=128, L=3
// R4: csrfill XCD-range-filtered (writes stay in one XCD L2 -> no partial-line
//     writeback amplification); enc GEMM reads f32 x directly; dinv+gbounds
//     fused; cursor folded into scan_fill; aggregate 8-wide gather unroll.
// ---------------------------------------------------------------------------

#define TPB 256
#define FILL_CHUNK 2048

typedef __attribute__((ext_vector_type(8))) short bf16x8;
typedef __attribute__((ext_vector_type(4))) float f32x4;

__device__ __forceinline__ float bf2f(unsigned short s) {
  unsigned int u = ((unsigned int)s) << 16;
  float f;
  __builtin_memcpy(&f, &u, 4);
  return f;
}

__device__ __forceinline__ unsigned short f2bf(float f) {
  unsigned int u;
  __builtin_memcpy(&u, &f, 4);
  u = (u + 0x7FFF + ((u >> 16) & 1)) >> 16;  // RNE
  return (unsigned short)u;
}

// ---------------- small utility kernels ----------------

__global__ __launch_bounds__(TPB) void count_dst_k(const int* __restrict__ dst,
                                                   int* __restrict__ cnt, int E) {
  int e = blockIdx.x * TPB + threadIdx.x;
  if (e < E) atomicAdd(&cnt[dst[e]], 1);
}

// dinv + graph boundaries in one node pass
__global__ __launch_bounds__(TPB) void prep_node_k(const int* __restrict__ cnt,
                                                   float* __restrict__ dinv,
                                                   const int* __restrict__ batch,
                                                   int* __restrict__ gstart, int n, int G) {
  int i = blockIdx.x * TPB + threadIdx.x;
  if (i >= n) return;
  dinv[i] = 1.0f / sqrtf((float)cnt[i] + 1.0f);
  int b = batch[i];
  if (i == 0) {
    for (int g = 0; g <= b; ++g) gstart[g] = 0;
  } else {
    int pb = batch[i - 1];
    for (int g = pb + 1; g <= b; ++g) gstart[g] = i;
  }
  if (i == n - 1) {
    for (int g = b + 1; g <= G; ++g) gstart[g] = n;
  }
}

// ---------------- multi-block exclusive scan ----------------

__global__ __launch_bounds__(TPB) void scan_partial_k(const int* __restrict__ cnt,
                                                      int* __restrict__ bsum, int n) {
  __shared__ int sd[TPB];
  int t = threadIdx.x, i0 = blockIdx.x * 512 + t * 2;
  int s = 0;
  if (i0 < n) s += cnt[i0];
  if (i0 + 1 < n) s += cnt[i0 + 1];
  sd[t] = s;
  __syncthreads();
  for (int st = TPB / 2; st > 0; st >>= 1) {
    if (t < st) sd[t] += sd[t + st];
    __syncthreads();
  }
  if (t == 0) bsum[blockIdx.x] = sd[0];
}

__global__ __launch_bounds__(TPB) void scan_small_k(const int* __restrict__ bsum,
                                                    int* __restrict__ bpre, int P,
                                                    int* __restrict__ rowptr, int n) {
  __shared__ int sd[TPB];
  int t = threadIdx.x;
  int v = (t < P) ? bsum[t] : 0;
  sd[t] = v;
  __syncthreads();
  for (int d = 1; d < TPB; d <<= 1) {
    int w = (t >= d) ? sd[t - d] : 0;
    __syncthreads();
    sd[t] += w;
    __syncthreads();
  }
  if (t < P) bpre[t] = sd[t] - v;
  if (t == TPB - 1) rowptr[n] = sd[TPB - 1];
}

// fills rowptr AND cursor (identical) — saves the d2d copy
__global__ __launch_bounds__(TPB) void scan_fill_k(const int* __restrict__ cnt,
                                                   const int* __restrict__ bpre,
                                                   int* __restrict__ rowptr,
                                                   int* __restrict__ cursor, int n) {
  __shared__ int sd[TPB];
  int t = threadIdx.x, i0 = blockIdx.x * 512 + t * 2;
  int c0 = (i0 < n) ? cnt[i0] : 0;
  int c1 = (i0 + 1 < n) ? cnt[i0 + 1] : 0;
  int s = c0 + c1;
  sd[t] = s;
  __syncthreads();
  for (int d = 1; d < TPB; d <<= 1) {
    int w = (t >= d) ? sd[t - d] : 0;
    __syncthreads();
    sd[t] += w;
    __syncthreads();
  }
  int ex = sd[t] - s + bpre[blockIdx.x];
  if (i0 < n) { rowptr[i0] = ex; cursor[i0] = ex; }
  if (i0 + 1 < n) { rowptr[i0 + 1] = ex + c0; cursor[i0 + 1] = ex + c0; }
}

// ---------------- CSR fill, XCD-range filtered ----------------
// Block b handles edges in chunk (b>>3) whose dst lies in node-range (b&7).
// Under round-robin block->XCD dispatch, all writes to a csr line then come
// from one XCD's L2 -> full-line writebacks (kills 16x write amplification).

__global__ __launch_bounds__(TPB) void csrfill_k(const int* __restrict__ esrc,
                                                 const int* __restrict__ edst,
                                                 int* __restrict__ cursor,
                                                 int* __restrict__ csr_src, int E, int n) {
  int range = blockIdx.x & 7;
  int chunk = blockIdx.x >> 3;
  int nper = (n + 7) >> 3;
  int lo = range * nper;
  int hi = lo + nper; if (hi > n) hi = n;
  int base = chunk * FILL_CHUNK;
  int end = base + FILL_CHUNK; if (end > E) end = E;
  for (int e = base + threadIdx.x; e < end; e += TPB) {
    int d = edst[e];
    if (d >= lo && d < hi) {
      int p = atomicAdd(&cursor[d], 1);
      csr_src[p] = esrc[e];
    }
  }
}

// ---------------- dtype prep ----------------

// W [K][C] f32 -> Wt [C][K] bf16
__global__ __launch_bounds__(TPB) void transp_cvt_k(const float* __restrict__ src,
                                                    unsigned short* __restrict__ dst,
                                                    int K, int C) {
  int idx = blockIdx.x * TPB + threadIdx.x;
  if (idx >= K * C) return;
  int k = idx / C, c = idx % C;
  dst[c * K + k] = f2bf(src[idx]);
}

// ---------------- MFMA GEMM ----------------
// A: [nrows][K] (bf16, or f32 if F32IN) -> LDS bf16, XOR-swizzled.
// Wt: [128][K] bf16.  Optional fused input-LN+ReLU, output dinv-scale.

template <int K, bool BIAS, bool LNRELU, bool SCALE, bool F32IN>
__global__ __launch_bounds__(TPB) void mfma_gemm_k(
    const void* __restrict__ Av, const unsigned short* __restrict__ Wt,
    const float* __restrict__ bias, unsigned short* __restrict__ C, int nrows,
    const int* __restrict__ batch, const float* __restrict__ meanA,
    const float* __restrict__ rsigA, const float* __restrict__ lnw,
    const float* __restrict__ lnb, const float* __restrict__ dinv) {
  __shared__ short As[128 * K];
  __shared__ short Bs[128 * K];
  const int tid = threadIdx.x;
  const int r0 = blockIdx.x << 7;
  const int lane = tid & 63;
  const int wv = tid >> 6;
  const int lr = lane & 15, lg = lane >> 4;
  constexpr int CPR = K / 8;

  for (int i = tid; i < 128 * CPR; i += TPB) {
    int rloc = i / CPR, cb = i % CPR;
    int r = r0 + rloc;
    bf16x8 v = {0, 0, 0, 0, 0, 0, 0, 0};
    if (r < nrows) {
      if (F32IN) {
        const float* Af = ((const float*)Av) + (long)r * K + cb * 8;
        float4 f0 = *(const float4*)Af;
        float4 f1 = *(const float4*)(Af + 4);
        v[0] = (short)f2bf(f0.x); v[1] = (short)f2bf(f0.y);
        v[2] = (short)f2bf(f0.z); v[3] = (short)f2bf(f0.w);
        v[4] = (short)f2bf(f1.x); v[5] = (short)f2bf(f1.y);
        v[6] = (short)f2bf(f1.z); v[7] = (short)f2bf(f1.w);
      } else {
        v = *(const bf16x8*)(((const unsigned short*)Av) + (long)r * K + cb * 8);
        if (LNRELU) {
          int g = batch[r];
          float m = meanA[g], rs = rsigA[g];
          int c0 = cb * 8;
#pragma unroll
          for (int j = 0; j < 8; ++j) {
            float f = bf2f((unsigned short)v[j]);
            f = (f - m) * rs * lnw[c0 + j] + lnb[c0 + j];
            f = fmaxf(f, 0.f);
            v[j] = (short)f2bf(f);
          }
        }
      }
    }
    int sb = cb ^ (rloc & 7);
    *(bf16x8*)(&As[rloc * K + sb * 8]) = v;
  }
  for (int i = tid; i < 128 * CPR; i += TPB) {
    int rloc = i / CPR, cb = i % CPR;
    bf16x8 v = *(const bf16x8*)(Wt + (long)rloc * K + cb * 8);
    int sb = cb ^ (rloc & 7);
    *(bf16x8*)(&Bs[rloc * K + sb * 8]) = v;
  }
  __syncthreads();

  f32x4 acc[2][8];
#pragma unroll
  for (int m = 0; m < 2; ++m)
#pragma unroll
    for (int n = 0; n < 8; ++n) acc[m][n] = {0.f, 0.f, 0.f, 0.f};

  const int wrow = wv * 32;
#pragma unroll
  for (int k0 = 0; k0 < K; k0 += 32) {
    const int cbk = (k0 >> 3) + lg;
    bf16x8 a[2], b[8];
#pragma unroll
    for (int m = 0; m < 2; ++m) {
      int rr = wrow + m * 16 + lr;
      int sb = cbk ^ (rr & 7);
      a[m] = *(const bf16x8*)(&As[rr * K + sb * 8]);
    }
#pragma unroll
    for (int n = 0; n < 8; ++n) {
      int rr = n * 16 + lr;
      int sb = cbk ^ (rr & 7);
      b[n] = *(const bf16x8*)(&Bs[rr * K + sb * 8]);
    }
#pragma unroll
    for (int m = 0; m < 2; ++m)
#pragma unroll
      for (int n = 0; n < 8; ++n)
        acc[m][n] = __builtin_amdgcn_mfma_f32_16x16x32_bf16(a[m], b[n], acc[m][n], 0, 0, 0);
  }

  float bv[8];
#pragma unroll
  for (int n = 0; n < 8; ++n) bv[n] = BIAS ? bias[n * 16 + lr] : 0.f;
#pragma unroll
  for (int m = 0; m < 2; ++m) {
#pragma unroll
    for (int ri = 0; ri < 4; ++ri) {
      int r = r0 + wrow + m * 16 + lg * 4 + ri;
      if (r < nrows) {
        float dv = SCALE ? dinv[r] : 1.f;
#pragma unroll
        for (int n = 0; n < 8; ++n) {
          float v = acc[m][n][ri] + bv[n];
          if (SCALE) v *= dv;
          C[(long)r * 128 + n * 16 + lr] = f2bf(v);
        }
      }
    }
  }
}

// ---------------- aggregation ----------------
// xws already dinv-scaled: out[d] = dd*(xws[d] + sum_e xws[s]) + b
// one wave per node; lane holds 2 channels (uint = 2x bf16);
// csr batch via coalesced load + shfl broadcast; 8-wide independent gathers.

__global__ __launch_bounds__(TPB) void aggregate_k(
    const unsigned int* __restrict__ xws, const int* __restrict__ rowptr,
    const int* __restrict__ csr, const float* __restrict__ dinv,
    const float* __restrict__ bias, ushort2* __restrict__ outb,
    float* __restrict__ rowsum, float* __restrict__ rowsumsq, int n) {
  int wave = threadIdx.x >> 6, lane = threadIdx.x & 63;
  int d = (blockIdx.x << 2) + wave;
  if (d >= n) return;
  float dd = dinv[d];
  unsigned int v = xws[(long)d * 64 + lane];
  float ax = bf2f((unsigned short)(v & 0xffff));
  float ay = bf2f((unsigned short)(v >> 16));
  int p0 = rowptr[d], p1 = rowptr[d + 1];
  for (int base = p0; base < p1; base += 64) {
    int idx = base + lane;
    int sl = (idx < p1) ? csr[idx] : 0;
    int cnt = p1 - base;
    if (cnt > 64) cnt = 64;
    int e = 0;
    for (; e + 8 <= cnt; e += 8) {
      unsigned int u0 = xws[(long)__shfl(sl, e) * 64 + lane];
      unsigned int u1 = xws[(long)__shfl(sl, e + 1) * 64 + lane];
      unsigned int u2 = xws[(long)__shfl(sl, e + 2) * 64 + lane];
      unsigned int u3 = xws[(long)__shfl(sl, e + 3) * 64 + lane];
      unsigned int u4 = xws[(long)__shfl(sl, e + 4) * 64 + lane];
      unsigned int u5 = xws[(long)__shfl(sl, e + 5) * 64 + lane];
      unsigned int u6 = xws[(long)__shfl(sl, e + 6) * 64 + lane];
      unsigned int u7 = xws[(long)__shfl(sl, e + 7) * 64 + lane];
      ax += bf2f((unsigned short)(u0 & 0xffff)) + bf2f((unsigned short)(u1 & 0xffff)) +
            bf2f((unsigned short)(u2 & 0xffff)) + bf2f((unsigned short)(u3 & 0xffff)) +
            bf2f((unsigned short)(u4 & 0xffff)) + bf2f((unsigned short)(u5 & 0xffff)) +
            bf2f((unsigned short)(u6 & 0xffff)) + bf2f((unsigned short)(u7 & 0xffff));
      ay += bf2f((unsigned short)(u0 >> 16)) + bf2f((unsigned short)(u1 >> 16)) +
            bf2f((unsigned short)(u2 >> 16)) + bf2f((unsigned short)(u3 >> 16)) +
            bf2f((unsigned short)(u4 >> 16)) + bf2f((unsigned short)(u5 >> 16)) +
            bf2f((unsigned short)(u6 >> 16)) + bf2f((unsigned short)(u7 >> 16));
    }
    for (; e < cnt; ++e) {
      unsigned int u = xws[(long)__shfl(sl, e) * 64 + lane];
      ax += bf2f((unsigned short)(u & 0xffff));
      ay += bf2f((unsigned short)(u >> 16));
    }
  }
  const float2* b2 = (const float2*)bias;
  float2 bb = b2[lane];
  ax = ax * dd + bb.x;
  ay = ay * dd + bb.y;
  ushort2 ob;
  ob.x = f2bf(ax);
  ob.y = f2bf(ay);
  outb[(long)d * 64 + lane] = ob;
  float s1 = ax + ay;
  float s2 = ax * ax + ay * ay;
#pragma unroll
  for (int m = 32; m >= 1; m >>= 1) {
    s1 += __shfl_xor(s1, m);
    s2 += __shfl_xor(s2, m);
  }
  if (lane == 0) { rowsum[d] = s1; rowsumsq[d] = s2; }
}

// ---------------- per-graph LN stats (double accumulation) ----------------

__global__ __launch_bounds__(TPB) void gstats_k(const float* __restrict__ rowsum,
                                                const float* __restrict__ rowsumsq,
                                                const int* __restrict__ gstart,
                                                float* __restrict__ meanA,
                                                float* __restrict__ rsigA,
                                                float* __restrict__ cntA) {
  __shared__ double sd1[TPB], sd2[TPB];
  int g = blockIdx.x, t = threadIdx.x;
  int n0 = gstart[g], n1 = gstart[g + 1];
  double s1 = 0, s2 = 0;
  for (int i = n0 + t; i < n1; i += TPB) { s1 += rowsum[i]; s2 += rowsumsq[i]; }
  sd1[t] = s1; sd2[t] = s2;
  __syncthreads();
  for (int st = TPB / 2; st > 0; st >>= 1) {
    if (t < st) { sd1[t] += sd1[t + st]; sd2[t] += sd2[t + st]; }
    __syncthreads();
  }
  if (t == 0) {
    double cntd = (double)(n1 - n0) * 128.0;
    if (cntd > 0.0) {
      double mean = sd1[0] / cntd;
      double var = sd2[0] / cntd - mean * mean;
      if (var < 0.0) var = 0.0;
      meanA[g] = (float)mean;
      rsigA[g] = (float)(1.0 / sqrt(var + 1e-5));
    } else {
      meanA[g] = 0.f;
      rsigA[g] = 0.f;
    }
    cntA[g] = (float)(n1 - n0);
  }
}

// ---------------- global add pool: raw bf16 rows -> 8 deterministic partials --

__global__ __launch_bounds__(128) void pool_k(const unsigned short* __restrict__ x,
                                              const int* __restrict__ gstart,
                                              float* __restrict__ part) {
  int g = blockIdx.x >> 3, s = blockIdx.x & 7, j = threadIdx.x;
  int n0 = gstart[g], n1 = gstart[g + 1];
  float acc = 0.f;
  for (int nn = n0 + s; nn < n1; nn += 8) acc += bf2f(x[(long)nn * 128 + j]);
  part[((long)s * 64 + g) * 128 + j] = acc;
}

// ---------------- MLP head: one block per graph, final LN folded in ----------

__global__ __launch_bounds__(TPB) void head_k(
    const float* __restrict__ partK, const float* __restrict__ partD,
    const float* __restrict__ meanF, const float* __restrict__ rsigF,
    const float* __restrict__ cntF, const float* __restrict__ lnw2,
    const float* __restrict__ lnb2, const float* __restrict__ W1,
    const float* __restrict__ b1, const float* __restrict__ W2,
    const float* __restrict__ b2, const float* __restrict__ W3,
    const float* __restrict__ b3, float* __restrict__ out) {
  __shared__ float ps[256];
  __shared__ float part[256];
  __shared__ float h1[128];
  __shared__ float h2[64];
  int g = blockIdx.x, tid = threadIdx.x;
  {
    int j = tid & 127, side = tid >> 7;
    const float* pp = side ? partD : partK;
    float S = 0.f;
#pragma unroll
    for (int s = 0; s < 8; ++s) S += pp[((long)s * 64 + g) * 128 + j];
    float m = meanF[side * 64 + g], r = rsigF[side * 64 + g], c = cntF[side * 64 + g];
    ps[tid] = lnw2[j] * r * (S - m * c) + lnb2[j] * c;
  }
  __syncthreads();
  {
    int j = tid & 127, half = tid >> 7;
    float acc = 0.f;
    const float* w = W1 + (size_t)half * 128 * 128 + j;
    const float* p = ps + half * 128;
#pragma unroll 8
    for (int k = 0; k < 128; ++k) acc = fmaf(p[k], w[(size_t)k * 128], acc);
    part[tid] = acc;
    __syncthreads();
    if (tid < 128) h1[tid] = fmaxf(part[tid] + part[tid + 128] + b1[tid], 0.f);
    __syncthreads();
  }
  {
    int j = tid & 63, q = tid >> 6;
    float acc = 0.f;
    const float* w = W2 + (size_t)q * 32 * 64 + j;
    const float* p = h1 + q * 32;
#pragma unroll 8
    for (int k = 0; k < 32; ++k) acc = fmaf(p[k], w[(size_t)k * 64], acc);
    part[tid] = acc;
    __syncthreads();
    if (tid < 64)
      h2[tid] = fmaxf(part[tid] + part[tid + 64] + part[tid + 128] + part[tid + 192] + b2[tid], 0.f);
    __syncthreads();
  }
  if (tid < 64) {
    float v = h2[tid] * W3[tid];
#pragma unroll
    for (int m = 32; m >= 1; m >>= 1) v += __shfl_xor(v, m);
    if (tid == 0) out[g] = v + b3[0];
  }
}

// ---------------------------------------------------------------------------

extern "C" void kernel_launch(void* const* d_in, const int* in_sizes, int n_in,
                              void* d_out, int out_size, void* d_ws, size_t ws_size,
                              hipStream_t stream) {
  const int N = in_sizes[2];       // 100000
  const int E = in_sizes[1] / 2;   // 1000000
  const int G = 64, H = 128, D = 64, L = 3;
  (void)n_in; (void)ws_size; (void)D; (void)out_size;

  const float* kernel_x = (const float*)d_in[0];
  const int* kernel_ei  = (const int*)d_in[1];
  const int* kernel_b   = (const int*)d_in[2];
  const float* design_x = (const float*)d_in[3];
  const int* design_ei  = (const int*)d_in[4];
  const int* design_b   = (const int*)d_in[5];
  const float* encW  = (const float*)d_in[7];
  const float* encB  = (const float*)d_in[8];
  const float* convW = (const float*)d_in[9];
  const float* convB = (const float*)d_in[10];
  const float* lnw   = (const float*)d_in[11];
  const float* lnb   = (const float*)d_in[12];
  const float* W1 = (const float*)d_in[13];
  const float* b1 = (const float*)d_in[14];
  const float* W2 = (const float*)d_in[15];
  const float* b2 = (const float*)d_in[16];
  const float* W3 = (const float*)d_in[17];
  const float* b3 = (const float*)d_in[18];
  float* out = (float*)d_out;

  char* ws = (char*)d_ws;
  size_t off = 0;
  auto alloc = [&](size_t bytes) -> void* {
    void* p = ws + off;
    off = (off + bytes + 511) & ~(size_t)511;
    return p;
  };
  unsigned short* hb   = (unsigned short*)alloc((size_t)N * H * 2);  // enc out
  unsigned short* bufX = (unsigned short*)alloc((size_t)N * H * 2);  // xws
  unsigned short* bufY = (unsigned short*)alloc((size_t)N * H * 2);  // agg out
  float* dinv    = (float*)alloc((size_t)N * 4);
  int* cntI      = (int*)alloc((size_t)N * 4);
  int* rowptr    = (int*)alloc((size_t)(N + 1) * 4);
  int* cursor    = (int*)alloc((size_t)N * 4);
  int* csr_src   = (int*)alloc((size_t)E * 4);
  int* gstart    = (int*)alloc((size_t)(G + 1) * 4);
  float* rowsum  = (float*)alloc((size_t)N * 4);
  float* rowsumsq= (float*)alloc((size_t)N * 4);
  float* meanS   = (float*)alloc((size_t)G * 4);
  float* rsigS   = (float*)alloc((size_t)G * 4);
  float* cntS    = (float*)alloc((size_t)G * 4);
  float* meanF   = (float*)alloc((size_t)2 * G * 4);
  float* rsigF   = (float*)alloc((size_t)2 * G * 4);
  float* cntF    = (float*)alloc((size_t)2 * G * 4);
  float* partK   = (float*)alloc((size_t)8 * G * 128 * 4);
  float* partD   = (float*)alloc((size_t)8 * G * 128 * 4);
  int* bsum      = (int*)alloc(512 * 4);
  int* bpre      = (int*)alloc(512 * 4);
  unsigned short* encWt  = (unsigned short*)alloc((size_t)128 * 64 * 2);
  unsigned short* convWt = (unsigned short*)alloc((size_t)L * 128 * 128 * 2);

  const int gN    = (N + TPB - 1) / TPB;
  const int gE    = (E + TPB - 1) / TPB;
  const int gGemm = (N + 127) / 128;
  const int gAgg  = (N + 3) / 4;
  const int P     = (N + 511) / 512;
  const int gFill = 8 * ((E + FILL_CHUNK - 1) / FILL_CHUNK);

  transp_cvt_k<<<(64 * 128 + TPB - 1) / TPB, TPB, 0, stream>>>(encW, encWt, 64, 128);
  for (int i = 0; i < L; ++i)
    transp_cvt_k<<<(128 * 128 + TPB - 1) / TPB, TPB, 0, stream>>>(
        convW + (size_t)i * H * H, convWt + (size_t)i * H * H, 128, 128);

  struct GraphIn { const float* x; const int* ei; const int* batch; };
  GraphIn graphs[2] = {
      {kernel_x, kernel_ei, kernel_b},
      {design_x, design_ei, design_b},
  };

  for (int gi = 0; gi < 2; ++gi) {
    const float* x = graphs[gi].x;
    const int* esrc = graphs[gi].ei;
    const int* edst = graphs[gi].ei + E;
    const int* batch = graphs[gi].batch;

    hipMemsetAsync(cntI, 0, (size_t)N * 4, stream);
    count_dst_k<<<gE, TPB, 0, stream>>>(edst, cntI, E);
    prep_node_k<<<gN, TPB, 0, stream>>>(cntI, dinv, batch, gstart, N, G);
    scan_partial_k<<<P, TPB, 0, stream>>>(cntI, bsum, N);
    scan_small_k<<<1, TPB, 0, stream>>>(bsum, bpre, P, rowptr, N);
    scan_fill_k<<<P, TPB, 0, stream>>>(cntI, bpre, rowptr, cursor, N);
    csrfill_k<<<gFill, TPB, 0, stream>>>(esrc, edst, cursor, csr_src, E, N);

    // encoder: hb = bf16(x @ encW + encB)   (f32 input staged directly)
    mfma_gemm_k<64, true, false, false, true><<<gGemm, TPB, 0, stream>>>(
        x, encWt, encB, hb, N, nullptr, nullptr, nullptr, nullptr, nullptr, nullptr);

    for (int i = 0; i < L; ++i) {
      const unsigned short* src = (i == 0) ? hb : bufY;
      float* mS = (i == L - 1) ? meanF + gi * G : meanS;
      float* rS = (i == L - 1) ? rsigF + gi * G : rsigS;
      float* cS = (i == L - 1) ? cntF + gi * G : cntS;
      if (i == 0)
        mfma_gemm_k<128, false, false, true, false><<<gGemm, TPB, 0, stream>>>(
            src, convWt + (size_t)i * H * H, nullptr, bufX, N,
            nullptr, nullptr, nullptr, nullptr, nullptr, dinv);
      else
        mfma_gemm_k<128, false, true, true, false><<<gGemm, TPB, 0, stream>>>(
            src, convWt + (size_t)i * H * H, nullptr, bufX, N,
            batch, meanS, rsigS, lnw + (size_t)(i - 1) * H,
            lnb + (size_t)(i - 1) * H, dinv);
      aggregate_k<<<gAgg, TPB, 0, stream>>>((const unsigned int*)bufX, rowptr, csr_src,
                                            dinv, convB + (size_t)i * H,
                                            (ushort2*)bufY, rowsum, rowsumsq, N);
      gstats_k<<<G, TPB, 0, stream>>>(rowsum, rowsumsq, gstart, mS, rS, cS);
    }
    pool_k<<<G * 8, 128, 0, stream>>>(bufY, gstart, gi ? partD : partK);
  }

  head_k<<<G, TPB, 0, stream>>>(partK, partD, meanF, rsigF, cntF,
                                lnw + (size_t)(L - 1) * H, lnb + (size_t)(L - 1) * H,
                                W1, b1, W2, b2, W3, b3, out);
}

// Round 7
// 735.568 us; speedup vs baseline: 3.1926x; 1.1386x over previous
//
#include <hip/hip_runtime.h>

// ---------------------------------------------------------------------------
// SimpleDifferentialGNN: 2x GCN encoder + global_add_pool + MLP head.
// N=100000, E=1000000, G=64, D=64, H=128, L=3
// R6: same as R5 (vectorized pool, merged wprep) with ushort8 -> local
//     ext_vector_type typedef (HIP has no built-in ushort8).
// ---------------------------------------------------------------------------

#define TPB 256
#define FILL_CHUNK 2048

typedef __attribute__((ext_vector_type(8))) short bf16x8;
typedef __attribute__((ext_vector_type(8))) unsigned short u16x8;
typedef __attribute__((ext_vector_type(4))) float f32x4;

__device__ __forceinline__ float bf2f(unsigned short s) {
  unsigned int u = ((unsigned int)s) << 16;
  float f;
  __builtin_memcpy(&f, &u, 4);
  return f;
}

__device__ __forceinline__ unsigned short f2bf(float f) {
  unsigned int u;
  __builtin_memcpy(&u, &f, 4);
  u = (u + 0x7FFF + ((u >> 16) & 1)) >> 16;  // RNE
  return (unsigned short)u;
}

// ---------------- small utility kernels ----------------

__global__ __launch_bounds__(TPB) void count_dst_k(const int* __restrict__ dst,
                                                   int* __restrict__ cnt, int E) {
  int e = blockIdx.x * TPB + threadIdx.x;
  if (e < E) atomicAdd(&cnt[dst[e]], 1);
}

// dinv + graph boundaries in one node pass
__global__ __launch_bounds__(TPB) void prep_node_k(const int* __restrict__ cnt,
                                                   float* __restrict__ dinv,
                                                   const int* __restrict__ batch,
                                                   int* __restrict__ gstart, int n, int G) {
  int i = blockIdx.x * TPB + threadIdx.x;
  if (i >= n) return;
  dinv[i] = 1.0f / sqrtf((float)cnt[i] + 1.0f);
  int b = batch[i];
  if (i == 0) {
    for (int g = 0; g <= b; ++g) gstart[g] = 0;
  } else {
    int pb = batch[i - 1];
    for (int g = pb + 1; g <= b; ++g) gstart[g] = i;
  }
  if (i == n - 1) {
    for (int g = b + 1; g <= G; ++g) gstart[g] = n;
  }
}

// ---------------- multi-block exclusive scan ----------------

__global__ __launch_bounds__(TPB) void scan_partial_k(const int* __restrict__ cnt,
                                                      int* __restrict__ bsum, int n) {
  __shared__ int sd[TPB];
  int t = threadIdx.x, i0 = blockIdx.x * 512 + t * 2;
  int s = 0;
  if (i0 < n) s += cnt[i0];
  if (i0 + 1 < n) s += cnt[i0 + 1];
  sd[t] = s;
  __syncthreads();
  for (int st = TPB / 2; st > 0; st >>= 1) {
    if (t < st) sd[t] += sd[t + st];
    __syncthreads();
  }
  if (t == 0) bsum[blockIdx.x] = sd[0];
}

__global__ __launch_bounds__(TPB) void scan_small_k(const int* __restrict__ bsum,
                                                    int* __restrict__ bpre, int P,
                                                    int* __restrict__ rowptr, int n) {
  __shared__ int sd[TPB];
  int t = threadIdx.x;
  int v = (t < P) ? bsum[t] : 0;
  sd[t] = v;
  __syncthreads();
  for (int d = 1; d < TPB; d <<= 1) {
    int w = (t >= d) ? sd[t - d] : 0;
    __syncthreads();
    sd[t] += w;
    __syncthreads();
  }
  if (t < P) bpre[t] = sd[t] - v;
  if (t == TPB - 1) rowptr[n] = sd[TPB - 1];
}

// fills rowptr AND cursor (identical) — saves the d2d copy
__global__ __launch_bounds__(TPB) void scan_fill_k(const int* __restrict__ cnt,
                                                   const int* __restrict__ bpre,
                                                   int* __restrict__ rowptr,
                                                   int* __restrict__ cursor, int n) {
  __shared__ int sd[TPB];
  int t = threadIdx.x, i0 = blockIdx.x * 512 + t * 2;
  int c0 = (i0 < n) ? cnt[i0] : 0;
  int c1 = (i0 + 1 < n) ? cnt[i0 + 1] : 0;
  int s = c0 + c1;
  sd[t] = s;
  __syncthreads();
  for (int d = 1; d < TPB; d <<= 1) {
    int w = (t >= d) ? sd[t - d] : 0;
    __syncthreads();
    sd[t] += w;
    __syncthreads();
  }
  int ex = sd[t] - s + bpre[blockIdx.x];
  if (i0 < n) { rowptr[i0] = ex; cursor[i0] = ex; }
  if (i0 + 1 < n) { rowptr[i0 + 1] = ex + c0; cursor[i0 + 1] = ex + c0; }
}

// ---------------- CSR fill, XCD-range filtered ----------------
// Block b handles edges in chunk (b>>3) whose dst lies in node-range (b&7):
// all writes to a csr line come from one XCD's L2 -> full-line writebacks.

__global__ __launch_bounds__(TPB) void csrfill_k(const int* __restrict__ esrc,
                                                 const int* __restrict__ edst,
                                                 int* __restrict__ cursor,
                                                 int* __restrict__ csr_src, int E, int n) {
  int range = blockIdx.x & 7;
  int chunk = blockIdx.x >> 3;
  int nper = (n + 7) >> 3;
  int lo = range * nper;
  int hi = lo + nper; if (hi > n) hi = n;
  int base = chunk * FILL_CHUNK;
  int end = base + FILL_CHUNK; if (end > E) end = E;
  for (int e = base + threadIdx.x; e < end; e += TPB) {
    int d = edst[e];
    if (d >= lo && d < hi) {
      int p = atomicAdd(&cursor[d], 1);
      csr_src[p] = esrc[e];
    }
  }
}

// ---------------- weight prep: all 4 matrices in one dispatch ----------------

__global__ __launch_bounds__(TPB) void wprep_k(const float* __restrict__ encW,
                                               const float* __restrict__ convW,
                                               unsigned short* __restrict__ encWt,
                                               unsigned short* __restrict__ convWt) {
  int idx = blockIdx.x * TPB + threadIdx.x;
  if (idx < 64 * 128) {
    int k = idx >> 7, c = idx & 127;
    encWt[c * 64 + k] = f2bf(encW[idx]);
  }
  idx -= 64 * 128;
  if (idx >= 0 && idx < 3 * 128 * 128) {
    int l = idx >> 14, r = idx & 16383;
    int k = r >> 7, c = r & 127;
    convWt[l * 16384 + c * 128 + k] = f2bf(convW[idx]);
  }
}

// ---------------- MFMA GEMM ----------------
// A: [nrows][K] (bf16, or f32 if F32IN) -> LDS bf16, XOR-swizzled.
// Wt: [128][K] bf16.  Optional fused input-LN+ReLU, output dinv-scale.

template <int K, bool BIAS, bool LNRELU, bool SCALE, bool F32IN>
__global__ __launch_bounds__(TPB) void mfma_gemm_k(
    const void* __restrict__ Av, const unsigned short* __restrict__ Wt,
    const float* __restrict__ bias, unsigned short* __restrict__ C, int nrows,
    const int* __restrict__ batch, const float* __restrict__ meanA,
    const float* __restrict__ rsigA, const float* __restrict__ lnw,
    const float* __restrict__ lnb, const float* __restrict__ dinv) {
  __shared__ short As[128 * K];
  __shared__ short Bs[128 * K];
  const int tid = threadIdx.x;
  const int r0 = blockIdx.x << 7;
  const int lane = tid & 63;
  const int wv = tid >> 6;
  const int lr = lane & 15, lg = lane >> 4;
  constexpr int CPR = K / 8;

  for (int i = tid; i < 128 * CPR; i += TPB) {
    int rloc = i / CPR, cb = i % CPR;
    int r = r0 + rloc;
    bf16x8 v = {0, 0, 0, 0, 0, 0, 0, 0};
    if (r < nrows) {
      if (F32IN) {
        const float* Af = ((const float*)Av) + (long)r * K + cb * 8;
        float4 f0 = *(const float4*)Af;
        float4 f1 = *(const float4*)(Af + 4);
        v[0] = (short)f2bf(f0.x); v[1] = (short)f2bf(f0.y);
        v[2] = (short)f2bf(f0.z); v[3] = (short)f2bf(f0.w);
        v[4] = (short)f2bf(f1.x); v[5] = (short)f2bf(f1.y);
        v[6] = (short)f2bf(f1.z); v[7] = (short)f2bf(f1.w);
      } else {
        v = *(const bf16x8*)(((const unsigned short*)Av) + (long)r * K + cb * 8);
        if (LNRELU) {
          int g = batch[r];
          float m = meanA[g], rs = rsigA[g];
          int c0 = cb * 8;
#pragma unroll
          for (int j = 0; j < 8; ++j) {
            float f = bf2f((unsigned short)v[j]);
            f = (f - m) * rs * lnw[c0 + j] + lnb[c0 + j];
            f = fmaxf(f, 0.f);
            v[j] = (short)f2bf(f);
          }
        }
      }
    }
    int sb = cb ^ (rloc & 7);
    *(bf16x8*)(&As[rloc * K + sb * 8]) = v;
  }
  for (int i = tid; i < 128 * CPR; i += TPB) {
    int rloc = i / CPR, cb = i % CPR;
    bf16x8 v = *(const bf16x8*)(Wt + (long)rloc * K + cb * 8);
    int sb = cb ^ (rloc & 7);
    *(bf16x8*)(&Bs[rloc * K + sb * 8]) = v;
  }
  __syncthreads();

  f32x4 acc[2][8];
#pragma unroll
  for (int m = 0; m < 2; ++m)
#pragma unroll
    for (int n = 0; n < 8; ++n) acc[m][n] = {0.f, 0.f, 0.f, 0.f};

  const int wrow = wv * 32;
#pragma unroll
  for (int k0 = 0; k0 < K; k0 += 32) {
    const int cbk = (k0 >> 3) + lg;
    bf16x8 a[2], b[8];
#pragma unroll
    for (int m = 0; m < 2; ++m) {
      int rr = wrow + m * 16 + lr;
      int sb = cbk ^ (rr & 7);
      a[m] = *(const bf16x8*)(&As[rr * K + sb * 8]);
    }
#pragma unroll
    for (int n = 0; n < 8; ++n) {
      int rr = n * 16 + lr;
      int sb = cbk ^ (rr & 7);
      b[n] = *(const bf16x8*)(&Bs[rr * K + sb * 8]);
    }
#pragma unroll
    for (int m = 0; m < 2; ++m)
#pragma unroll
      for (int n = 0; n < 8; ++n)
        acc[m][n] = __builtin_amdgcn_mfma_f32_16x16x32_bf16(a[m], b[n], acc[m][n], 0, 0, 0);
  }

  float bv[8];
#pragma unroll
  for (int n = 0; n < 8; ++n) bv[n] = BIAS ? bias[n * 16 + lr] : 0.f;
#pragma unroll
  for (int m = 0; m < 2; ++m) {
#pragma unroll
    for (int ri = 0; ri < 4; ++ri) {
      int r = r0 + wrow + m * 16 + lg * 4 + ri;
      if (r < nrows) {
        float dv = SCALE ? dinv[r] : 1.f;
#pragma unroll
        for (int n = 0; n < 8; ++n) {
          float v = acc[m][n][ri] + bv[n];
          if (SCALE) v *= dv;
          C[(long)r * 128 + n * 16 + lr] = f2bf(v);
        }
      }
    }
  }
}

// ---------------- aggregation ----------------
// xws already dinv-scaled: out[d] = dd*(xws[d] + sum_e xws[s]) + b
// one wave per node; lane holds 2 channels (uint = 2x bf16);
// csr batch via coalesced load + shfl broadcast; 8-wide independent gathers.

__global__ __launch_bounds__(TPB) void aggregate_k(
    const unsigned int* __restrict__ xws, const int* __restrict__ rowptr,
    const int* __restrict__ csr, const float* __restrict__ dinv,
    const float* __restrict__ bias, ushort2* __restrict__ outb,
    float2* __restrict__ rs2, int n) {
  int wave = threadIdx.x >> 6, lane = threadIdx.x & 63;
  int d = (blockIdx.x << 2) + wave;
  if (d >= n) return;
  float dd = dinv[d];
  unsigned int v = xws[(long)d * 64 + lane];
  float ax = bf2f((unsigned short)(v & 0xffff));
  float ay = bf2f((unsigned short)(v >> 16));
  int p0 = rowptr[d], p1 = rowptr[d + 1];
  for (int base = p0; base < p1; base += 64) {
    int idx = base + lane;
    int sl = (idx < p1) ? csr[idx] : 0;
    int cnt = p1 - base;
    if (cnt > 64) cnt = 64;
    int e = 0;
    for (; e + 8 <= cnt; e += 8) {
      unsigned int u0 = xws[(long)__shfl(sl, e) * 64 + lane];
      unsigned int u1 = xws[(long)__shfl(sl, e + 1) * 64 + lane];
      unsigned int u2 = xws[(long)__shfl(sl, e + 2) * 64 + lane];
      unsigned int u3 = xws[(long)__shfl(sl, e + 3) * 64 + lane];
      unsigned int u4 = xws[(long)__shfl(sl, e + 4) * 64 + lane];
      unsigned int u5 = xws[(long)__shfl(sl, e + 5) * 64 + lane];
      unsigned int u6 = xws[(long)__shfl(sl, e + 6) * 64 + lane];
      unsigned int u7 = xws[(long)__shfl(sl, e + 7) * 64 + lane];
      ax += bf2f((unsigned short)(u0 & 0xffff)) + bf2f((unsigned short)(u1 & 0xffff)) +
            bf2f((unsigned short)(u2 & 0xffff)) + bf2f((unsigned short)(u3 & 0xffff)) +
            bf2f((unsigned short)(u4 & 0xffff)) + bf2f((unsigned short)(u5 & 0xffff)) +
            bf2f((unsigned short)(u6 & 0xffff)) + bf2f((unsigned short)(u7 & 0xffff));
      ay += bf2f((unsigned short)(u0 >> 16)) + bf2f((unsigned short)(u1 >> 16)) +
            bf2f((unsigned short)(u2 >> 16)) + bf2f((unsigned short)(u3 >> 16)) +
            bf2f((unsigned short)(u4 >> 16)) + bf2f((unsigned short)(u5 >> 16)) +
            bf2f((unsigned short)(u6 >> 16)) + bf2f((unsigned short)(u7 >> 16));
    }
    for (; e < cnt; ++e) {
      unsigned int u = xws[(long)__shfl(sl, e) * 64 + lane];
      ax += bf2f((unsigned short)(u & 0xffff));
      ay += bf2f((unsigned short)(u >> 16));
    }
  }
  const float2* b2 = (const float2*)bias;
  float2 bb = b2[lane];
  ax = ax * dd + bb.x;
  ay = ay * dd + bb.y;
  ushort2 ob;
  ob.x = f2bf(ax);
  ob.y = f2bf(ay);
  outb[(long)d * 64 + lane] = ob;
  float s1 = ax + ay;
  float s2 = ax * ax + ay * ay;
#pragma unroll
  for (int m = 32; m >= 1; m >>= 1) {
    s1 += __shfl_xor(s1, m);
    s2 += __shfl_xor(s2, m);
  }
  if (lane == 0) { rs2[d] = make_float2(s1, s2); }
}

// ---------------- per-graph LN stats (double accumulation) ----------------

__global__ __launch_bounds__(TPB) void gstats_k(const float2* __restrict__ rs2,
                                                const int* __restrict__ gstart,
                                                float* __restrict__ meanA,
                                                float* __restrict__ rsigA,
                                                float* __restrict__ cntA) {
  __shared__ double sd1[TPB], sd2[TPB];
  int g = blockIdx.x, t = threadIdx.x;
  int n0 = gstart[g], n1 = gstart[g + 1];
  double s1 = 0, s2 = 0;
  for (int i = n0 + t; i < n1; i += TPB) {
    float2 v = rs2[i];
    s1 += v.x; s2 += v.y;
  }
  sd1[t] = s1; sd2[t] = s2;
  __syncthreads();
  for (int st = TPB / 2; st > 0; st >>= 1) {
    if (t < st) { sd1[t] += sd1[t + st]; sd2[t] += sd2[t + st]; }
    __syncthreads();
  }
  if (t == 0) {
    double cntd = (double)(n1 - n0) * 128.0;
    if (cntd > 0.0) {
      double mean = sd1[0] / cntd;
      double var = sd2[0] / cntd - mean * mean;
      if (var < 0.0) var = 0.0;
      meanA[g] = (float)mean;
      rsigA[g] = (float)(1.0 / sqrt(var + 1e-5));
    } else {
      meanA[g] = 0.f;
      rsigA[g] = 0.f;
    }
    cntA[g] = (float)(n1 - n0);
  }
}

// ---------------- global add pool (vectorized) ----------------
// block (g, s): 16 row-slots x 16 channel-threads; 16B loads so 16 threads
// cover one 256B row; LDS tree-reduce over row-slots; 8 deterministic
// partials per graph as before.

__global__ __launch_bounds__(TPB) void pool_k(const unsigned short* __restrict__ x,
                                              const int* __restrict__ gstart,
                                              float* __restrict__ part) {
  __shared__ float red[16][132];  // padded: 2-way bank alias only
  int g = blockIdx.x >> 3, s = blockIdx.x & 7;
  int tid = threadIdx.x;
  int ro = tid >> 4, c8 = tid & 15;
  int n0 = gstart[g], n1 = gstart[g + 1];
  float acc[8];
#pragma unroll
  for (int j = 0; j < 8; ++j) acc[j] = 0.f;
  for (int nn = n0 + s + ro * 8; nn < n1; nn += 8 * 16) {
    u16x8 v = *(const u16x8*)(x + (long)nn * 128 + c8 * 8);
#pragma unroll
    for (int j = 0; j < 8; ++j) acc[j] += bf2f(v[j]);
  }
#pragma unroll
  for (int j = 0; j < 8; ++j) red[ro][c8 * 8 + j] = acc[j];
  __syncthreads();
  for (int st = 8; st > 0; st >>= 1) {
    if (ro < st) {
#pragma unroll
      for (int j = 0; j < 8; ++j) red[ro][c8 * 8 + j] += red[ro + st][c8 * 8 + j];
    }
    __syncthreads();
  }
  if (tid < 128) part[((long)s * 64 + g) * 128 + tid] = red[0][tid];
}

// ---------------- MLP head: one block per graph, final LN folded in ----------

__global__ __launch_bounds__(TPB) void head_k(
    const float* __restrict__ partK, const float* __restrict__ partD,
    const float* __restrict__ meanF, const float* __restrict__ rsigF,
    const float* __restrict__ cntF, const float* __restrict__ lnw2,
    const float* __restrict__ lnb2, const float* __restrict__ W1,
    const float* __restrict__ b1, const float* __restrict__ W2,
    const float* __restrict__ b2, const float* __restrict__ W3,
    const float* __restrict__ b3, float* __restrict__ out) {
  __shared__ float ps[256];
  __shared__ float part[256];
  __shared__ float h1[128];
  __shared__ float h2[64];
  int g = blockIdx.x, tid = threadIdx.x;
  {
    int j = tid & 127, side = tid >> 7;
    const float* pp = side ? partD : partK;
    float S = 0.f;
#pragma unroll
    for (int s = 0; s < 8; ++s) S += pp[((long)s * 64 + g) * 128 + j];
    float m = meanF[side * 64 + g], r = rsigF[side * 64 + g], c = cntF[side * 64 + g];
    ps[tid] = lnw2[j] * r * (S - m * c) + lnb2[j] * c;
  }
  __syncthreads();
  {
    int j = tid & 127, half = tid >> 7;
    float acc = 0.f;
    const float* w = W1 + (size_t)half * 128 * 128 + j;
    const float* p = ps + half * 128;
#pragma unroll 8
    for (int k = 0; k < 128; ++k) acc = fmaf(p[k], w[(size_t)k * 128], acc);
    part[tid] = acc;
    __syncthreads();
    if (tid < 128) h1[tid] = fmaxf(part[tid] + part[tid + 128] + b1[tid], 0.f);
    __syncthreads();
  }
  {
    int j = tid & 63, q = tid >> 6;
    float acc = 0.f;
    const float* w = W2 + (size_t)q * 32 * 64 + j;
    const float* p = h1 + q * 32;
#pragma unroll 8
    for (int k = 0; k < 32; ++k) acc = fmaf(p[k], w[(size_t)k * 64], acc);
    part[tid] = acc;
    __syncthreads();
    if (tid < 64)
      h2[tid] = fmaxf(part[tid] + part[tid + 64] + part[tid + 128] + part[tid + 192] + b2[tid], 0.f);
    __syncthreads();
  }
  if (tid < 64) {
    float v = h2[tid] * W3[tid];
#pragma unroll
    for (int m = 32; m >= 1; m >>= 1) v += __shfl_xor(v, m);
    if (tid == 0) out[g] = v + b3[0];
  }
}

// ---------------------------------------------------------------------------

extern "C" void kernel_launch(void* const* d_in, const int* in_sizes, int n_in,
                              void* d_out, int out_size, void* d_ws, size_t ws_size,
                              hipStream_t stream) {
  const int N = in_sizes[2];       // 100000
  const int E = in_sizes[1] / 2;   // 1000000
  const int G = 64, H = 128, D = 64, L = 3;
  (void)n_in; (void)ws_size; (void)D; (void)out_size;

  const float* kernel_x = (const float*)d_in[0];
  const int* kernel_ei  = (const int*)d_in[1];
  const int* kernel_b   = (const int*)d_in[2];
  const float* design_x = (const float*)d_in[3];
  const int* design_ei  = (const int*)d_in[4];
  const int* design_b   = (const int*)d_in[5];
  const float* encW  = (const float*)d_in[7];
  const float* encB  = (const float*)d_in[8];
  const float* convW = (const float*)d_in[9];
  const float* convB = (const float*)d_in[10];
  const float* lnw   = (const float*)d_in[11];
  const float* lnb   = (const float*)d_in[12];
  const float* W1 = (const float*)d_in[13];
  const float* b1 = (const float*)d_in[14];
  const float* W2 = (const float*)d_in[15];
  const float* b2 = (const float*)d_in[16];
  const float* W3 = (const float*)d_in[17];
  const float* b3 = (const float*)d_in[18];
  float* out = (float*)d_out;

  char* ws = (char*)d_ws;
  size_t off = 0;
  auto alloc = [&](size_t bytes) -> void* {
    void* p = ws + off;
    off = (off + bytes + 511) & ~(size_t)511;
    return p;
  };
  unsigned short* hb   = (unsigned short*)alloc((size_t)N * H * 2);  // enc out
  unsigned short* bufX = (unsigned short*)alloc((size_t)N * H * 2);  // xws
  unsigned short* bufY = (unsigned short*)alloc((size_t)N * H * 2);  // agg out
  float* dinv    = (float*)alloc((size_t)N * 4);
  int* cntI      = (int*)alloc((size_t)N * 4);
  int* rowptr    = (int*)alloc((size_t)(N + 1) * 4);
  int* cursor    = (int*)alloc((size_t)N * 4);
  int* csr_src   = (int*)alloc((size_t)E * 4);
  int* gstart    = (int*)alloc((size_t)(G + 1) * 4);
  float2* rs2    = (float2*)alloc((size_t)N * 8);
  float* meanS   = (float*)alloc((size_t)G * 4);
  float* rsigS   = (float*)alloc((size_t)G * 4);
  float* cntS    = (float*)alloc((size_t)G * 4);
  float* meanF   = (float*)alloc((size_t)2 * G * 4);
  float* rsigF   = (float*)alloc((size_t)2 * G * 4);
  float* cntF    = (float*)alloc((size_t)2 * G * 4);
  float* partK   = (float*)alloc((size_t)8 * G * 128 * 4);
  float* partD   = (float*)alloc((size_t)8 * G * 128 * 4);
  int* bsum      = (int*)alloc(512 * 4);
  int* bpre      = (int*)alloc(512 * 4);
  unsigned short* encWt  = (unsigned short*)alloc((size_t)128 * 64 * 2);
  unsigned short* convWt = (unsigned short*)alloc((size_t)L * 128 * 128 * 2);

  const int gN    = (N + TPB - 1) / TPB;
  const int gE    = (E + TPB - 1) / TPB;
  const int gGemm = (N + 127) / 128;
  const int gAgg  = (N + 3) / 4;
  const int P     = (N + 511) / 512;
  const int gFill = 8 * ((E + FILL_CHUNK - 1) / FILL_CHUNK);

  wprep_k<<<(64 * 128 + 3 * 128 * 128 + TPB - 1) / TPB, TPB, 0, stream>>>(
      encW, convW, encWt, convWt);

  struct GraphIn { const float* x; const int* ei; const int* batch; };
  GraphIn graphs[2] = {
      {kernel_x, kernel_ei, kernel_b},
      {design_x, design_ei, design_b},
  };

  for (int gi = 0; gi < 2; ++gi) {
    const float* x = graphs[gi].x;
    const int* esrc = graphs[gi].ei;
    const int* edst = graphs[gi].ei + E;
    const int* batch = graphs[gi].batch;

    hipMemsetAsync(cntI, 0, (size_t)N * 4, stream);
    count_dst_k<<<gE, TPB, 0, stream>>>(edst, cntI, E);
    prep_node_k<<<gN, TPB, 0, stream>>>(cntI, dinv, batch, gstart, N, G);
    scan_partial_k<<<P, TPB, 0, stream>>>(cntI, bsum, N);
    scan_small_k<<<1, TPB, 0, stream>>>(bsum, bpre, P, rowptr, N);
    scan_fill_k<<<P, TPB, 0, stream>>>(cntI, bpre, rowptr, cursor, N);
    csrfill_k<<<gFill, TPB, 0, stream>>>(esrc, edst, cursor, csr_src, E, N);

    // encoder: hb = bf16(x @ encW + encB)   (f32 input staged directly)
    mfma_gemm_k<64, true, false, false, true><<<gGemm, TPB, 0, stream>>>(
        x, encWt, encB, hb, N, nullptr, nullptr, nullptr, nullptr, nullptr, nullptr);

    for (int i = 0; i < L; ++i) {
      const unsigned short* src = (i == 0) ? hb : bufY;
      float* mS = (i == L - 1) ? meanF + gi * G : meanS;
      float* rS = (i == L - 1) ? rsigF + gi * G : rsigS;
      float* cS = (i == L - 1) ? cntF + gi * G : cntS;
      if (i == 0)
        mfma_gemm_k<128, false, false, true, false><<<gGemm, TPB, 0, stream>>>(
            src, convWt + (size_t)i * H * H, nullptr, bufX, N,
            nullptr, nullptr, nullptr, nullptr, nullptr, dinv);
      else
        mfma_gemm_k<128, false, true, true, false><<<gGemm, TPB, 0, stream>>>(
            src, convWt + (size_t)i * H * H, nullptr, bufX, N,
            batch, meanS, rsigS, lnw + (size_t)(i - 1) * H,
            lnb + (size_t)(i - 1) * H, dinv);
      aggregate_k<<<gAgg, TPB, 0, stream>>>((const unsigned int*)bufX, rowptr, csr_src,
                                            dinv, convB + (size_t)i * H,
                                            (ushort2*)bufY, rs2, N);
      gstats_k<<<G, TPB, 0, stream>>>(rs2, gstart, mS, rS, cS);
    }
    pool_k<<<G * 8, TPB, 0, stream>>>(bufY, gstart, gi ? partD : partK);
  }

  head_k<<<G, TPB, 0, stream>>>(partK, partD, meanF, rsigF, cntF,
                                lnw + (size_t)(L - 1) * H, lnb + (size_t)(L - 1) * H,
                                W1, b1, W2, b2, W3, b3, out);
}

// Round 8
// 703.353 us; speedup vs baseline: 3.3388x; 1.0458x over previous
//
#include <hip/hip_runtime.h>

// ---------------------------------------------------------------------------
// SimpleDifferentialGNN: 2x GCN encoder + global_add_pool + MLP head.
// N=100000, E=1000000, G=64, D=64, H=128, L=3
// R7: aggregate gather widened to dwordx4 — 16 lanes/row, 4 edges per load
//     instruction, group-combine via shfl_xor(16/32). Cuts per-edge
//     instruction overhead ~9 -> ~5 wave-instrs.
// ---------------------------------------------------------------------------

#define TPB 256
#define FILL_CHUNK 2048

typedef __attribute__((ext_vector_type(8))) short bf16x8;
typedef __attribute__((ext_vector_type(4))) float f32x4;

__device__ __forceinline__ float bf2f(unsigned short s) {
  unsigned int u = ((unsigned int)s) << 16;
  float f;
  __builtin_memcpy(&f, &u, 4);
  return f;
}

__device__ __forceinline__ unsigned short f2bf(float f) {
  unsigned int u;
  __builtin_memcpy(&u, &f, 4);
  u = (u + 0x7FFF + ((u >> 16) & 1)) >> 16;  // RNE
  return (unsigned short)u;
}

// ---------------- small utility kernels ----------------

__global__ __launch_bounds__(TPB) void count_dst_k(const int* __restrict__ dst,
                                                   int* __restrict__ cnt, int E) {
  int e = blockIdx.x * TPB + threadIdx.x;
  if (e < E) atomicAdd(&cnt[dst[e]], 1);
}

// dinv + graph boundaries in one node pass
__global__ __launch_bounds__(TPB) void prep_node_k(const int* __restrict__ cnt,
                                                   float* __restrict__ dinv,
                                                   const int* __restrict__ batch,
                                                   int* __restrict__ gstart, int n, int G) {
  int i = blockIdx.x * TPB + threadIdx.x;
  if (i >= n) return;
  dinv[i] = 1.0f / sqrtf((float)cnt[i] + 1.0f);
  int b = batch[i];
  if (i == 0) {
    for (int g = 0; g <= b; ++g) gstart[g] = 0;
  } else {
    int pb = batch[i - 1];
    for (int g = pb + 1; g <= b; ++g) gstart[g] = i;
  }
  if (i == n - 1) {
    for (int g = b + 1; g <= G; ++g) gstart[g] = n;
  }
}

// ---------------- multi-block exclusive scan ----------------

__global__ __launch_bounds__(TPB) void scan_partial_k(const int* __restrict__ cnt,
                                                      int* __restrict__ bsum, int n) {
  __shared__ int sd[TPB];
  int t = threadIdx.x, i0 = blockIdx.x * 512 + t * 2;
  int s = 0;
  if (i0 < n) s += cnt[i0];
  if (i0 + 1 < n) s += cnt[i0 + 1];
  sd[t] = s;
  __syncthreads();
  for (int st = TPB / 2; st > 0; st >>= 1) {
    if (t < st) sd[t] += sd[t + st];
    __syncthreads();
  }
  if (t == 0) bsum[blockIdx.x] = sd[0];
}

__global__ __launch_bounds__(TPB) void scan_small_k(const int* __restrict__ bsum,
                                                    int* __restrict__ bpre, int P,
                                                    int* __restrict__ rowptr, int n) {
  __shared__ int sd[TPB];
  int t = threadIdx.x;
  int v = (t < P) ? bsum[t] : 0;
  sd[t] = v;
  __syncthreads();
  for (int d = 1; d < TPB; d <<= 1) {
    int w = (t >= d) ? sd[t - d] : 0;
    __syncthreads();
    sd[t] += w;
    __syncthreads();
  }
  if (t < P) bpre[t] = sd[t] - v;
  if (t == TPB - 1) rowptr[n] = sd[TPB - 1];
}

// fills rowptr AND cursor (identical) — saves the d2d copy
__global__ __launch_bounds__(TPB) void scan_fill_k(const int* __restrict__ cnt,
                                                   const int* __restrict__ bpre,
                                                   int* __restrict__ rowptr,
                                                   int* __restrict__ cursor, int n) {
  __shared__ int sd[TPB];
  int t = threadIdx.x, i0 = blockIdx.x * 512 + t * 2;
  int c0 = (i0 < n) ? cnt[i0] : 0;
  int c1 = (i0 + 1 < n) ? cnt[i0 + 1] : 0;
  int s = c0 + c1;
  sd[t] = s;
  __syncthreads();
  for (int d = 1; d < TPB; d <<= 1) {
    int w = (t >= d) ? sd[t - d] : 0;
    __syncthreads();
    sd[t] += w;
    __syncthreads();
  }
  int ex = sd[t] - s + bpre[blockIdx.x];
  if (i0 < n) { rowptr[i0] = ex; cursor[i0] = ex; }
  if (i0 + 1 < n) { rowptr[i0 + 1] = ex + c0; cursor[i0 + 1] = ex + c0; }
}

// ---------------- CSR fill, XCD-range filtered ----------------
// Block b handles edges in chunk (b>>3) whose dst lies in node-range (b&7):
// all writes to a csr line come from one XCD's L2 -> full-line writebacks.

__global__ __launch_bounds__(TPB) void csrfill_k(const int* __restrict__ esrc,
                                                 const int* __restrict__ edst,
                                                 int* __restrict__ cursor,
                                                 int* __restrict__ csr_src, int E, int n) {
  int range = blockIdx.x & 7;
  int chunk = blockIdx.x >> 3;
  int nper = (n + 7) >> 3;
  int lo = range * nper;
  int hi = lo + nper; if (hi > n) hi = n;
  int base = chunk * FILL_CHUNK;
  int end = base + FILL_CHUNK; if (end > E) end = E;
  for (int e = base + threadIdx.x; e < end; e += TPB) {
    int d = edst[e];
    if (d >= lo && d < hi) {
      int p = atomicAdd(&cursor[d], 1);
      csr_src[p] = esrc[e];
    }
  }
}

// ---------------- weight prep: all 4 matrices in one dispatch ----------------

__global__ __launch_bounds__(TPB) void wprep_k(const float* __restrict__ encW,
                                               const float* __restrict__ convW,
                                               unsigned short* __restrict__ encWt,
                                               unsigned short* __restrict__ convWt) {
  int idx = blockIdx.x * TPB + threadIdx.x;
  if (idx < 64 * 128) {
    int k = idx >> 7, c = idx & 127;
    encWt[c * 64 + k] = f2bf(encW[idx]);
  }
  idx -= 64 * 128;
  if (idx >= 0 && idx < 3 * 128 * 128) {
    int l = idx >> 14, r = idx & 16383;
    int k = r >> 7, c = r & 127;
    convWt[l * 16384 + c * 128 + k] = f2bf(convW[idx]);
  }
}

// ---------------- MFMA GEMM ----------------
// A: [nrows][K] (bf16, or f32 if F32IN) -> LDS bf16, XOR-swizzled.
// Wt: [128][K] bf16.  Optional fused input-LN+ReLU, output dinv-scale.

template <int K, bool BIAS, bool LNRELU, bool SCALE, bool F32IN>
__global__ __launch_bounds__(TPB) void mfma_gemm_k(
    const void* __restrict__ Av, const unsigned short* __restrict__ Wt,
    const float* __restrict__ bias, unsigned short* __restrict__ C, int nrows,
    const int* __restrict__ batch, const float* __restrict__ meanA,
    const float* __restrict__ rsigA, const float* __restrict__ lnw,
    const float* __restrict__ lnb, const float* __restrict__ dinv) {
  __shared__ short As[128 * K];
  __shared__ short Bs[128 * K];
  const int tid = threadIdx.x;
  const int r0 = blockIdx.x << 7;
  const int lane = tid & 63;
  const int wv = tid >> 6;
  const int lr = lane & 15, lg = lane >> 4;
  constexpr int CPR = K / 8;

  for (int i = tid; i < 128 * CPR; i += TPB) {
    int rloc = i / CPR, cb = i % CPR;
    int r = r0 + rloc;
    bf16x8 v = {0, 0, 0, 0, 0, 0, 0, 0};
    if (r < nrows) {
      if (F32IN) {
        const float* Af = ((const float*)Av) + (long)r * K + cb * 8;
        float4 f0 = *(const float4*)Af;
        float4 f1 = *(const float4*)(Af + 4);
        v[0] = (short)f2bf(f0.x); v[1] = (short)f2bf(f0.y);
        v[2] = (short)f2bf(f0.z); v[3] = (short)f2bf(f0.w);
        v[4] = (short)f2bf(f1.x); v[5] = (short)f2bf(f1.y);
        v[6] = (short)f2bf(f1.z); v[7] = (short)f2bf(f1.w);
      } else {
        v = *(const bf16x8*)(((const unsigned short*)Av) + (long)r * K + cb * 8);
        if (LNRELU) {
          int g = batch[r];
          float m = meanA[g], rs = rsigA[g];
          int c0 = cb * 8;
#pragma unroll
          for (int j = 0; j < 8; ++j) {
            float f = bf2f((unsigned short)v[j]);
            f = (f - m) * rs * lnw[c0 + j] + lnb[c0 + j];
            f = fmaxf(f, 0.f);
            v[j] = (short)f2bf(f);
          }
        }
      }
    }
    int sb = cb ^ (rloc & 7);
    *(bf16x8*)(&As[rloc * K + sb * 8]) = v;
  }
  for (int i = tid; i < 128 * CPR; i += TPB) {
    int rloc = i / CPR, cb = i % CPR;
    bf16x8 v = *(const bf16x8*)(Wt + (long)rloc * K + cb * 8);
    int sb = cb ^ (rloc & 7);
    *(bf16x8*)(&Bs[rloc * K + sb * 8]) = v;
  }
  __syncthreads();

  f32x4 acc[2][8];
#pragma unroll
  for (int m = 0; m < 2; ++m)
#pragma unroll
    for (int n = 0; n < 8; ++n) acc[m][n] = {0.f, 0.f, 0.f, 0.f};

  const int wrow = wv * 32;
#pragma unroll
  for (int k0 = 0; k0 < K; k0 += 32) {
    const int cbk = (k0 >> 3) + lg;
    bf16x8 a[2], b[8];
#pragma unroll
    for (int m = 0; m < 2; ++m) {
      int rr = wrow + m * 16 + lr;
      int sb = cbk ^ (rr & 7);
      a[m] = *(const bf16x8*)(&As[rr * K + sb * 8]);
    }
#pragma unroll
    for (int n = 0; n < 8; ++n) {
      int rr = n * 16 + lr;
      int sb = cbk ^ (rr & 7);
      b[n] = *(const bf16x8*)(&Bs[rr * K + sb * 8]);
    }
#pragma unroll
    for (int m = 0; m < 2; ++m)
#pragma unroll
      for (int n = 0; n < 8; ++n)
        acc[m][n] = __builtin_amdgcn_mfma_f32_16x16x32_bf16(a[m], b[n], acc[m][n], 0, 0, 0);
  }

  float bv[8];
#pragma unroll
  for (int n = 0; n < 8; ++n) bv[n] = BIAS ? bias[n * 16 + lr] : 0.f;
#pragma unroll
  for (int m = 0; m < 2; ++m) {
#pragma unroll
    for (int ri = 0; ri < 4; ++ri) {
      int r = r0 + wrow + m * 16 + lg * 4 + ri;
      if (r < nrows) {
        float dv = SCALE ? dinv[r] : 1.f;
#pragma unroll
        for (int n = 0; n < 8; ++n) {
          float v = acc[m][n][ri] + bv[n];
          if (SCALE) v *= dv;
          C[(long)r * 128 + n * 16 + lr] = f2bf(v);
        }
      }
    }
  }
}

// ---------------- aggregation (dwordx4 gather) ----------------
// xws already dinv-scaled: out[d] = dd*(xws[d] + sum_e xws[s]) + b.
// One wave per node. Row = 16 uint4 (256B). Lane L: group g3=L>>4 handles
// edge (e + g3); cpos=L&15 covers channels cpos*8..+7 as one uint4 load.
// 4 edges per load instruction; 2 loads in flight; adds predicated;
// group partial sums combined with shfl_xor(16), shfl_xor(32).

__global__ __launch_bounds__(TPB) void aggregate_k(
    const uint4* __restrict__ xws, const int* __restrict__ rowptr,
    const int* __restrict__ csr, const float* __restrict__ dinv,
    const float* __restrict__ bias, uint4* __restrict__ outb,
    float2* __restrict__ rs2, int n) {
  int wave = threadIdx.x >> 6, lane = threadIdx.x & 63;
  int d = (blockIdx.x << 2) + wave;
  if (d >= n) return;
  const int g3 = lane >> 4, cpos = lane & 15;
  float acc[8];
#pragma unroll
  for (int j = 0; j < 8; ++j) acc[j] = 0.f;

  int p0 = rowptr[d], p1 = rowptr[d + 1];
  for (int base = p0; base < p1; base += 64) {
    int idx = base + lane;
    int sl = (idx < p1) ? csr[idx] : 0;
    int cnt = p1 - base;
    if (cnt > 64) cnt = 64;
    for (int e = 0; e < cnt; e += 8) {
      int e0 = e + g3, e1 = e + 4 + g3;
      int s0 = __shfl(sl, e0);  // lanes >= cnt hold 0 -> safe row
      int s1 = __shfl(sl, e1);
      uint4 u0 = xws[(long)s0 * 16 + cpos];
      uint4 u1 = xws[(long)s1 * 16 + cpos];
      if (e0 < cnt) {
        acc[0] += __uint_as_float(u0.x << 16);
        acc[1] += __uint_as_float(u0.x & 0xffff0000u);
        acc[2] += __uint_as_float(u0.y << 16);
        acc[3] += __uint_as_float(u0.y & 0xffff0000u);
        acc[4] += __uint_as_float(u0.z << 16);
        acc[5] += __uint_as_float(u0.z & 0xffff0000u);
        acc[6] += __uint_as_float(u0.w << 16);
        acc[7] += __uint_as_float(u0.w & 0xffff0000u);
      }
      if (e1 < cnt) {
        acc[0] += __uint_as_float(u1.x << 16);
        acc[1] += __uint_as_float(u1.x & 0xffff0000u);
        acc[2] += __uint_as_float(u1.y << 16);
        acc[3] += __uint_as_float(u1.y & 0xffff0000u);
        acc[4] += __uint_as_float(u1.z << 16);
        acc[5] += __uint_as_float(u1.z & 0xffff0000u);
        acc[6] += __uint_as_float(u1.w << 16);
        acc[7] += __uint_as_float(u1.w & 0xffff0000u);
      }
    }
  }

  // combine the 4 edge-groups (all lanes end with identical totals)
#pragma unroll
  for (int j = 0; j < 8; ++j) {
    acc[j] += __shfl_xor(acc[j], 16);
    acc[j] += __shfl_xor(acc[j], 32);
  }

  // self term + dd scale + bias
  uint4 su = xws[(long)d * 16 + cpos];
  float dd = dinv[d];
  float sv[8];
  sv[0] = __uint_as_float(su.x << 16);
  sv[1] = __uint_as_float(su.x & 0xffff0000u);
  sv[2] = __uint_as_float(su.y << 16);
  sv[3] = __uint_as_float(su.y & 0xffff0000u);
  sv[4] = __uint_as_float(su.z << 16);
  sv[5] = __uint_as_float(su.z & 0xffff0000u);
  sv[6] = __uint_as_float(su.w << 16);
  sv[7] = __uint_as_float(su.w & 0xffff0000u);
  const float4* b4 = (const float4*)bias;
  float4 bb0 = b4[cpos * 2];
  float4 bb1 = b4[cpos * 2 + 1];
  float val[8];
  val[0] = (acc[0] + sv[0]) * dd + bb0.x;
  val[1] = (acc[1] + sv[1]) * dd + bb0.y;
  val[2] = (acc[2] + sv[2]) * dd + bb0.z;
  val[3] = (acc[3] + sv[3]) * dd + bb0.w;
  val[4] = (acc[4] + sv[4]) * dd + bb1.x;
  val[5] = (acc[5] + sv[5]) * dd + bb1.y;
  val[6] = (acc[6] + sv[6]) * dd + bb1.z;
  val[7] = (acc[7] + sv[7]) * dd + bb1.w;

  if (g3 == 0) {
    uint4 o;
    o.x = (unsigned)f2bf(val[0]) | ((unsigned)f2bf(val[1]) << 16);
    o.y = (unsigned)f2bf(val[2]) | ((unsigned)f2bf(val[3]) << 16);
    o.z = (unsigned)f2bf(val[4]) | ((unsigned)f2bf(val[5]) << 16);
    o.w = (unsigned)f2bf(val[6]) | ((unsigned)f2bf(val[7]) << 16);
    outb[(long)d * 16 + cpos] = o;
  }

  float s1 = 0.f, s2 = 0.f;
#pragma unroll
  for (int j = 0; j < 8; ++j) {
    s1 += val[j];
    s2 += val[j] * val[j];
  }
#pragma unroll
  for (int m = 8; m >= 1; m >>= 1) {
    s1 += __shfl_xor(s1, m);
    s2 += __shfl_xor(s2, m);
  }
  if (lane == 0) rs2[d] = make_float2(s1, s2);
}

// ---------------- per-graph LN stats (double accumulation) ----------------

__global__ __launch_bounds__(TPB) void gstats_k(const float2* __restrict__ rs2,
                                                const int* __restrict__ gstart,
                                                float* __restrict__ meanA,
                                                float* __restrict__ rsigA,
                                                float* __restrict__ cntA) {
  __shared__ double sd1[TPB], sd2[TPB];
  int g = blockIdx.x, t = threadIdx.x;
  int n0 = gstart[g], n1 = gstart[g + 1];
  double s1 = 0, s2 = 0;
  for (int i = n0 + t; i < n1; i += TPB) {
    float2 v = rs2[i];
    s1 += v.x; s2 += v.y;
  }
  sd1[t] = s1; sd2[t] = s2;
  __syncthreads();
  for (int st = TPB / 2; st > 0; st >>= 1) {
    if (t < st) { sd1[t] += sd1[t + st]; sd2[t] += sd2[t + st]; }
    __syncthreads();
  }
  if (t == 0) {
    double cntd = (double)(n1 - n0) * 128.0;
    if (cntd > 0.0) {
      double mean = sd1[0] / cntd;
      double var = sd2[0] / cntd - mean * mean;
      if (var < 0.0) var = 0.0;
      meanA[g] = (float)mean;
      rsigA[g] = (float)(1.0 / sqrt(var + 1e-5));
    } else {
      meanA[g] = 0.f;
      rsigA[g] = 0.f;
    }
    cntA[g] = (float)(n1 - n0);
  }
}

// ---------------- global add pool (vectorized) ----------------

typedef __attribute__((ext_vector_type(8))) unsigned short u16x8;

__global__ __launch_bounds__(TPB) void pool_k(const unsigned short* __restrict__ x,
                                              const int* __restrict__ gstart,
                                              float* __restrict__ part) {
  __shared__ float red[16][132];  // padded: 2-way bank alias only
  int g = blockIdx.x >> 3, s = blockIdx.x & 7;
  int tid = threadIdx.x;
  int ro = tid >> 4, c8 = tid & 15;
  int n0 = gstart[g], n1 = gstart[g + 1];
  float acc[8];
#pragma unroll
  for (int j = 0; j < 8; ++j) acc[j] = 0.f;
  for (int nn = n0 + s + ro * 8; nn < n1; nn += 8 * 16) {
    u16x8 v = *(const u16x8*)(x + (long)nn * 128 + c8 * 8);
#pragma unroll
    for (int j = 0; j < 8; ++j) acc[j] += bf2f(v[j]);
  }
#pragma unroll
  for (int j = 0; j < 8; ++j) red[ro][c8 * 8 + j] = acc[j];
  __syncthreads();
  for (int st = 8; st > 0; st >>= 1) {
    if (ro < st) {
#pragma unroll
      for (int j = 0; j < 8; ++j) red[ro][c8 * 8 + j] += red[ro + st][c8 * 8 + j];
    }
    __syncthreads();
  }
  if (tid < 128) part[((long)s * 64 + g) * 128 + tid] = red[0][tid];
}

// ---------------- MLP head: one block per graph, final LN folded in ----------

__global__ __launch_bounds__(TPB) void head_k(
    const float* __restrict__ partK, const float* __restrict__ partD,
    const float* __restrict__ meanF, const float* __restrict__ rsigF,
    const float* __restrict__ cntF, const float* __restrict__ lnw2,
    const float* __restrict__ lnb2, const float* __restrict__ W1,
    const float* __restrict__ b1, const float* __restrict__ W2,
    const float* __restrict__ b2, const float* __restrict__ W3,
    const float* __restrict__ b3, float* __restrict__ out) {
  __shared__ float ps[256];
  __shared__ float part[256];
  __shared__ float h1[128];
  __shared__ float h2[64];
  int g = blockIdx.x, tid = threadIdx.x;
  {
    int j = tid & 127, side = tid >> 7;
    const float* pp = side ? partD : partK;
    float S = 0.f;
#pragma unroll
    for (int s = 0; s < 8; ++s) S += pp[((long)s * 64 + g) * 128 + j];
    float m = meanF[side * 64 + g], r = rsigF[side * 64 + g], c = cntF[side * 64 + g];
    ps[tid] = lnw2[j] * r * (S - m * c) + lnb2[j] * c;
  }
  __syncthreads();
  {
    int j = tid & 127, half = tid >> 7;
    float acc = 0.f;
    const float* w = W1 + (size_t)half * 128 * 128 + j;
    const float* p = ps + half * 128;
#pragma unroll 8
    for (int k = 0; k < 128; ++k) acc = fmaf(p[k], w[(size_t)k * 128], acc);
    part[tid] = acc;
    __syncthreads();
    if (tid < 128) h1[tid] = fmaxf(part[tid] + part[tid + 128] + b1[tid], 0.f);
    __syncthreads();
  }
  {
    int j = tid & 63, q = tid >> 6;
    float acc = 0.f;
    const float* w = W2 + (size_t)q * 32 * 64 + j;
    const float* p = h1 + q * 32;
#pragma unroll 8
    for (int k = 0; k < 32; ++k) acc = fmaf(p[k], w[(size_t)k * 64], acc);
    part[tid] = acc;
    __syncthreads();
    if (tid < 64)
      h2[tid] = fmaxf(part[tid] + part[tid + 64] + part[tid + 128] + part[tid + 192] + b2[tid], 0.f);
    __syncthreads();
  }
  if (tid < 64) {
    float v = h2[tid] * W3[tid];
#pragma unroll
    for (int m = 32; m >= 1; m >>= 1) v += __shfl_xor(v, m);
    if (tid == 0) out[g] = v + b3[0];
  }
}

// ---------------------------------------------------------------------------

extern "C" void kernel_launch(void* const* d_in, const int* in_sizes, int n_in,
                              void* d_out, int out_size, void* d_ws, size_t ws_size,
                              hipStream_t stream) {
  const int N = in_sizes[2];       // 100000
  const int E = in_sizes[1] / 2;   // 1000000
  const int G = 64, H = 128, D = 64, L = 3;
  (void)n_in; (void)ws_size; (void)D; (void)out_size;

  const float* kernel_x = (const float*)d_in[0];
  const int* kernel_ei  = (const int*)d_in[1];
  const int* kernel_b   = (const int*)d_in[2];
  const float* design_x = (const float*)d_in[3];
  const int* design_ei  = (const int*)d_in[4];
  const int* design_b   = (const int*)d_in[5];
  const float* encW  = (const float*)d_in[7];
  const float* encB  = (const float*)d_in[8];
  const float* convW = (const float*)d_in[9];
  const float* convB = (const float*)d_in[10];
  const float* lnw   = (const float*)d_in[11];
  const float* lnb   = (const float*)d_in[12];
  const float* W1 = (const float*)d_in[13];
  const float* b1 = (const float*)d_in[14];
  const float* W2 = (const float*)d_in[15];
  const float* b2 = (const float*)d_in[16];
  const float* W3 = (const float*)d_in[17];
  const float* b3 = (const float*)d_in[18];
  float* out = (float*)d_out;

  char* ws = (char*)d_ws;
  size_t off = 0;
  auto alloc = [&](size_t bytes) -> void* {
    void* p = ws + off;
    off = (off + bytes + 511) & ~(size_t)511;
    return p;
  };
  unsigned short* hb   = (unsigned short*)alloc((size_t)N * H * 2);  // enc out
  unsigned short* bufX = (unsigned short*)alloc((size_t)N * H * 2);  // xws
  unsigned short* bufY = (unsigned short*)alloc((size_t)N * H * 2);  // agg out
  float* dinv    = (float*)alloc((size_t)N * 4);
  int* cntI      = (int*)alloc((size_t)N * 4);
  int* rowptr    = (int*)alloc((size_t)(N + 1) * 4);
  int* cursor    = (int*)alloc((size_t)N * 4);
  int* csr_src   = (int*)alloc((size_t)E * 4);
  int* gstart    = (int*)alloc((size_t)(G + 1) * 4);
  float2* rs2    = (float2*)alloc((size_t)N * 8);
  float* meanS   = (float*)alloc((size_t)G * 4);
  float* rsigS   = (float*)alloc((size_t)G * 4);
  float* cntS    = (float*)alloc((size_t)G * 4);
  float* meanF   = (float*)alloc((size_t)2 * G * 4);
  float* rsigF   = (float*)alloc((size_t)2 * G * 4);
  float* cntF    = (float*)alloc((size_t)2 * G * 4);
  float* partK   = (float*)alloc((size_t)8 * G * 128 * 4);
  float* partD   = (float*)alloc((size_t)8 * G * 128 * 4);
  int* bsum      = (int*)alloc(512 * 4);
  int* bpre      = (int*)alloc(512 * 4);
  unsigned short* encWt  = (unsigned short*)alloc((size_t)128 * 64 * 2);
  unsigned short* convWt = (unsigned short*)alloc((size_t)L * 128 * 128 * 2);

  const int gN    = (N + TPB - 1) / TPB;
  const int gE    = (E + TPB - 1) / TPB;
  const int gGemm = (N + 127) / 128;
  const int gAgg  = (N + 3) / 4;
  const int P     = (N + 511) / 512;
  const int gFill = 8 * ((E + FILL_CHUNK - 1) / FILL_CHUNK);

  wprep_k<<<(64 * 128 + 3 * 128 * 128 + TPB - 1) / TPB, TPB, 0, stream>>>(
      encW, convW, encWt, convWt);

  struct GraphIn { const float* x; const int* ei; const int* batch; };
  GraphIn graphs[2] = {
      {kernel_x, kernel_ei, kernel_b},
      {design_x, design_ei, design_b},
  };

  for (int gi = 0; gi < 2; ++gi) {
    const float* x = graphs[gi].x;
    const int* esrc = graphs[gi].ei;
    const int* edst = graphs[gi].ei + E;
    const int* batch = graphs[gi].batch;

    hipMemsetAsync(cntI, 0, (size_t)N * 4, stream);
    count_dst_k<<<gE, TPB, 0, stream>>>(edst, cntI, E);
    prep_node_k<<<gN, TPB, 0, stream>>>(cntI, dinv, batch, gstart, N, G);
    scan_partial_k<<<P, TPB, 0, stream>>>(cntI, bsum, N);
    scan_small_k<<<1, TPB, 0, stream>>>(bsum, bpre, P, rowptr, N);
    scan_fill_k<<<P, TPB, 0, stream>>>(cntI, bpre, rowptr, cursor, N);
    csrfill_k<<<gFill, TPB, 0, stream>>>(esrc, edst, cursor, csr_src, E, N);

    // encoder: hb = bf16(x @ encW + encB)   (f32 input staged directly)
    mfma_gemm_k<64, true, false, false, true><<<gGemm, TPB, 0, stream>>>(
        x, encWt, encB, hb, N, nullptr, nullptr, nullptr, nullptr, nullptr, nullptr);

    for (int i = 0; i < L; ++i) {
      const unsigned short* src = (i == 0) ? hb : bufY;
      float* mS = (i == L - 1) ? meanF + gi * G : meanS;
      float* rS = (i == L - 1) ? rsigF + gi * G : rsigS;
      float* cS = (i == L - 1) ? cntF + gi * G : cntS;
      if (i == 0)
        mfma_gemm_k<128, false, false, true, false><<<gGemm, TPB, 0, stream>>>(
            src, convWt + (size_t)i * H * H, nullptr, bufX, N,
            nullptr, nullptr, nullptr, nullptr, nullptr, dinv);
      else
        mfma_gemm_k<128, false, true, true, false><<<gGemm, TPB, 0, stream>>>(
            src, convWt + (size_t)i * H * H, nullptr, bufX, N,
            batch, meanS, rsigS, lnw + (size_t)(i - 1) * H,
            lnb + (size_t)(i - 1) * H, dinv);
      aggregate_k<<<gAgg, TPB, 0, stream>>>((const uint4*)bufX, rowptr, csr_src,
                                            dinv, convB + (size_t)i * H,
                                            (uint4*)bufY, rs2, N);
      gstats_k<<<G, TPB, 0, stream>>>(rs2, gstart, mS, rS, cS);
    }
    pool_k<<<G * 8, TPB, 0, stream>>>(bufY, gstart, gi ? partD : partK);
  }

  head_k<<<G, TPB, 0, stream>>>(partK, partD, meanF, rsigF, cntF,
                                lnw + (size_t)(L - 1) * H, lnb + (size_t)(L - 1) * H,
                                W1, b1, W2, b2, W3, b3, out);
}

// Round 9
// 630.820 us; speedup vs baseline: 3.7227x; 1.1150x over previous
//
#include <hip/hip_runtime.h>

// ---------------------------------------------------------------------------
// SimpleDifferentialGNN: 2x GCN encoder + global_add_pool + MLP head.
// N=100000, E=1000000, G=64, D=64, H=128, L=3
// R8: UNION-GRAPH fusion — both graphs processed as one 2N-node/2E-edge
//     batched graph (design nodes +N, design batch +64 -> 128 LN groups).
//     36 -> 20 dispatches (launch-gap reduction), 2x parallelism per kernel.
//     hb aliases bufY to bound workspace.
// ---------------------------------------------------------------------------

#define TPB 256
#define FILL_CHUNK 2048

typedef __attribute__((ext_vector_type(8))) short bf16x8;
typedef __attribute__((ext_vector_type(8))) unsigned short u16x8;
typedef __attribute__((ext_vector_type(4))) float f32x4;

__device__ __forceinline__ float bf2f(unsigned short s) {
  unsigned int u = ((unsigned int)s) << 16;
  float f;
  __builtin_memcpy(&f, &u, 4);
  return f;
}

__device__ __forceinline__ unsigned short f2bf(float f) {
  unsigned int u;
  __builtin_memcpy(&u, &f, 4);
  u = (u + 0x7FFF + ((u >> 16) & 1)) >> 16;  // RNE
  return (unsigned short)u;
}

// ---------------- union edge counting ----------------
// e < E: kernel edge (dst = kei[E+e]); else design edge (dst = dei[e] + N)

__global__ __launch_bounds__(TPB) void count_dst_k(const int* __restrict__ kei,
                                                   const int* __restrict__ dei,
                                                   int* __restrict__ cnt, int E) {
  int e = blockIdx.x * TPB + threadIdx.x;
  if (e >= 2 * E) return;
  int d = (e < E) ? kei[E + e] : dei[e] + 100000;
  atomicAdd(&cnt[d], 1);
}

// dinv + unified batch + graph boundaries in one node pass (union: NT=2N, 128 groups)
__global__ __launch_bounds__(TPB) void prep_node_k(const int* __restrict__ cnt,
                                                   float* __restrict__ dinv,
                                                   const int* __restrict__ kb,
                                                   const int* __restrict__ db,
                                                   int* __restrict__ batchU,
                                                   int* __restrict__ gstart,
                                                   int N, int NT) {
  int i = blockIdx.x * TPB + threadIdx.x;
  if (i >= NT) return;
  dinv[i] = 1.0f / sqrtf((float)cnt[i] + 1.0f);
  int b = (i < N) ? kb[i] : db[i - N] + 64;
  batchU[i] = b;
  if (i == 0) {
    for (int g = 0; g <= b; ++g) gstart[g] = 0;
  } else {
    int pb = (i - 1 < N) ? kb[i - 1] : db[i - 1 - N] + 64;
    for (int g = pb + 1; g <= b; ++g) gstart[g] = i;
  }
  if (i == NT - 1) {
    for (int g = b + 1; g <= 128; ++g) gstart[g] = NT;
  }
}

// ---------------- multi-block exclusive scan (NT elements) ----------------

__global__ __launch_bounds__(TPB) void scan_partial_k(const int* __restrict__ cnt,
                                                      int* __restrict__ bsum, int n) {
  __shared__ int sd[TPB];
  int t = threadIdx.x, i0 = blockIdx.x * 512 + t * 2;
  int s = 0;
  if (i0 < n) s += cnt[i0];
  if (i0 + 1 < n) s += cnt[i0 + 1];
  sd[t] = s;
  __syncthreads();
  for (int st = TPB / 2; st > 0; st >>= 1) {
    if (t < st) sd[t] += sd[t + st];
    __syncthreads();
  }
  if (t == 0) bsum[blockIdx.x] = sd[0];
}

// 512-thread scan of up to 512 partials
__global__ __launch_bounds__(512) void scan_small_k(const int* __restrict__ bsum,
                                                    int* __restrict__ bpre, int P,
                                                    int* __restrict__ rowptr, int n) {
  __shared__ int sd[512];
  int t = threadIdx.x;
  int v = (t < P) ? bsum[t] : 0;
  sd[t] = v;
  __syncthreads();
  for (int d = 1; d < 512; d <<= 1) {
    int w = (t >= d) ? sd[t - d] : 0;
    __syncthreads();
    sd[t] += w;
    __syncthreads();
  }
  if (t < P) bpre[t] = sd[t] - v;
  if (t == 511) rowptr[n] = sd[511];
}

// fills rowptr AND cursor (identical) — saves the d2d copy
__global__ __launch_bounds__(TPB) void scan_fill_k(const int* __restrict__ cnt,
                                                   const int* __restrict__ bpre,
                                                   int* __restrict__ rowptr,
                                                   int* __restrict__ cursor, int n) {
  __shared__ int sd[TPB];
  int t = threadIdx.x, i0 = blockIdx.x * 512 + t * 2;
  int c0 = (i0 < n) ? cnt[i0] : 0;
  int c1 = (i0 + 1 < n) ? cnt[i0 + 1] : 0;
  int s = c0 + c1;
  sd[t] = s;
  __syncthreads();
  for (int d = 1; d < TPB; d <<= 1) {
    int w = (t >= d) ? sd[t - d] : 0;
    __syncthreads();
    sd[t] += w;
    __syncthreads();
  }
  int ex = sd[t] - s + bpre[blockIdx.x];
  if (i0 < n) { rowptr[i0] = ex; cursor[i0] = ex; }
  if (i0 + 1 < n) { rowptr[i0 + 1] = ex + c0; cursor[i0 + 1] = ex + c0; }
}

// ---------------- CSR fill, XCD-range filtered, union edges ----------------

__global__ __launch_bounds__(TPB) void csrfill_k(const int* __restrict__ kei,
                                                 const int* __restrict__ dei,
                                                 int* __restrict__ cursor,
                                                 int* __restrict__ csr_src,
                                                 int E, int NT) {
  int range = blockIdx.x & 7;
  int chunk = blockIdx.x >> 3;
  int nper = (NT + 7) >> 3;
  int lo = range * nper;
  int hi = lo + nper; if (hi > NT) hi = NT;
  int base = chunk * FILL_CHUNK;
  int end = base + FILL_CHUNK; if (end > 2 * E) end = 2 * E;
  const int N = NT >> 1;
  for (int e = base + threadIdx.x; e < end; e += TPB) {
    int s, d;
    if (e < E) { s = kei[e]; d = kei[E + e]; }
    else       { s = dei[e - E] + N; d = dei[e] + N; }
    if (d >= lo && d < hi) {
      int p = atomicAdd(&cursor[d], 1);
      csr_src[p] = s;
    }
  }
}

// ---------------- weight prep: all 4 matrices in one dispatch ----------------

__global__ __launch_bounds__(TPB) void wprep_k(const float* __restrict__ encW,
                                               const float* __restrict__ convW,
                                               unsigned short* __restrict__ encWt,
                                               unsigned short* __restrict__ convWt) {
  int idx = blockIdx.x * TPB + threadIdx.x;
  if (idx < 64 * 128) {
    int k = idx >> 7, c = idx & 127;
    encWt[c * 64 + k] = f2bf(encW[idx]);
  }
  idx -= 64 * 128;
  if (idx >= 0 && idx < 3 * 128 * 128) {
    int l = idx >> 14, r = idx & 16383;
    int k = r >> 7, c = r & 127;
    convWt[l * 16384 + c * 128 + k] = f2bf(convW[idx]);
  }
}

// ---------------- MFMA GEMM ----------------
// A: [nrows][K] bf16, or (if F32IN) two f32 sources split at nsplit.
// Wt: [128][K] bf16.  Optional fused input-LN+ReLU, output dinv-scale.

template <int K, bool BIAS, bool LNRELU, bool SCALE, bool F32IN>
__global__ __launch_bounds__(TPB) void mfma_gemm_k(
    const unsigned short* __restrict__ A, const float* __restrict__ X1,
    const float* __restrict__ X2, int nsplit,
    const unsigned short* __restrict__ Wt,
    const float* __restrict__ bias, unsigned short* __restrict__ C, int nrows,
    const int* __restrict__ batch, const float* __restrict__ meanA,
    const float* __restrict__ rsigA, const float* __restrict__ lnw,
    const float* __restrict__ lnb, const float* __restrict__ dinv) {
  __shared__ short As[128 * K];
  __shared__ short Bs[128 * K];
  const int tid = threadIdx.x;
  const int r0 = blockIdx.x << 7;
  const int lane = tid & 63;
  const int wv = tid >> 6;
  const int lr = lane & 15, lg = lane >> 4;
  constexpr int CPR = K / 8;

  for (int i = tid; i < 128 * CPR; i += TPB) {
    int rloc = i / CPR, cb = i % CPR;
    int r = r0 + rloc;
    bf16x8 v = {0, 0, 0, 0, 0, 0, 0, 0};
    if (r < nrows) {
      if (F32IN) {
        const float* Af = (r < nsplit ? X1 + (long)r * K : X2 + (long)(r - nsplit) * K) + cb * 8;
        float4 f0 = *(const float4*)Af;
        float4 f1 = *(const float4*)(Af + 4);
        v[0] = (short)f2bf(f0.x); v[1] = (short)f2bf(f0.y);
        v[2] = (short)f2bf(f0.z); v[3] = (short)f2bf(f0.w);
        v[4] = (short)f2bf(f1.x); v[5] = (short)f2bf(f1.y);
        v[6] = (short)f2bf(f1.z); v[7] = (short)f2bf(f1.w);
      } else {
        v = *(const bf16x8*)(A + (long)r * K + cb * 8);
        if (LNRELU) {
          int g = batch[r];
          float m = meanA[g], rs = rsigA[g];
          int c0 = cb * 8;
#pragma unroll
          for (int j = 0; j < 8; ++j) {
            float f = bf2f((unsigned short)v[j]);
            f = (f - m) * rs * lnw[c0 + j] + lnb[c0 + j];
            f = fmaxf(f, 0.f);
            v[j] = (short)f2bf(f);
          }
        }
      }
    }
    int sb = cb ^ (rloc & 7);
    *(bf16x8*)(&As[rloc * K + sb * 8]) = v;
  }
  for (int i = tid; i < 128 * CPR; i += TPB) {
    int rloc = i / CPR, cb = i % CPR;
    bf16x8 v = *(const bf16x8*)(Wt + (long)rloc * K + cb * 8);
    int sb = cb ^ (rloc & 7);
    *(bf16x8*)(&Bs[rloc * K + sb * 8]) = v;
  }
  __syncthreads();

  f32x4 acc[2][8];
#pragma unroll
  for (int m = 0; m < 2; ++m)
#pragma unroll
    for (int n = 0; n < 8; ++n) acc[m][n] = {0.f, 0.f, 0.f, 0.f};

  const int wrow = wv * 32;
#pragma unroll
  for (int k0 = 0; k0 < K; k0 += 32) {
    const int cbk = (k0 >> 3) + lg;
    bf16x8 a[2], b[8];
#pragma unroll
    for (int m = 0; m < 2; ++m) {
      int rr = wrow + m * 16 + lr;
      int sb = cbk ^ (rr & 7);
      a[m] = *(const bf16x8*)(&As[rr * K + sb * 8]);
    }
#pragma unroll
    for (int n = 0; n < 8; ++n) {
      int rr = n * 16 + lr;
      int sb = cbk ^ (rr & 7);
      b[n] = *(const bf16x8*)(&Bs[rr * K + sb * 8]);
    }
#pragma unroll
    for (int m = 0; m < 2; ++m)
#pragma unroll
      for (int n = 0; n < 8; ++n)
        acc[m][n] = __builtin_amdgcn_mfma_f32_16x16x32_bf16(a[m], b[n], acc[m][n], 0, 0, 0);
  }

  float bv[8];
#pragma unroll
  for (int n = 0; n < 8; ++n) bv[n] = BIAS ? bias[n * 16 + lr] : 0.f;
#pragma unroll
  for (int m = 0; m < 2; ++m) {
#pragma unroll
    for (int ri = 0; ri < 4; ++ri) {
      int r = r0 + wrow + m * 16 + lg * 4 + ri;
      if (r < nrows) {
        float dv = SCALE ? dinv[r] : 1.f;
#pragma unroll
        for (int n = 0; n < 8; ++n) {
          float v = acc[m][n][ri] + bv[n];
          if (SCALE) v *= dv;
          C[(long)r * 128 + n * 16 + lr] = f2bf(v);
        }
      }
    }
  }
}

// ---------------- aggregation (dwordx4 gather), union nodes ----------------

__global__ __launch_bounds__(TPB) void aggregate_k(
    const uint4* __restrict__ xws, const int* __restrict__ rowptr,
    const int* __restrict__ csr, const float* __restrict__ dinv,
    const float* __restrict__ bias, uint4* __restrict__ outb,
    float2* __restrict__ rs2, int n) {
  int wave = threadIdx.x >> 6, lane = threadIdx.x & 63;
  int d = (blockIdx.x << 2) + wave;
  if (d >= n) return;
  const int g3 = lane >> 4, cpos = lane & 15;
  float acc[8];
#pragma unroll
  for (int j = 0; j < 8; ++j) acc[j] = 0.f;

  int p0 = rowptr[d], p1 = rowptr[d + 1];
  for (int base = p0; base < p1; base += 64) {
    int idx = base + lane;
    int sl = (idx < p1) ? csr[idx] : 0;
    int cnt = p1 - base;
    if (cnt > 64) cnt = 64;
    for (int e = 0; e < cnt; e += 8) {
      int e0 = e + g3, e1 = e + 4 + g3;
      int s0 = __shfl(sl, e0);
      int s1 = __shfl(sl, e1);
      uint4 u0 = xws[(long)s0 * 16 + cpos];
      uint4 u1 = xws[(long)s1 * 16 + cpos];
      if (e0 < cnt) {
        acc[0] += __uint_as_float(u0.x << 16);
        acc[1] += __uint_as_float(u0.x & 0xffff0000u);
        acc[2] += __uint_as_float(u0.y << 16);
        acc[3] += __uint_as_float(u0.y & 0xffff0000u);
        acc[4] += __uint_as_float(u0.z << 16);
        acc[5] += __uint_as_float(u0.z & 0xffff0000u);
        acc[6] += __uint_as_float(u0.w << 16);
        acc[7] += __uint_as_float(u0.w & 0xffff0000u);
      }
      if (e1 < cnt) {
        acc[0] += __uint_as_float(u1.x << 16);
        acc[1] += __uint_as_float(u1.x & 0xffff0000u);
        acc[2] += __uint_as_float(u1.y << 16);
        acc[3] += __uint_as_float(u1.y & 0xffff0000u);
        acc[4] += __uint_as_float(u1.z << 16);
        acc[5] += __uint_as_float(u1.z & 0xffff0000u);
        acc[6] += __uint_as_float(u1.w << 16);
        acc[7] += __uint_as_float(u1.w & 0xffff0000u);
      }
    }
  }

#pragma unroll
  for (int j = 0; j < 8; ++j) {
    acc[j] += __shfl_xor(acc[j], 16);
    acc[j] += __shfl_xor(acc[j], 32);
  }

  uint4 su = xws[(long)d * 16 + cpos];
  float dd = dinv[d];
  float sv[8];
  sv[0] = __uint_as_float(su.x << 16);
  sv[1] = __uint_as_float(su.x & 0xffff0000u);
  sv[2] = __uint_as_float(su.y << 16);
  sv[3] = __uint_as_float(su.y & 0xffff0000u);
  sv[4] = __uint_as_float(su.z << 16);
  sv[5] = __uint_as_float(su.z & 0xffff0000u);
  sv[6] = __uint_as_float(su.w << 16);
  sv[7] = __uint_as_float(su.w & 0xffff0000u);
  const float4* b4 = (const float4*)bias;
  float4 bb0 = b4[cpos * 2];
  float4 bb1 = b4[cpos * 2 + 1];
  float val[8];
  val[0] = (acc[0] + sv[0]) * dd + bb0.x;
  val[1] = (acc[1] + sv[1]) * dd + bb0.y;
  val[2] = (acc[2] + sv[2]) * dd + bb0.z;
  val[3] = (acc[3] + sv[3]) * dd + bb0.w;
  val[4] = (acc[4] + sv[4]) * dd + bb1.x;
  val[5] = (acc[5] + sv[5]) * dd + bb1.y;
  val[6] = (acc[6] + sv[6]) * dd + bb1.z;
  val[7] = (acc[7] + sv[7]) * dd + bb1.w;

  if (g3 == 0) {
    uint4 o;
    o.x = (unsigned)f2bf(val[0]) | ((unsigned)f2bf(val[1]) << 16);
    o.y = (unsigned)f2bf(val[2]) | ((unsigned)f2bf(val[3]) << 16);
    o.z = (unsigned)f2bf(val[4]) | ((unsigned)f2bf(val[5]) << 16);
    o.w = (unsigned)f2bf(val[6]) | ((unsigned)f2bf(val[7]) << 16);
    outb[(long)d * 16 + cpos] = o;
  }

  float s1 = 0.f, s2 = 0.f;
#pragma unroll
  for (int j = 0; j < 8; ++j) {
    s1 += val[j];
    s2 += val[j] * val[j];
  }
#pragma unroll
  for (int m = 8; m >= 1; m >>= 1) {
    s1 += __shfl_xor(s1, m);
    s2 += __shfl_xor(s2, m);
  }
  if (lane == 0) rs2[d] = make_float2(s1, s2);
}

// ---------------- per-graph LN stats: 128 groups ----------------

__global__ __launch_bounds__(TPB) void gstats_k(const float2* __restrict__ rs2,
                                                const int* __restrict__ gstart,
                                                float* __restrict__ meanA,
                                                float* __restrict__ rsigA,
                                                float* __restrict__ cntA) {
  __shared__ double sd1[TPB], sd2[TPB];
  int g = blockIdx.x, t = threadIdx.x;
  int n0 = gstart[g], n1 = gstart[g + 1];
  double s1 = 0, s2 = 0;
  for (int i = n0 + t; i < n1; i += TPB) {
    float2 v = rs2[i];
    s1 += v.x; s2 += v.y;
  }
  sd1[t] = s1; sd2[t] = s2;
  __syncthreads();
  for (int st = TPB / 2; st > 0; st >>= 1) {
    if (t < st) { sd1[t] += sd1[t + st]; sd2[t] += sd2[t + st]; }
    __syncthreads();
  }
  if (t == 0) {
    double cntd = (double)(n1 - n0) * 128.0;
    if (cntd > 0.0) {
      double mean = sd1[0] / cntd;
      double var = sd2[0] / cntd - mean * mean;
      if (var < 0.0) var = 0.0;
      meanA[g] = (float)mean;
      rsigA[g] = (float)(1.0 / sqrt(var + 1e-5));
    } else {
      meanA[g] = 0.f;
      rsigA[g] = 0.f;
    }
    cntA[g] = (float)(n1 - n0);
  }
}

// ---------------- global add pool (vectorized), 128 groups ----------------

__global__ __launch_bounds__(TPB) void pool_k(const unsigned short* __restrict__ x,
                                              const int* __restrict__ gstart,
                                              float* __restrict__ part) {
  __shared__ float red[16][132];
  int g = blockIdx.x >> 3, s = blockIdx.x & 7;
  int tid = threadIdx.x;
  int ro = tid >> 4, c8 = tid & 15;
  int n0 = gstart[g], n1 = gstart[g + 1];
  float acc[8];
#pragma unroll
  for (int j = 0; j < 8; ++j) acc[j] = 0.f;
  for (int nn = n0 + s + ro * 8; nn < n1; nn += 8 * 16) {
    u16x8 v = *(const u16x8*)(x + (long)nn * 128 + c8 * 8);
#pragma unroll
    for (int j = 0; j < 8; ++j) acc[j] += bf2f(v[j]);
  }
#pragma unroll
  for (int j = 0; j < 8; ++j) red[ro][c8 * 8 + j] = acc[j];
  __syncthreads();
  for (int st = 8; st > 0; st >>= 1) {
    if (ro < st) {
#pragma unroll
      for (int j = 0; j < 8; ++j) red[ro][c8 * 8 + j] += red[ro + st][c8 * 8 + j];
    }
    __syncthreads();
  }
  if (tid < 128) part[((long)s * 128 + g) * 128 + tid] = red[0][tid];
}

// ---------------- MLP head: one block per output graph ----------------
// side 0 = kernel (group g), side 1 = design (group 64+g); final LN folded in.

__global__ __launch_bounds__(TPB) void head_k(
    const float* __restrict__ part, const float* __restrict__ meanU,
    const float* __restrict__ rsigU, const float* __restrict__ cntU,
    const float* __restrict__ lnw2, const float* __restrict__ lnb2,
    const float* __restrict__ W1, const float* __restrict__ b1,
    const float* __restrict__ W2, const float* __restrict__ b2,
    const float* __restrict__ W3, const float* __restrict__ b3,
    float* __restrict__ out) {
  __shared__ float ps[256];
  __shared__ float prt[256];
  __shared__ float h1[128];
  __shared__ float h2[64];
  int g = blockIdx.x, tid = threadIdx.x;
  {
    int j = tid & 127, side = tid >> 7;
    int gg = side ? 64 + g : g;
    float S = 0.f;
#pragma unroll
    for (int s = 0; s < 8; ++s) S += part[((long)s * 128 + gg) * 128 + j];
    float m = meanU[gg], r = rsigU[gg], c = cntU[gg];
    ps[tid] = lnw2[j] * r * (S - m * c) + lnb2[j] * c;
  }
  __syncthreads();
  {
    int j = tid & 127, half = tid >> 7;
    float acc = 0.f;
    const float* w = W1 + (size_t)half * 128 * 128 + j;
    const float* p = ps + half * 128;
#pragma unroll 8
    for (int k = 0; k < 128; ++k) acc = fmaf(p[k], w[(size_t)k * 128], acc);
    prt[tid] = acc;
    __syncthreads();
    if (tid < 128) h1[tid] = fmaxf(prt[tid] + prt[tid + 128] + b1[tid], 0.f);
    __syncthreads();
  }
  {
    int j = tid & 63, q = tid >> 6;
    float acc = 0.f;
    const float* w = W2 + (size_t)q * 32 * 64 + j;
    const float* p = h1 + q * 32;
#pragma unroll 8
    for (int k = 0; k < 32; ++k) acc = fmaf(p[k], w[(size_t)k * 64], acc);
    prt[tid] = acc;
    __syncthreads();
    if (tid < 64)
      h2[tid] = fmaxf(prt[tid] + prt[tid + 64] + prt[tid + 128] + prt[tid + 192] + b2[tid], 0.f);
    __syncthreads();
  }
  if (tid < 64) {
    float v = h2[tid] * W3[tid];
#pragma unroll
    for (int m = 32; m >= 1; m >>= 1) v += __shfl_xor(v, m);
    if (tid == 0) out[g] = v + b3[0];
  }
}

// ---------------------------------------------------------------------------

extern "C" void kernel_launch(void* const* d_in, const int* in_sizes, int n_in,
                              void* d_out, int out_size, void* d_ws, size_t ws_size,
                              hipStream_t stream) {
  const int N = in_sizes[2];       // 100000
  const int E = in_sizes[1] / 2;   // 1000000
  const int NT = 2 * N, ET = 2 * E;
  const int H = 128, L = 3;
  (void)n_in; (void)ws_size; (void)out_size;

  const float* kernel_x = (const float*)d_in[0];
  const int* kernel_ei  = (const int*)d_in[1];
  const int* kernel_b   = (const int*)d_in[2];
  const float* design_x = (const float*)d_in[3];
  const int* design_ei  = (const int*)d_in[4];
  const int* design_b   = (const int*)d_in[5];
  const float* encW  = (const float*)d_in[7];
  const float* encB  = (const float*)d_in[8];
  const float* convW = (const float*)d_in[9];
  const float* convB = (const float*)d_in[10];
  const float* lnw   = (const float*)d_in[11];
  const float* lnb   = (const float*)d_in[12];
  const float* W1 = (const float*)d_in[13];
  const float* b1 = (const float*)d_in[14];
  const float* W2 = (const float*)d_in[15];
  const float* b2 = (const float*)d_in[16];
  const float* W3 = (const float*)d_in[17];
  const float* b3 = (const float*)d_in[18];
  float* out = (float*)d_out;

  char* ws = (char*)d_ws;
  size_t off = 0;
  auto alloc = [&](size_t bytes) -> void* {
    void* p = ws + off;
    off = (off + bytes + 511) & ~(size_t)511;
    return p;
  };
  // bufA: enc-out / agg-out (aliased: enc->hb consumed by conv0 before agg0 writes)
  unsigned short* bufA = (unsigned short*)alloc((size_t)NT * H * 2);
  unsigned short* bufX = (unsigned short*)alloc((size_t)NT * H * 2);  // xws
  float* dinv    = (float*)alloc((size_t)NT * 4);
  int* cntI      = (int*)alloc((size_t)NT * 4);
  int* rowptr    = (int*)alloc((size_t)(NT + 1) * 4);
  int* cursor    = (int*)alloc((size_t)NT * 4);
  int* csr_src   = (int*)alloc((size_t)ET * 4);
  int* batchU    = (int*)alloc((size_t)NT * 4);
  int* gstart    = (int*)alloc((size_t)129 * 4);
  float2* rs2    = (float2*)alloc((size_t)NT * 8);
  float* meanS   = (float*)alloc((size_t)128 * 4);
  float* rsigS   = (float*)alloc((size_t)128 * 4);
  float* cntS    = (float*)alloc((size_t)128 * 4);
  float* meanU   = (float*)alloc((size_t)128 * 4);
  float* rsigU   = (float*)alloc((size_t)128 * 4);
  float* cntU    = (float*)alloc((size_t)128 * 4);
  float* part    = (float*)alloc((size_t)8 * 128 * 128 * 4);
  int* bsum      = (int*)alloc(512 * 4);
  int* bpre      = (int*)alloc(512 * 4);
  unsigned short* encWt  = (unsigned short*)alloc((size_t)128 * 64 * 2);
  unsigned short* convWt = (unsigned short*)alloc((size_t)L * 128 * 128 * 2);

  const int gNT   = (NT + TPB - 1) / TPB;
  const int gET   = (ET + TPB - 1) / TPB;
  const int gGemm = (NT + 127) / 128;        // 1563
  const int gAgg  = (NT + 3) / 4;            // 50000
  const int P     = (NT + 511) / 512;        // 391 (<=512)
  const int gFill = 8 * ((ET + FILL_CHUNK - 1) / FILL_CHUNK);

  wprep_k<<<(64 * 128 + 3 * 128 * 128 + TPB - 1) / TPB, TPB, 0, stream>>>(
      encW, convW, encWt, convWt);

  hipMemsetAsync(cntI, 0, (size_t)NT * 4, stream);
  count_dst_k<<<gET, TPB, 0, stream>>>(kernel_ei, design_ei, cntI, E);
  prep_node_k<<<gNT, TPB, 0, stream>>>(cntI, dinv, kernel_b, design_b, batchU,
                                       gstart, N, NT);
  scan_partial_k<<<P, TPB, 0, stream>>>(cntI, bsum, NT);
  scan_small_k<<<1, 512, 0, stream>>>(bsum, bpre, P, rowptr, NT);
  scan_fill_k<<<P, TPB, 0, stream>>>(cntI, bpre, rowptr, cursor, NT);
  csrfill_k<<<gFill, TPB, 0, stream>>>(kernel_ei, design_ei, cursor, csr_src, E, NT);

  // encoder: bufA = bf16(x @ encW + encB), both graphs
  mfma_gemm_k<64, true, false, false, true><<<gGemm, TPB, 0, stream>>>(
      nullptr, kernel_x, design_x, N, encWt, encB, bufA, NT,
      nullptr, nullptr, nullptr, nullptr, nullptr, nullptr);

  for (int i = 0; i < L; ++i) {
    float* mS = (i == L - 1) ? meanU : meanS;
    float* rS = (i == L - 1) ? rsigU : rsigS;
    float* cS = (i == L - 1) ? cntU : cntS;
    if (i == 0)
      mfma_gemm_k<128, false, false, true, false><<<gGemm, TPB, 0, stream>>>(
          bufA, nullptr, nullptr, 0, convWt + (size_t)i * H * H, nullptr, bufX, NT,
          nullptr, nullptr, nullptr, nullptr, nullptr, dinv);
    else
      mfma_gemm_k<128, false, true, true, false><<<gGemm, TPB, 0, stream>>>(
          bufA, nullptr, nullptr, 0, convWt + (size_t)i * H * H, nullptr, bufX, NT,
          batchU, meanS, rsigS, lnw + (size_t)(i - 1) * H,
          lnb + (size_t)(i - 1) * H, dinv);
    aggregate_k<<<gAgg, TPB, 0, stream>>>((const uint4*)bufX, rowptr, csr_src,
                                          dinv, convB + (size_t)i * H,
                                          (uint4*)bufA, rs2, NT);
    gstats_k<<<128, TPB, 0, stream>>>(rs2, gstart, mS, rS, cS);
  }
  pool_k<<<128 * 8, TPB, 0, stream>>>(bufA, gstart, part);

  head_k<<<64, TPB, 0, stream>>>(part, meanU, rsigU, cntU,
                                 lnw + (size_t)(L - 1) * H, lnb + (size_t)(L - 1) * H,
                                 W1, b1, W2, b2, W3, b3, out);
}

// Round 11
// 627.298 us; speedup vs baseline: 3.7436x; 1.0056x over previous
//
#include <hip/hip_runtime.h>

// ---------------------------------------------------------------------------
// SimpleDifferentialGNN: 2x GCN encoder + global_add_pool + MLP head.
// N=100000, E=1000000, G=64, D=64, H=128, L=3
// R10: dot2-bf16 builtin REVERTED (hardware semantics mismatch -> absmax 320).
//      Back to exact shift/mask unpack, with channel-pair adds as float2
//      vector ops so LLVM can emit v_pk_add_f32 (2 adds/instr).
// ---------------------------------------------------------------------------

#define TPB 256
#define FILL_CHUNK 2048

typedef __attribute__((ext_vector_type(8))) short bf16x8;
typedef __attribute__((ext_vector_type(8))) unsigned short u16x8;
typedef __attribute__((ext_vector_type(4))) float f32x4;
typedef __attribute__((ext_vector_type(2))) float f32x2;

__device__ __forceinline__ float bf2f(unsigned short s) {
  unsigned int u = ((unsigned int)s) << 16;
  float f;
  __builtin_memcpy(&f, &u, 4);
  return f;
}

__device__ __forceinline__ unsigned short f2bf(float f) {
  unsigned int u;
  __builtin_memcpy(&u, &f, 4);
  u = (u + 0x7FFF + ((u >> 16) & 1)) >> 16;  // RNE
  return (unsigned short)u;
}

// ---------------- union edge counting ----------------

__global__ __launch_bounds__(TPB) void count_dst_k(const int* __restrict__ kei,
                                                   const int* __restrict__ dei,
                                                   int* __restrict__ cnt, int E) {
  int e = blockIdx.x * TPB + threadIdx.x;
  if (e >= 2 * E) return;
  int d = (e < E) ? kei[E + e] : dei[e] + 100000;
  atomicAdd(&cnt[d], 1);
}

// dinv + unified batch + graph boundaries (union: NT=2N, 128 groups)
__global__ __launch_bounds__(TPB) void prep_node_k(const int* __restrict__ cnt,
                                                   float* __restrict__ dinv,
                                                   const int* __restrict__ kb,
                                                   const int* __restrict__ db,
                                                   int* __restrict__ batchU,
                                                   int* __restrict__ gstart,
                                                   int N, int NT) {
  int i = blockIdx.x * TPB + threadIdx.x;
  if (i >= NT) return;
  dinv[i] = 1.0f / sqrtf((float)cnt[i] + 1.0f);
  int b = (i < N) ? kb[i] : db[i - N] + 64;
  batchU[i] = b;
  if (i == 0) {
    for (int g = 0; g <= b; ++g) gstart[g] = 0;
  } else {
    int pb = (i - 1 < N) ? kb[i - 1] : db[i - 1 - N] + 64;
    for (int g = pb + 1; g <= b; ++g) gstart[g] = i;
  }
  if (i == NT - 1) {
    for (int g = b + 1; g <= 128; ++g) gstart[g] = NT;
  }
}

// ---------------- multi-block exclusive scan (NT elements) ----------------

__global__ __launch_bounds__(TPB) void scan_partial_k(const int* __restrict__ cnt,
                                                      int* __restrict__ bsum, int n) {
  __shared__ int sd[TPB];
  int t = threadIdx.x, i0 = blockIdx.x * 512 + t * 2;
  int s = 0;
  if (i0 < n) s += cnt[i0];
  if (i0 + 1 < n) s += cnt[i0 + 1];
  sd[t] = s;
  __syncthreads();
  for (int st = TPB / 2; st > 0; st >>= 1) {
    if (t < st) sd[t] += sd[t + st];
    __syncthreads();
  }
  if (t == 0) bsum[blockIdx.x] = sd[0];
}

__global__ __launch_bounds__(512) void scan_small_k(const int* __restrict__ bsum,
                                                    int* __restrict__ bpre, int P,
                                                    int* __restrict__ rowptr, int n) {
  __shared__ int sd[512];
  int t = threadIdx.x;
  int v = (t < P) ? bsum[t] : 0;
  sd[t] = v;
  __syncthreads();
  for (int d = 1; d < 512; d <<= 1) {
    int w = (t >= d) ? sd[t - d] : 0;
    __syncthreads();
    sd[t] += w;
    __syncthreads();
  }
  if (t < P) bpre[t] = sd[t] - v;
  if (t == 511) rowptr[n] = sd[511];
}

__global__ __launch_bounds__(TPB) void scan_fill_k(const int* __restrict__ cnt,
                                                   const int* __restrict__ bpre,
                                                   int* __restrict__ rowptr,
                                                   int* __restrict__ cursor, int n) {
  __shared__ int sd[TPB];
  int t = threadIdx.x, i0 = blockIdx.x * 512 + t * 2;
  int c0 = (i0 < n) ? cnt[i0] : 0;
  int c1 = (i0 + 1 < n) ? cnt[i0 + 1] : 0;
  int s = c0 + c1;
  sd[t] = s;
  __syncthreads();
  for (int d = 1; d < TPB; d <<= 1) {
    int w = (t >= d) ? sd[t - d] : 0;
    __syncthreads();
    sd[t] += w;
    __syncthreads();
  }
  int ex = sd[t] - s + bpre[blockIdx.x];
  if (i0 < n) { rowptr[i0] = ex; cursor[i0] = ex; }
  if (i0 + 1 < n) { rowptr[i0 + 1] = ex + c0; cursor[i0 + 1] = ex + c0; }
}

// ---------------- CSR fill, XCD-range filtered, union edges ----------------

__global__ __launch_bounds__(TPB) void csrfill_k(const int* __restrict__ kei,
                                                 const int* __restrict__ dei,
                                                 int* __restrict__ cursor,
                                                 int* __restrict__ csr_src,
                                                 int E, int NT) {
  int range = blockIdx.x & 7;
  int chunk = blockIdx.x >> 3;
  int nper = (NT + 7) >> 3;
  int lo = range * nper;
  int hi = lo + nper; if (hi > NT) hi = NT;
  int base = chunk * FILL_CHUNK;
  int end = base + FILL_CHUNK; if (end > 2 * E) end = 2 * E;
  const int N = NT >> 1;
  for (int e = base + threadIdx.x; e < end; e += TPB) {
    int s, d;
    if (e < E) { s = kei[e]; d = kei[E + e]; }
    else       { s = dei[e - E] + N; d = dei[e] + N; }
    if (d >= lo && d < hi) {
      int p = atomicAdd(&cursor[d], 1);
      csr_src[p] = s;
    }
  }
}

// ---------------- weight prep ----------------

__global__ __launch_bounds__(TPB) void wprep_k(const float* __restrict__ encW,
                                               const float* __restrict__ convW,
                                               unsigned short* __restrict__ encWt,
                                               unsigned short* __restrict__ convWt) {
  int idx = blockIdx.x * TPB + threadIdx.x;
  if (idx < 64 * 128) {
    int k = idx >> 7, c = idx & 127;
    encWt[c * 64 + k] = f2bf(encW[idx]);
  }
  idx -= 64 * 128;
  if (idx >= 0 && idx < 3 * 128 * 128) {
    int l = idx >> 14, r = idx & 16383;
    int k = r >> 7, c = r & 127;
    convWt[l * 16384 + c * 128 + k] = f2bf(convW[idx]);
  }
}

// ---------------- MFMA GEMM ----------------

template <int K, bool BIAS, bool LNRELU, bool SCALE, bool F32IN>
__global__ __launch_bounds__(TPB) void mfma_gemm_k(
    const unsigned short* __restrict__ A, const float* __restrict__ X1,
    const float* __restrict__ X2, int nsplit,
    const unsigned short* __restrict__ Wt,
    const float* __restrict__ bias, unsigned short* __restrict__ C, int nrows,
    const int* __restrict__ batch, const float* __restrict__ meanA,
    const float* __restrict__ rsigA, const float* __restrict__ lnw,
    const float* __restrict__ lnb, const float* __restrict__ dinv) {
  __shared__ short As[128 * K];
  __shared__ short Bs[128 * K];
  const int tid = threadIdx.x;
  const int r0 = blockIdx.x << 7;
  const int lane = tid & 63;
  const int wv = tid >> 6;
  const int lr = lane & 15, lg = lane >> 4;
  constexpr int CPR = K / 8;

  for (int i = tid; i < 128 * CPR; i += TPB) {
    int rloc = i / CPR, cb = i % CPR;
    int r = r0 + rloc;
    bf16x8 v = {0, 0, 0, 0, 0, 0, 0, 0};
    if (r < nrows) {
      if (F32IN) {
        const float* Af = (r < nsplit ? X1 + (long)r * K : X2 + (long)(r - nsplit) * K) + cb * 8;
        float4 f0 = *(const float4*)Af;
        float4 f1 = *(const float4*)(Af + 4);
        v[0] = (short)f2bf(f0.x); v[1] = (short)f2bf(f0.y);
        v[2] = (short)f2bf(f0.z); v[3] = (short)f2bf(f0.w);
        v[4] = (short)f2bf(f1.x); v[5] = (short)f2bf(f1.y);
        v[6] = (short)f2bf(f1.z); v[7] = (short)f2bf(f1.w);
      } else {
        v = *(const bf16x8*)(A + (long)r * K + cb * 8);
        if (LNRELU) {
          int g = batch[r];
          float m = meanA[g], rs = rsigA[g];
          int c0 = cb * 8;
#pragma unroll
          for (int j = 0; j < 8; ++j) {
            float f = bf2f((unsigned short)v[j]);
            f = (f - m) * rs * lnw[c0 + j] + lnb[c0 + j];
            f = fmaxf(f, 0.f);
            v[j] = (short)f2bf(f);
          }
        }
      }
    }
    int sb = cb ^ (rloc & 7);
    *(bf16x8*)(&As[rloc * K + sb * 8]) = v;
  }
  for (int i = tid; i < 128 * CPR; i += TPB) {
    int rloc = i / CPR, cb = i % CPR;
    bf16x8 v = *(const bf16x8*)(Wt + (long)rloc * K + cb * 8);
    int sb = cb ^ (rloc & 7);
    *(bf16x8*)(&Bs[rloc * K + sb * 8]) = v;
  }
  __syncthreads();

  f32x4 acc[2][8];
#pragma unroll
  for (int m = 0; m < 2; ++m)
#pragma unroll
    for (int n = 0; n < 8; ++n) acc[m][n] = {0.f, 0.f, 0.f, 0.f};

  const int wrow = wv * 32;
#pragma unroll
  for (int k0 = 0; k0 < K; k0 += 32) {
    const int cbk = (k0 >> 3) + lg;
    bf16x8 a[2], b[8];
#pragma unroll
    for (int m = 0; m < 2; ++m) {
      int rr = wrow + m * 16 + lr;
      int sb = cbk ^ (rr & 7);
      a[m] = *(const bf16x8*)(&As[rr * K + sb * 8]);
    }
#pragma unroll
    for (int n = 0; n < 8; ++n) {
      int rr = n * 16 + lr;
      int sb = cbk ^ (rr & 7);
      b[n] = *(const bf16x8*)(&Bs[rr * K + sb * 8]);
    }
#pragma unroll
    for (int m = 0; m < 2; ++m)
#pragma unroll
      for (int n = 0; n < 8; ++n)
        acc[m][n] = __builtin_amdgcn_mfma_f32_16x16x32_bf16(a[m], b[n], acc[m][n], 0, 0, 0);
  }

  float bv[8];
#pragma unroll
  for (int n = 0; n < 8; ++n) bv[n] = BIAS ? bias[n * 16 + lr] : 0.f;
#pragma unroll
  for (int m = 0; m < 2; ++m) {
#pragma unroll
    for (int ri = 0; ri < 4; ++ri) {
      int r = r0 + wrow + m * 16 + lg * 4 + ri;
      if (r < nrows) {
        float dv = SCALE ? dinv[r] : 1.f;
#pragma unroll
        for (int n = 0; n < 8; ++n) {
          float v = acc[m][n][ri] + bv[n];
          if (SCALE) v *= dv;
          C[(long)r * 128 + n * 16 + lr] = f2bf(v);
        }
      }
    }
  }
}

// ---------------- aggregation (dwordx4 gather, packed f32x2 accumulate) -----
// xws already dinv-scaled: out[d] = dd*(xws[d] + sum_e xws[s]) + b.
// One wave per node; 16 lanes cover one 256B row (uint4 each); 4 edge groups.
// Channel-pair adds as float2 vector ops -> v_pk_add_f32 (2 adds/instr).

__global__ __launch_bounds__(TPB) void aggregate_k(
    const uint4* __restrict__ xws, const int* __restrict__ rowptr,
    const int* __restrict__ csr, const float* __restrict__ dinv,
    const float* __restrict__ bias, uint4* __restrict__ outb,
    float2* __restrict__ rs2, int n) {
  int wave = threadIdx.x >> 6, lane = threadIdx.x & 63;
  int d = (blockIdx.x << 2) + wave;
  if (d >= n) return;
  const int g3 = lane >> 4, cpos = lane & 15;
  f32x2 a01 = {0.f, 0.f}, a23 = {0.f, 0.f}, a45 = {0.f, 0.f}, a67 = {0.f, 0.f};

#define ACCQ(U)                                                          \
  {                                                                      \
    f32x2 t;                                                             \
    t.x = __uint_as_float((U).x << 16);                                  \
    t.y = __uint_as_float((U).x & 0xffff0000u);                          \
    a01 += t;                                                            \
    t.x = __uint_as_float((U).y << 16);                                  \
    t.y = __uint_as_float((U).y & 0xffff0000u);                          \
    a23 += t;                                                            \
    t.x = __uint_as_float((U).z << 16);                                  \
    t.y = __uint_as_float((U).z & 0xffff0000u);                          \
    a45 += t;                                                            \
    t.x = __uint_as_float((U).w << 16);                                  \
    t.y = __uint_as_float((U).w & 0xffff0000u);                          \
    a67 += t;                                                            \
  }

  int p0 = rowptr[d], p1 = rowptr[d + 1];
  for (int base = p0; base < p1; base += 64) {
    int idx = base + lane;
    int sl = (idx < p1) ? csr[idx] : 0;
    int cnt = p1 - base;
    if (cnt > 64) cnt = 64;
    for (int e = 0; e < cnt; e += 8) {
      int e0 = e + g3, e1 = e + 4 + g3;
      int s0 = __shfl(sl, e0);  // lanes >= cnt hold 0 -> safe row
      int s1 = __shfl(sl, e1);
      uint4 u0 = xws[(long)s0 * 16 + cpos];
      uint4 u1 = xws[(long)s1 * 16 + cpos];
      if (e0 < cnt) ACCQ(u0);
      if (e1 < cnt) ACCQ(u1);
    }
  }
#undef ACCQ

  float acc[8] = {a01.x, a01.y, a23.x, a23.y, a45.x, a45.y, a67.x, a67.y};
#pragma unroll
  for (int j = 0; j < 8; ++j) {
    acc[j] += __shfl_xor(acc[j], 16);
    acc[j] += __shfl_xor(acc[j], 32);
  }

  uint4 su = xws[(long)d * 16 + cpos];
  float dd = dinv[d];
  float sv[8];
  sv[0] = __uint_as_float(su.x << 16);
  sv[1] = __uint_as_float(su.x & 0xffff0000u);
  sv[2] = __uint_as_float(su.y << 16);
  sv[3] = __uint_as_float(su.y & 0xffff0000u);
  sv[4] = __uint_as_float(su.z << 16);
  sv[5] = __uint_as_float(su.z & 0xffff0000u);
  sv[6] = __uint_as_float(su.w << 16);
  sv[7] = __uint_as_float(su.w & 0xffff0000u);
  const float4* b4 = (const float4*)bias;
  float4 bb0 = b4[cpos * 2];
  float4 bb1 = b4[cpos * 2 + 1];
  float val[8];
  val[0] = (acc[0] + sv[0]) * dd + bb0.x;
  val[1] = (acc[1] + sv[1]) * dd + bb0.y;
  val[2] = (acc[2] + sv[2]) * dd + bb0.z;
  val[3] = (acc[3] + sv[3]) * dd + bb0.w;
  val[4] = (acc[4] + sv[4]) * dd + bb1.x;
  val[5] = (acc[5] + sv[5]) * dd + bb1.y;
  val[6] = (acc[6] + sv[6]) * dd + bb1.z;
  val[7] = (acc[7] + sv[7]) * dd + bb1.w;

  if (g3 == 0) {
    uint4 o;
    o.x = (unsigned)f2bf(val[0]) | ((unsigned)f2bf(val[1]) << 16);
    o.y = (unsigned)f2bf(val[2]) | ((unsigned)f2bf(val[3]) << 16);
    o.z = (unsigned)f2bf(val[4]) | ((unsigned)f2bf(val[5]) << 16);
    o.w = (unsigned)f2bf(val[6]) | ((unsigned)f2bf(val[7]) << 16);
    outb[(long)d * 16 + cpos] = o;
  }

  float s1 = 0.f, s2 = 0.f;
#pragma unroll
  for (int j = 0; j < 8; ++j) {
    s1 += val[j];
    s2 += val[j] * val[j];
  }
#pragma unroll
  for (int m = 8; m >= 1; m >>= 1) {
    s1 += __shfl_xor(s1, m);
    s2 += __shfl_xor(s2, m);
  }
  if (lane == 0) rs2[d] = make_float2(s1, s2);
}

// ---------------- per-graph LN stats: 128 groups ----------------

__global__ __launch_bounds__(TPB) void gstats_k(const float2* __restrict__ rs2,
                                                const int* __restrict__ gstart,
                                                float* __restrict__ meanA,
                                                float* __restrict__ rsigA,
                                                float* __restrict__ cntA) {
  __shared__ double sd1[TPB], sd2[TPB];
  int g = blockIdx.x, t = threadIdx.x;
  int n0 = gstart[g], n1 = gstart[g + 1];
  double s1 = 0, s2 = 0;
  for (int i = n0 + t; i < n1; i += TPB) {
    float2 v = rs2[i];
    s1 += v.x; s2 += v.y;
  }
  sd1[t] = s1; sd2[t] = s2;
  __syncthreads();
  for (int st = TPB / 2; st > 0; st >>= 1) {
    if (t < st) { sd1[t] += sd1[t + st]; sd2[t] += sd2[t + st]; }
    __syncthreads();
  }
  if (t == 0) {
    double cntd = (double)(n1 - n0) * 128.0;
    if (cntd > 0.0) {
      double mean = sd1[0] / cntd;
      double var = sd2[0] / cntd - mean * mean;
      if (var < 0.0) var = 0.0;
      meanA[g] = (float)mean;
      rsigA[g] = (float)(1.0 / sqrt(var + 1e-5));
    } else {
      meanA[g] = 0.f;
      rsigA[g] = 0.f;
    }
    cntA[g] = (float)(n1 - n0);
  }
}

// ---------------- global add pool (vectorized), 128 groups ----------------

__global__ __launch_bounds__(TPB) void pool_k(const unsigned short* __restrict__ x,
                                              const int* __restrict__ gstart,
                                              float* __restrict__ part) {
  __shared__ float red[16][132];
  int g = blockIdx.x >> 3, s = blockIdx.x & 7;
  int tid = threadIdx.x;
  int ro = tid >> 4, c8 = tid & 15;
  int n0 = gstart[g], n1 = gstart[g + 1];
  float acc[8];
#pragma unroll
  for (int j = 0; j < 8; ++j) acc[j] = 0.f;
  for (int nn = n0 + s + ro * 8; nn < n1; nn += 8 * 16) {
    u16x8 v = *(const u16x8*)(x + (long)nn * 128 + c8 * 8);
#pragma unroll
    for (int j = 0; j < 8; ++j) acc[j] += bf2f(v[j]);
  }
#pragma unroll
  for (int j = 0; j < 8; ++j) red[ro][c8 * 8 + j] = acc[j];
  __syncthreads();
  for (int st = 8; st > 0; st >>= 1) {
    if (ro < st) {
#pragma unroll
      for (int j = 0; j < 8; ++j) red[ro][c8 * 8 + j] += red[ro + st][c8 * 8 + j];
    }
    __syncthreads();
  }
  if (tid < 128) part[((long)s * 128 + g) * 128 + tid] = red[0][tid];
}

// ---------------- MLP head: one block per output graph ----------------

__global__ __launch_bounds__(TPB) void head_k(
    const float* __restrict__ part, const float* __restrict__ meanU,
    const float* __restrict__ rsigU, const float* __restrict__ cntU,
    const float* __restrict__ lnw2, const float* __restrict__ lnb2,
    const float* __restrict__ W1, const float* __restrict__ b1,
    const float* __restrict__ W2, const float* __restrict__ b2,
    const float* __restrict__ W3, const float* __restrict__ b3,
    float* __restrict__ out) {
  __shared__ float ps[256];
  __shared__ float prt[256];
  __shared__ float h1[128];
  __shared__ float h2[64];
  int g = blockIdx.x, tid = threadIdx.x;
  {
    int j = tid & 127, side = tid >> 7;
    int gg = side ? 64 + g : g;
    float S = 0.f;
#pragma unroll
    for (int s = 0; s < 8; ++s) S += part[((long)s * 128 + gg) * 128 + j];
    float m = meanU[gg], r = rsigU[gg], c = cntU[gg];
    ps[tid] = lnw2[j] * r * (S - m * c) + lnb2[j] * c;
  }
  __syncthreads();
  {
    int j = tid & 127, half = tid >> 7;
    float acc = 0.f;
    const float* w = W1 + (size_t)half * 128 * 128 + j;
    const float* p = ps + half * 128;
#pragma unroll 8
    for (int k = 0; k < 128; ++k) acc = fmaf(p[k], w[(size_t)k * 128], acc);
    prt[tid] = acc;
    __syncthreads();
    if (tid < 128) h1[tid] = fmaxf(prt[tid] + prt[tid + 128] + b1[tid], 0.f);
    __syncthreads();
  }
  {
    int j = tid & 63, q = tid >> 6;
    float acc = 0.f;
    const float* w = W2 + (size_t)q * 32 * 64 + j;
    const float* p = h1 + q * 32;
#pragma unroll 8
    for (int k = 0; k < 32; ++k) acc = fmaf(p[k], w[(size_t)k * 64], acc);
    prt[tid] = acc;
    __syncthreads();
    if (tid < 64)
      h2[tid] = fmaxf(prt[tid] + prt[tid + 64] + prt[tid + 128] + prt[tid + 192] + b2[tid], 0.f);
    __syncthreads();
  }
  if (tid < 64) {
    float v = h2[tid] * W3[tid];
#pragma unroll
    for (int m = 32; m >= 1; m >>= 1) v += __shfl_xor(v, m);
    if (tid == 0) out[g] = v + b3[0];
  }
}

// ---------------------------------------------------------------------------

extern "C" void kernel_launch(void* const* d_in, const int* in_sizes, int n_in,
                              void* d_out, int out_size, void* d_ws, size_t ws_size,
                              hipStream_t stream) {
  const int N = in_sizes[2];       // 100000
  const int E = in_sizes[1] / 2;   // 1000000
  const int NT = 2 * N, ET = 2 * E;
  const int H = 128, L = 3;
  (void)n_in; (void)ws_size; (void)out_size;

  const float* kernel_x = (const float*)d_in[0];
  const int* kernel_ei  = (const int*)d_in[1];
  const int* kernel_b   = (const int*)d_in[2];
  const float* design_x = (const float*)d_in[3];
  const int* design_ei  = (const int*)d_in[4];
  const int* design_b   = (const int*)d_in[5];
  const float* encW  = (const float*)d_in[7];
  const float* encB  = (const float*)d_in[8];
  const float* convW = (const float*)d_in[9];
  const float* convB = (const float*)d_in[10];
  const float* lnw   = (const float*)d_in[11];
  const float* lnb   = (const float*)d_in[12];
  const float* W1 = (const float*)d_in[13];
  const float* b1 = (const float*)d_in[14];
  const float* W2 = (const float*)d_in[15];
  const float* b2 = (const float*)d_in[16];
  const float* W3 = (const float*)d_in[17];
  const float* b3 = (const float*)d_in[18];
  float* out = (float*)d_out;

  char* ws = (char*)d_ws;
  size_t off = 0;
  auto alloc = [&](size_t bytes) -> void* {
    void* p = ws + off;
    off = (off + bytes + 511) & ~(size_t)511;
    return p;
  };
  unsigned short* bufA = (unsigned short*)alloc((size_t)NT * H * 2);
  unsigned short* bufX = (unsigned short*)alloc((size_t)NT * H * 2);
  float* dinv    = (float*)alloc((size_t)NT * 4);
  int* cntI      = (int*)alloc((size_t)NT * 4);
  int* rowptr    = (int*)alloc((size_t)(NT + 1) * 4);
  int* cursor    = (int*)alloc((size_t)NT * 4);
  int* csr_src   = (int*)alloc((size_t)ET * 4);
  int* batchU    = (int*)alloc((size_t)NT * 4);
  int* gstart    = (int*)alloc((size_t)129 * 4);
  float2* rs2    = (float2*)alloc((size_t)NT * 8);
  float* meanS   = (float*)alloc((size_t)128 * 4);
  float* rsigS   = (float*)alloc((size_t)128 * 4);
  float* cntS    = (float*)alloc((size_t)128 * 4);
  float* meanU   = (float*)alloc((size_t)128 * 4);
  float* rsigU   = (float*)alloc((size_t)128 * 4);
  float* cntU    = (float*)alloc((size_t)128 * 4);
  float* part    = (float*)alloc((size_t)8 * 128 * 128 * 4);
  int* bsum      = (int*)alloc(512 * 4);
  int* bpre      = (int*)alloc(512 * 4);
  unsigned short* encWt  = (unsigned short*)alloc((size_t)128 * 64 * 2);
  unsigned short* convWt = (unsigned short*)alloc((size_t)L * 128 * 128 * 2);

  const int gNT   = (NT + TPB - 1) / TPB;
  const int gET   = (ET + TPB - 1) / TPB;
  const int gGemm = (NT + 127) / 128;
  const int gAgg  = (NT + 3) / 4;
  const int P     = (NT + 511) / 512;
  const int gFill = 8 * ((ET + FILL_CHUNK - 1) / FILL_CHUNK);

  wprep_k<<<(64 * 128 + 3 * 128 * 128 + TPB - 1) / TPB, TPB, 0, stream>>>(
      encW, convW, encWt, convWt);

  hipMemsetAsync(cntI, 0, (size_t)NT * 4, stream);
  count_dst_k<<<gET, TPB, 0, stream>>>(kernel_ei, design_ei, cntI, E);
  prep_node_k<<<gNT, TPB, 0, stream>>>(cntI, dinv, kernel_b, design_b, batchU,
                                       gstart, N, NT);
  scan_partial_k<<<P, TPB, 0, stream>>>(cntI, bsum, NT);
  scan_small_k<<<1, 512, 0, stream>>>(bsum, bpre, P, rowptr, NT);
  scan_fill_k<<<P, TPB, 0, stream>>>(cntI, bpre, rowptr, cursor, NT);
  csrfill_k<<<gFill, TPB, 0, stream>>>(kernel_ei, design_ei, cursor, csr_src, E, NT);

  // encoder: bufA = bf16(x @ encW + encB), both graphs
  mfma_gemm_k<64, true, false, false, true><<<gGemm, TPB, 0, stream>>>(
      nullptr, kernel_x, design_x, N, encWt, encB, bufA, NT,
      nullptr, nullptr, nullptr, nullptr, nullptr, nullptr);

  for (int i = 0; i < L; ++i) {
    float* mS = (i == L - 1) ? meanU : meanS;
    float* rS = (i == L - 1) ? rsigU : rsigS;
    float* cS = (i == L - 1) ? cntU : cntS;
    if (i == 0)
      mfma_gemm_k<128, false, false, true, false><<<gGemm, TPB, 0, stream>>>(
          bufA, nullptr, nullptr, 0, convWt + (size_t)i * H * H, nullptr, bufX, NT,
          nullptr, nullptr, nullptr, nullptr, nullptr, dinv);
    else
      mfma_gemm_k<128, false, true, true, false><<<gGemm, TPB, 0, stream>>>(
          bufA, nullptr, nullptr, 0, convWt + (size_t)i * H * H, nullptr, bufX, NT,
          batchU, meanS, rsigS, lnw + (size_t)(i - 1) * H,
          lnb + (size_t)(i - 1) * H, dinv);
    aggregate_k<<<gAgg, TPB, 0, stream>>>((const uint4*)bufX, rowptr, csr_src,
                                          dinv, convB + (size_t)i * H,
                                          (uint4*)bufA, rs2, NT);
    gstats_k<<<128, TPB, 0, stream>>>(rs2, gstart, mS, rS, cS);
  }
  pool_k<<<128 * 8, TPB, 0, stream>>>(bufA, gstart, part);

  head_k<<<64, TPB, 0, stream>>>(part, meanU, rsigU, cntU,
                                 lnw + (size_t)(L - 1) * H, lnb + (size_t)(L - 1) * H,
                                 W1, b1, W2, b2, W3, b3, out);
}